// Round 1
// baseline (342.618 us; speedup 1.0000x reference)
//
#include <hip/hip_runtime.h>
#include <hip/hip_bf16.h>

typedef unsigned short u16;
typedef unsigned int u32;
typedef __bf16 bf16x8 __attribute__((ext_vector_type(8)));
typedef float f32x4 __attribute__((ext_vector_type(4)));

typedef __attribute__((address_space(1))) void gvoid_t;
typedef __attribute__((address_space(3))) void lvoid_t;
__device__ __forceinline__ void lds_cp16(void* lds, const void* g) {
    __builtin_amdgcn_global_load_lds((gvoid_t*)g, (lvoid_t*)lds, 16, 0, 0);
}

__device__ __forceinline__ float bf2f(u16 v) {
    u32 x = (u32)v << 16;
    return __builtin_bit_cast(float, x);
}
__device__ __forceinline__ u16 f2bf(float f) {
    return __builtin_bit_cast(u16, (__bf16)f);
}

// ---------------- block reduction (256 threads = 4 waves) ----------------
__device__ __forceinline__ float block_sum_256(float v, float* red) {
    #pragma unroll
    for (int o = 32; o > 0; o >>= 1) v += __shfl_xor(v, o);
    int w = threadIdx.x >> 6;
    if ((threadIdx.x & 63) == 0) red[w] = v;
    __syncthreads();
    return red[0] + red[1] + red[2] + red[3];
}

// ---------------- fused: weight conversions + rms_pos (one launch) ----------------
__global__ __launch_bounds__(256) void k_prep(
    const float* __restrict__ f_inw, const float* __restrict__ b_inw,
    const float* __restrict__ f_ow, const float* __restrict__ b_ow,
    const float* __restrict__ w1, const float* __restrict__ w2,
    u16* __restrict__ INWF, u16* __restrict__ INWB,
    u16* __restrict__ OWF, u16* __restrict__ OWB,
    u16* __restrict__ W1B, u16* __restrict__ W2B,
    const float* __restrict__ x, const float* __restrict__ pe,
    const float* __restrict__ wrms, u16* __restrict__ sib) {
    if (blockIdx.x < 21504) {
        int i = blockIdx.x * 256 + threadIdx.x;
        if (i < 1179648) { int n = i >> 9; INWF[i] = (n < 2192) ? f2bf(f_inw[i]) : (u16)0; return; }
        i -= 1179648;
        if (i < 1179648) { int n = i >> 9; INWB[i] = (n < 2192) ? f2bf(b_inw[i]) : (u16)0; return; }
        i -= 1179648;
        if (i < 524288) { OWF[i] = f2bf(f_ow[i]); return; }
        i -= 524288;
        if (i < 524288) { OWB[i] = f2bf(b_ow[i]); return; }
        i -= 524288;
        if (i < 1048576) { W1B[i] = f2bf(w1[i]); return; }
        i -= 1048576;
        if (i < 1048576) W2B[i] = f2bf(w2[i]);
        return;
    }
    __shared__ float red[4];
    int row = blockIdx.x - 21504, t = threadIdx.x;
    size_t base = (size_t)row * 512 + t * 2;
    float2 xv = *(const float2*)(x + base);
    float ss = block_sum_256(xv.x * xv.x + xv.y * xv.y, red);
    float sc = rsqrtf(ss * (1.f / 512.f) + 1.1920929e-07f);
    float2 pv = *(const float2*)(pe + base);
    float2 wv = *(const float2*)(wrms + t * 2);
    sib[base] = f2bf(xv.x * sc * wv.x + pv.x);
    sib[base + 1] = f2bf(xv.y * sc * wv.y + pv.y);
}

// ---------------- in_proj GEMM, BK=32 (async LDS staging; reverted from BK=64) ----------------
__global__ __launch_bounds__(256) void k_gemm_in(
    const u16* __restrict__ A, const u16* __restrict__ W0, const u16* __restrict__ W1,
    u16* __restrict__ Z0, u16* __restrict__ Z1,
    u16* __restrict__ XB0, u16* __restrict__ XB1) {
    const int z = blockIdx.z;
    const u16* W = z ? W1 : W0;
    u16* Z = z ? Z1 : Z0;
    u16* XB = z ? XB1 : XB0;
    const int K = 512;

    __shared__ __align__(16) u16 As[128 * 32];
    __shared__ __align__(16) u16 Bs[128 * 32];

    const int t = threadIdx.x;
    const int lane = t & 63;
    const int w = t >> 6;
    const int m0 = blockIdx.y * 128;
    const int n0 = blockIdx.x * 128;
    const int wm = (w >> 1) * 64;
    const int wn = (w & 1) * 64;
    const int fr = lane & 15;
    const int fk = (lane >> 4) * 8;

    f32x4 acc[4][4];
    #pragma unroll
    for (int i = 0; i < 4; ++i)
        #pragma unroll
        for (int j = 0; j < 4; ++j) acc[i][j] = (f32x4){0.f, 0.f, 0.f, 0.f};

    for (int kt = 0; kt < K; kt += 32) {
        #pragma unroll
        for (int j = 0; j < 2; ++j) {
            int off16 = j * 256 + t;
            int row = off16 >> 2;
            int kc = (off16 & 3) * 8;
            int gm = m0 + row;
            if (z) gm = (gm & ~2047) | (2047 - (gm & 2047));
            lds_cp16(As + off16 * 8, A + (size_t)gm * K + kt + kc);
            lds_cp16(Bs + off16 * 8, W + (size_t)(n0 + row) * K + kt + kc);
        }
        __syncthreads();
        bf16x8 af[4], bfr[4];
        #pragma unroll
        for (int i = 0; i < 4; ++i) af[i] = *(const bf16x8*)(As + (wm + i * 16 + fr) * 32 + fk);
        #pragma unroll
        for (int i = 0; i < 4; ++i) bfr[i] = *(const bf16x8*)(Bs + (wn + i * 16 + fr) * 32 + fk);
        #pragma unroll
        for (int i = 0; i < 4; ++i)
            #pragma unroll
            for (int j = 0; j < 4; ++j)
                acc[i][j] = __builtin_amdgcn_mfma_f32_16x16x32_bf16(af[i], bfr[j], acc[i][j], 0, 0, 0);
        __syncthreads();
    }
    #pragma unroll
    for (int i = 0; i < 4; ++i) {
        int rbase = m0 + wm + i * 16 + (lane >> 4) * 4;
        #pragma unroll
        for (int j = 0; j < 4; ++j) {
            int c = n0 + wn + j * 16 + fr;
            #pragma unroll
            for (int r = 0; r < 4; ++r) {
                u16 v = f2bf(acc[i][j][r]);
                int m = rbase + r;
                if (c < 1024) Z[(size_t)m * 1024 + c] = v;
                else if (c < 2192) XB[(size_t)m * 1184 + (c - 1024)] = v;
            }
        }
    }
}

// ---------------- generic 128x128-tile GEMM (m97 structure), EPI epilogues ----------------
// EPI 0: bf16 store; 1: gelu(acc+bias)->bf16; 2: f32 out = acc + bias + resid.
template <int EPI>
__global__ __launch_bounds__(256) void k_gemm128(
    const u16* __restrict__ A0, const u16* __restrict__ A1,
    const u16* __restrict__ W0, const u16* __restrict__ W1,
    u16* __restrict__ C0, u16* __restrict__ C1, int N, int K,
    const float* __restrict__ bias, const float* __restrict__ resid,
    float* __restrict__ outf) {
    const int z = blockIdx.z;
    const u16* A = z ? A1 : A0;
    const u16* W = z ? W1 : W0;
    u16* C = z ? C1 : C0;

    __shared__ __align__(16) u16 As[128 * 32];
    __shared__ __align__(16) u16 Bs[128 * 32];

    const int t = threadIdx.x;
    const int lane = t & 63;
    const int w = t >> 6;
    const int m0 = blockIdx.y * 128;
    const int n0 = blockIdx.x * 128;
    const int wm = (w >> 1) * 64;
    const int wn = (w & 1) * 64;
    const int fr = lane & 15;
    const int fk = (lane >> 4) * 8;

    f32x4 acc[4][4];
    #pragma unroll
    for (int i = 0; i < 4; ++i)
        #pragma unroll
        for (int j = 0; j < 4; ++j) acc[i][j] = (f32x4){0.f, 0.f, 0.f, 0.f};

    for (int kt = 0; kt < K; kt += 32) {
        #pragma unroll
        for (int j = 0; j < 2; ++j) {
            int off16 = j * 256 + t;
            int row = off16 >> 2;
            int kc = (off16 & 3) * 8;
            lds_cp16(As + off16 * 8, A + (size_t)(m0 + row) * K + kt + kc);
            lds_cp16(Bs + off16 * 8, W + (size_t)(n0 + row) * K + kt + kc);
        }
        __syncthreads();
        bf16x8 af[4], bfr[4];
        #pragma unroll
        for (int i = 0; i < 4; ++i) af[i] = *(const bf16x8*)(As + (wm + i * 16 + fr) * 32 + fk);
        #pragma unroll
        for (int i = 0; i < 4; ++i) bfr[i] = *(const bf16x8*)(Bs + (wn + i * 16 + fr) * 32 + fk);
        #pragma unroll
        for (int i = 0; i < 4; ++i)
            #pragma unroll
            for (int j = 0; j < 4; ++j)
                acc[i][j] = __builtin_amdgcn_mfma_f32_16x16x32_bf16(af[i], bfr[j], acc[i][j], 0, 0, 0);
        __syncthreads();
    }
    #pragma unroll
    for (int i = 0; i < 4; ++i) {
        int rbase = m0 + wm + i * 16 + (lane >> 4) * 4;
        #pragma unroll
        for (int j = 0; j < 4; ++j) {
            int col = n0 + wn + j * 16 + fr;
            #pragma unroll
            for (int r = 0; r < 4; ++r) {
                int m = rbase + r;
                float v = acc[i][j][r];
                if (EPI == 0) {
                    C[(size_t)m * N + col] = f2bf(v);
                } else if (EPI == 1) {
                    float xg = v + bias[col];
                    C[(size_t)m * N + col] = f2bf(0.5f * xg * (1.f + erff(xg * 0.70710678118654752f)));
                } else {
                    outf[(size_t)m * N + col] = v + bias[col] + resid[(size_t)m * N + col];
                }
            }
        }
    }
}

// ---------------- 128x64-tile GEMM for skinny-N shapes (keeps >=2 blk/CU grids) ----------------
// 4 waves stacked along M: each wave owns 32 rows x 64 cols (acc[2][4]).
template <int EPI>
__global__ __launch_bounds__(256) void k_gemm12864(
    const u16* __restrict__ A0, const u16* __restrict__ A1,
    const u16* __restrict__ W0, const u16* __restrict__ W1,
    u16* __restrict__ C0, u16* __restrict__ C1, int N, int K,
    const float* __restrict__ bias, const float* __restrict__ resid,
    float* __restrict__ outf) {
    const int z = blockIdx.z;
    const u16* A = z ? A1 : A0;
    const u16* W = z ? W1 : W0;
    u16* C = z ? C1 : C0;

    __shared__ __align__(16) u16 As[128 * 32];
    __shared__ __align__(16) u16 Bs[64 * 32];

    const int t = threadIdx.x;
    const int lane = t & 63;
    const int w = t >> 6;
    const int m0 = blockIdx.y * 128;
    const int n0 = blockIdx.x * 64;
    const int wm = w * 32;
    const int fr = lane & 15;
    const int fk = (lane >> 4) * 8;

    f32x4 acc[2][4];
    #pragma unroll
    for (int i = 0; i < 2; ++i)
        #pragma unroll
        for (int j = 0; j < 4; ++j) acc[i][j] = (f32x4){0.f, 0.f, 0.f, 0.f};

    for (int kt = 0; kt < K; kt += 32) {
        #pragma unroll
        for (int j = 0; j < 2; ++j) {
            int off16 = j * 256 + t;
            int row = off16 >> 2;
            int kc = (off16 & 3) * 8;
            lds_cp16(As + off16 * 8, A + (size_t)(m0 + row) * K + kt + kc);
        }
        lds_cp16(Bs + t * 8, W + (size_t)(n0 + (t >> 2)) * K + kt + (t & 3) * 8);
        __syncthreads();
        bf16x8 af[2], bfr[4];
        #pragma unroll
        for (int i = 0; i < 2; ++i) af[i] = *(const bf16x8*)(As + (wm + i * 16 + fr) * 32 + fk);
        #pragma unroll
        for (int j = 0; j < 4; ++j) bfr[j] = *(const bf16x8*)(Bs + (j * 16 + fr) * 32 + fk);
        #pragma unroll
        for (int i = 0; i < 2; ++i)
            #pragma unroll
            for (int j = 0; j < 4; ++j)
                acc[i][j] = __builtin_amdgcn_mfma_f32_16x16x32_bf16(af[i], bfr[j], acc[i][j], 0, 0, 0);
        __syncthreads();
    }
    #pragma unroll
    for (int i = 0; i < 2; ++i) {
        int rbase = m0 + wm + i * 16 + (lane >> 4) * 4;
        #pragma unroll
        for (int j = 0; j < 4; ++j) {
            int col = n0 + j * 16 + fr;
            #pragma unroll
            for (int r = 0; r < 4; ++r) {
                int m = rbase + r;
                float v = acc[i][j][r];
                if (EPI == 0) {
                    C[(size_t)m * N + col] = f2bf(v);
                } else if (EPI == 1) {
                    float xg = v + bias[col];
                    C[(size_t)m * N + col] = f2bf(0.5f * xg * (1.f + erff(xg * 0.70710678118654752f)));
                } else {
                    outf[(size_t)m * N + col] = v + bias[col] + resid[(size_t)m * N + col];
                }
            }
        }
    }
}

// ---------------- causal conv4 + silu, 8 rows/block sliding window ----------------
__global__ __launch_bounds__(160) void k_conv(
    const u16* __restrict__ xb0, const u16* __restrict__ xb1,
    const float* __restrict__ cw0, const float* __restrict__ cb0,
    const float* __restrict__ dtb0, const float* __restrict__ al0,
    const float* __restrict__ cw1, const float* __restrict__ cb1,
    const float* __restrict__ dtb1, const float* __restrict__ al1,
    u16* __restrict__ xc0, u16* __restrict__ xc1,
    float* __restrict__ dtO0, float* __restrict__ dAO0,
    float* __restrict__ dtO1, float* __restrict__ dAO1) {
    int g = blockIdx.x;
    int dir = g >> 9;
    int row0 = (g & 511) * 8;
    const u16* xb = dir ? xb1 : xb0;
    const float* cw = dir ? cw1 : cw0;
    const float* cb = dir ? cb1 : cb0;
    const float* dtb = dir ? dtb1 : dtb0;
    const float* al = dir ? al1 : al0;
    u16* xc = dir ? xc1 : xc0;
    float* dtO = dir ? dtO1 : dtO0;
    float* dAO = dir ? dAO1 : dAO0;
    int tl0 = row0 & 2047;
    int rbatch = row0 - tl0;
    int t = threadIdx.x;
    if (t < 144) {
        int col = t * 8;
        float cwa[8][4];
        #pragma unroll
        for (int j = 0; j < 8; ++j) {
            float4 c4 = *(const float4*)(cw + (col + j) * 4);
            cwa[j][0] = c4.x; cwa[j][1] = c4.y; cwa[j][2] = c4.z; cwa[j][3] = c4.w;
        }
        float cbv[8];
        float4 cb0v = *(const float4*)(cb + col);
        float4 cb1v = *(const float4*)(cb + col + 4);
        cbv[0] = cb0v.x; cbv[1] = cb0v.y; cbv[2] = cb0v.z; cbv[3] = cb0v.w;
        cbv[4] = cb1v.x; cbv[5] = cb1v.y; cbv[6] = cb1v.z; cbv[7] = cb1v.w;
        uint4 win[4];
        win[0] = win[1] = win[2] = make_uint4(0, 0, 0, 0);
        #pragma unroll
        for (int i = 0; i < 3; ++i) {
            int tt = tl0 - 3 + i;
            if (tt >= 0) win[i] = *(const uint4*)(xb + (size_t)(rbatch + tt) * 1184 + col);
        }
        for (int s = 0; s < 8; ++s) {
            win[3] = *(const uint4*)(xb + (size_t)(rbatch + tl0 + s) * 1184 + col);
            const u16* w0 = (const u16*)&win[0];
            const u16* w1 = (const u16*)&win[1];
            const u16* w2 = (const u16*)&win[2];
            const u16* w3 = (const u16*)&win[3];
            u16 ov[8];
            #pragma unroll
            for (int j = 0; j < 8; ++j) {
                float a = cbv[j] + bf2f(w0[j]) * cwa[j][0] + bf2f(w1[j]) * cwa[j][1]
                        + bf2f(w2[j]) * cwa[j][2] + bf2f(w3[j]) * cwa[j][3];
                ov[j] = f2bf(a / (1.f + expf(-a)));
            }
            *(uint4*)(xc + (size_t)(row0 + s) * 1152 + col) = *(const uint4*)ov;
            win[0] = win[1]; win[1] = win[2]; win[2] = win[3];
        }
    } else if (t < 160) {
        int hh = t - 144;
        float nal = -expf(al[hh]);
        float dtbv = dtb[hh];
        for (int s = 0; s < 8; ++s) {
            int row = row0 + s;
            float v = bf2f(xb[(size_t)row * 1184 + 1152 + hh]) + dtbv;
            float sp = (v > 20.f) ? v : log1pf(expf(v));
            dtO[row * 16 + hh] = sp;
            dAO[row * 16 + hh] = nal * sp;
        }
    }
}

// ======== SSD chunked scan ========
__global__ __launch_bounds__(256) void k_ssd_state(
    const u16* __restrict__ xc0, const float* __restrict__ dt0, const float* __restrict__ ld0,
    const u16* __restrict__ xc1, const float* __restrict__ dt1, const float* __restrict__ ld1,
    float* __restrict__ S, float* __restrict__ Aprod) {
    int blk = blockIdx.x;
    int c = blk & 31, h = (blk >> 5) & 15, b = (blk >> 9) & 1, dir = blk >> 10;
    const u16* xc = dir ? xc1 : xc0;
    const float* dtp = dir ? dt1 : dt0;
    const float* ldp = dir ? ld1 : ld0;
    const int t = threadIdx.x, w = t >> 6, lane = t & 63;
    const int fr = lane & 15, fk = (lane >> 4) * 8;

    __shared__ __align__(16) u16 sBt[64 * 72];
    __shared__ __align__(16) u16 sXp[64 * 72];
    __shared__ float ssc[64];
    size_t row0 = (size_t)b * 2048 + c * 64;

    if (t < 64) {
        float v = ldp[(row0 + t) * 16 + h];
        float dtv = dtp[(row0 + t) * 16 + h];
        #pragma unroll
        for (int o = 1; o < 64; o <<= 1) {
            float u = __shfl_up(v, o);
            if (lane >= o) v += u;
        }
        float last = __shfl(v, 63);
        ssc[t] = dtv * expf(last - v);
        if (t == 63) Aprod[blk] = expf(v);
    }
    __syncthreads();
    #pragma unroll
    for (int i2 = t; i2 < 512; i2 += 256) {
        int r = i2 >> 3, e8 = (i2 & 7) * 8;
        size_t rb = (row0 + r) * 1152;
        uint4 bv = *(const uint4*)(xc + rb + 1024 + e8);
        uint4 xv = *(const uint4*)(xc + rb + h * 64 + e8);
        const u16* bs = (const u16*)&bv;
        const u16* xs = (const u16*)&xv;
        float sc = ssc[r];
        #pragma unroll
        for (int j = 0; j < 8; ++j) {
            sBt[(e8 + j) * 72 + r] = bs[j];
            sXp[(e8 + j) * 72 + r] = f2bf(bf2f(xs[j]) * sc);
        }
    }
    __syncthreads();

    f32x4 acc[4];
    #pragma unroll
    for (int j = 0; j < 4; ++j) acc[j] = (f32x4){0.f, 0.f, 0.f, 0.f};
    #pragma unroll
    for (int k0 = 0; k0 < 64; k0 += 32) {
        bf16x8 a = *(const bf16x8*)(sBt + (w * 16 + fr) * 72 + k0 + fk);
        #pragma unroll
        for (int j = 0; j < 4; ++j) {
            bf16x8 bb = *(const bf16x8*)(sXp + (j * 16 + fr) * 72 + k0 + fk);
            acc[j] = __builtin_amdgcn_mfma_f32_16x16x32_bf16(a, bb, acc[j], 0, 0, 0);
        }
    }
    float* Sb = S + (size_t)blk * 4096;
    int nb = w * 16 + (lane >> 4) * 4;
    #pragma unroll
    for (int j = 0; j < 4; ++j) {
        int p = j * 16 + fr;
        *(f32x4*)(Sb + p * 64 + nb) = acc[j];
    }
}

// ---- Pass B: fully-parallel carry. grid 1024 = 64 blk-groups x 16; 1 element/thread ----
__global__ __launch_bounds__(256) void k_scan_carry(float* __restrict__ S,
                                                    const float* __restrict__ Aprod) {
    int g = blockIdx.x;
    int blk = g >> 4;
    int e = (g & 15) * 256 + threadIdx.x;
    size_t base = (size_t)blk * 32 * 4096 + e;
    float sv[32];
    #pragma unroll
    for (int c = 0; c < 32; ++c) sv[c] = S[base + (size_t)c * 4096];
    float ap[32];
    #pragma unroll
    for (int c = 0; c < 32; ++c) ap[c] = Aprod[blk * 32 + c];
    float h = 0.f;
    #pragma unroll
    for (int c = 0; c < 32; ++c) {
        S[base + (size_t)c * 4096] = h;
        h = ap[c] * h + sv[c];
    }
}

__global__ __launch_bounds__(256) void k_ssd_y(
    const u16* __restrict__ xc0, const float* __restrict__ dt0, const float* __restrict__ ld0,
    const float* __restrict__ Dv0, u16* __restrict__ y0,
    const u16* __restrict__ xc1, const float* __restrict__ dt1, const float* __restrict__ ld1,
    const float* __restrict__ Dv1, u16* __restrict__ y1,
    const float* __restrict__ S) {
    int blk = blockIdx.x;
    int c = blk & 31, h = (blk >> 5) & 15, b = (blk >> 9) & 1, dir = blk >> 10;
    const u16* xc = dir ? xc1 : xc0;
    const float* dtp = dir ? dt1 : dt0;
    const float* ldp = dir ? ld1 : ld0;
    u16* y = dir ? y1 : y0;
    const float Dh = (dir ? Dv1 : Dv0)[h];
    const int t = threadIdx.x, w = t >> 6, lane = t & 63;
    const int fr = lane & 15, fk = (lane >> 4) * 8;

    __shared__ __align__(16) u16 sB[64 * 72];
    __shared__ __align__(16) u16 sC[64 * 72];
    __shared__ __align__(16) u16 sXp[64 * 72];
    __shared__ __align__(16) u16 sHi[64 * 72];
    __shared__ __align__(16) u16 sLo[64 * 72];
    __shared__ __align__(16) u16 sGl[64 * 72];
    __shared__ float scl[64], sdt[64];
    size_t row0 = (size_t)b * 2048 + c * 64;

    if (t < 64) {
        float v = ldp[(row0 + t) * 16 + h];
        float dtv = dtp[(row0 + t) * 16 + h];
        #pragma unroll
        for (int o = 1; o < 64; o <<= 1) {
            float u = __shfl_up(v, o);
            if (lane >= o) v += u;
        }
        scl[t] = v;
        sdt[t] = dtv;
    }
    __syncthreads();
    #pragma unroll
    for (int i2 = t; i2 < 512; i2 += 256) {
        int r = i2 >> 3, e8 = (i2 & 7) * 8;
        size_t rb = (row0 + r) * 1152;
        *(uint4*)(sB + r * 72 + e8) = *(const uint4*)(xc + rb + 1024 + e8);
        *(uint4*)(sC + r * 72 + e8) = *(const uint4*)(xc + rb + 1088 + e8);
        uint4 xv = *(const uint4*)(xc + rb + h * 64 + e8);
        const u16* xs = (const u16*)&xv;
        float dtv = sdt[r];
        #pragma unroll
        for (int j = 0; j < 8; ++j) sXp[(e8 + j) * 72 + r] = f2bf(bf2f(xs[j]) * dtv);
    }
    #pragma unroll
    for (int i4 = t; i4 < 1024; i4 += 256) {
        int p = i4 >> 4, n4 = (i4 & 15) * 4;
        float4 hv = *(const float4*)(S + (size_t)blk * 4096 + p * 64 + n4);
        ushort4 hi4, lo4;
        hi4.x = f2bf(hv.x); lo4.x = f2bf(hv.x - bf2f(hi4.x));
        hi4.y = f2bf(hv.y); lo4.y = f2bf(hv.y - bf2f(hi4.y));
        hi4.z = f2bf(hv.z); lo4.z = f2bf(hv.z - bf2f(hi4.z));
        hi4.w = f2bf(hv.w); lo4.w = f2bf(hv.w - bf2f(hi4.w));
        *(ushort4*)(sHi + p * 72 + n4) = hi4;
        *(ushort4*)(sLo + p * 72 + n4) = lo4;
    }
    __syncthreads();

    f32x4 g[4], acc2[4];
    #pragma unroll
    for (int j = 0; j < 4; ++j) { g[j] = (f32x4){0.f,0.f,0.f,0.f}; acc2[j] = (f32x4){0.f,0.f,0.f,0.f}; }
    #pragma unroll
    for (int k0 = 0; k0 < 64; k0 += 32) {
        bf16x8 a = *(const bf16x8*)(sC + (w * 16 + fr) * 72 + k0 + fk);
        #pragma unroll
        for (int j = 0; j < 4; ++j) {
            bf16x8 bb = *(const bf16x8*)(sB + (j * 16 + fr) * 72 + k0 + fk);
            g[j] = __builtin_amdgcn_mfma_f32_16x16x32_bf16(a, bb, g[j], 0, 0, 0);
            bf16x8 bh = *(const bf16x8*)(sHi + (j * 16 + fr) * 72 + k0 + fk);
            acc2[j] = __builtin_amdgcn_mfma_f32_16x16x32_bf16(a, bh, acc2[j], 0, 0, 0);
            bf16x8 bl = *(const bf16x8*)(sLo + (j * 16 + fr) * 72 + k0 + fk);
            acc2[j] = __builtin_amdgcn_mfma_f32_16x16x32_bf16(a, bl, acc2[j], 0, 0, 0);
        }
    }
    #pragma unroll
    for (int j = 0; j < 4; ++j) {
        int r = j * 16 + fr;
        #pragma unroll
        for (int reg = 0; reg < 4; ++reg) {
            int s = w * 16 + (lane >> 4) * 4 + reg;
            float val = (r <= s) ? expf(scl[s] - scl[r]) * g[j][reg] : 0.f;
            sGl[s * 72 + r] = f2bf(val);
        }
    }
    __syncthreads();

    f32x4 acc1[4];
    #pragma unroll
    for (int j = 0; j < 4; ++j) acc1[j] = (f32x4){0.f, 0.f, 0.f, 0.f};
    #pragma unroll
    for (int k0 = 0; k0 < 64; k0 += 32) {
        bf16x8 a = *(const bf16x8*)(sGl + (w * 16 + fr) * 72 + k0 + fk);
        #pragma unroll
        for (int j = 0; j < 4; ++j) {
            bf16x8 bb = *(const bf16x8*)(sXp + (j * 16 + fr) * 72 + k0 + fk);
            acc1[j] = __builtin_amdgcn_mfma_f32_16x16x32_bf16(a, bb, acc1[j], 0, 0, 0);
        }
    }
    #pragma unroll
    for (int reg = 0; reg < 4; ++reg) {
        int s = w * 16 + (lane >> 4) * 4 + reg;
        float es = expf(scl[s]);
        size_t yrb = (row0 + s) * 1024 + h * 64;
        size_t xrb = (row0 + s) * 1152 + h * 64;
        #pragma unroll
        for (int j = 0; j < 4; ++j) {
            int p = j * 16 + fr;
            float xv = bf2f(xc[xrb + p]);
            y[yrb + p] = f2bf(acc1[j][reg] + es * acc2[j][reg] + xv * Dh);
        }
    }
}

// ---------------- gated RMS norm ----------------
__global__ __launch_bounds__(256) void k_gnorm(
    const u16* __restrict__ y0, const u16* __restrict__ z0,
    const float* __restrict__ gw0, u16* __restrict__ o0,
    const u16* __restrict__ y1, const u16* __restrict__ z1,
    const float* __restrict__ gw1, u16* __restrict__ o1) {
    __shared__ float red[4];
    int r = blockIdx.x;
    int dir = r >> 12, row = r & 4095;
    int t = threadIdx.x;
    const u16* y = dir ? y1 : y0;
    const u16* zp = dir ? z1 : z0;
    const float* gw = dir ? gw1 : gw0;
    u16* o = dir ? o1 : o0;
    ushort4 yv = *(const ushort4*)(y + (size_t)row * 1024 + t * 4);
    ushort4 zr = *(const ushort4*)(zp + (size_t)row * 1024 + t * 4);
    float z0f = bf2f(zr.x), z1f = bf2f(zr.y), z2f = bf2f(zr.z), z3f = bf2f(zr.w);
    float v0 = bf2f(yv.x) * (z0f / (1.f + expf(-z0f)));
    float v1 = bf2f(yv.y) * (z1f / (1.f + expf(-z1f)));
    float v2 = bf2f(yv.z) * (z2f / (1.f + expf(-z2f)));
    float v3 = bf2f(yv.w) * (z3f / (1.f + expf(-z3f)));
    float ss = block_sum_256(v0 * v0 + v1 * v1 + v2 * v2 + v3 * v3, red);
    float sc = rsqrtf(ss * (1.f / 1024.f) + 1e-5f);
    float4 gv = *(const float4*)(gw + t * 4);
    size_t ob = (size_t)row * 1024 + t * 4;
    o[ob + 0] = f2bf(v0 * sc * gv.x);
    o[ob + 1] = f2bf(v1 * sc * gv.y);
    o[ob + 2] = f2bf(v2 * sc * gv.z);
    o[ob + 3] = f2bf(v3 * sc * gv.w);
}

// ---- fused: x2 = x + (fwd+flip(bwd))*mask; rms(x2)*nfw -> bf16 ----
__global__ __launch_bounds__(256) void k_add_rms(
    const float* __restrict__ x, const u16* __restrict__ of,
    const u16* __restrict__ ob, const float* __restrict__ mask,
    const float* __restrict__ wrms,
    float* __restrict__ x2, u16* __restrict__ o) {
    __shared__ float red[4];
    int row = blockIdx.x, t = threadIdx.x;
    int bb = row >> 11, tl = row & 2047;
    size_t fb = (size_t)((bb << 11) + (2047 - tl)) * 512;
    float m = mask[row];
    size_t base = (size_t)row * 512 + t * 2;
    size_t fo = fb + t * 2;
    float2 xv = *(const float2*)(x + base);
    float v0 = xv.x + (bf2f(of[base]) + bf2f(ob[fo])) * m;
    float v1 = xv.y + (bf2f(of[base + 1]) + bf2f(ob[fo + 1])) * m;
    x2[base] = v0;
    x2[base + 1] = v1;
    float ss = block_sum_256(v0 * v0 + v1 * v1, red);
    float sc = rsqrtf(ss * (1.f / 512.f) + 1.1920929e-07f);
    float2 wv = *(const float2*)(wrms + t * 2);
    o[base] = f2bf(v0 * sc * wv.x);
    o[base + 1] = f2bf(v1 * sc * wv.y);
}

extern "C" void kernel_launch(void* const* d_in, const int* in_sizes, int n_in,
                              void* d_out, int out_size, void* d_ws, size_t ws_size,
                              hipStream_t stream) {
    const float* x = (const float*)d_in[0];
    const float* pe = (const float*)d_in[1];
    const float* mask = (const float*)d_in[2];
    const float* nsw = (const float*)d_in[3];
    const float* nfw = (const float*)d_in[4];
    const float* w1 = (const float*)d_in[5];
    const float* b1 = (const float*)d_in[6];
    const float* w2 = (const float*)d_in[7];
    const float* b2 = (const float*)d_in[8];
    const float* f_inw = (const float*)d_in[9];
    const float* f_cw = (const float*)d_in[10];
    const float* f_cb = (const float*)d_in[11];
    const float* f_dtb = (const float*)d_in[12];
    const float* f_al = (const float*)d_in[13];
    const float* f_D = (const float*)d_in[14];
    const float* f_gw = (const float*)d_in[15];
    const float* f_ow = (const float*)d_in[16];
    const float* b_inw = (const float*)d_in[17];
    const float* b_cw = (const float*)d_in[18];
    const float* b_cb = (const float*)d_in[19];
    const float* b_dtb = (const float*)d_in[20];
    const float* b_al = (const float*)d_in[21];
    const float* b_D = (const float*)d_in[22];
    const float* b_gw = (const float*)d_in[23];
    const float* b_ow = (const float*)d_in[24];
    float* out = (float*)d_out;

    char* ws = (char*)d_ws;
    u16* Z0   = (u16*)(ws + 0);
    u16* Z1   = (u16*)(ws + 8388608);
    u16* XB0  = (u16*)(ws + 16777216);
    u16* XB1  = (u16*)(ws + 26476544);
    u16* INWF = (u16*)(ws + 36175872);
    u16* INWB = (u16*)(ws + 38535168);
    u16* SIB  = (u16*)(ws + 40894464);
    u16* XC0  = (u16*)(ws + 36175872);
    u16* XC1  = (u16*)(ws + 45613056);
    float* dtF = (float*)(ws + 55050240);
    float* dAF = (float*)(ws + 55312384);
    float* dtB = (float*)(ws + 55574528);
    float* dAB = (float*)(ws + 55836672);
    u16* Y0   = (u16*)(ws + 16777216);
    u16* Y1   = (u16*)(ws + 25165824);
    u16* YG0  = (u16*)(ws + 36175872);
    u16* YG1  = (u16*)(ws + 44564480);
    u16* OP0  = (u16*)(ws + 0);
    u16* OP1  = (u16*)(ws + 4194304);
    float* X2 = (float*)(ws + 8388608);
    u16* X2B  = (u16*)(ws + 0);
    u16* HACT = (u16*)(ws + 16777216);
    u16* OWF = (u16*)(ws + 56098816);
    u16* OWB = (u16*)(ws + 57147392);
    u16* W1B = (u16*)(ws + 58195968);
    u16* W2B = (u16*)(ws + 60293120);
    float* SBUF = (float*)(ws + 62390272);
    float* APR  = (float*)(ws + 95944704);

    k_prep<<<25600, 256, 0, stream>>>(f_inw, b_inw, f_ow, b_ow, w1, w2,
                                      INWF, INWB, OWF, OWB, W1B, W2B,
                                      x, pe, nsw, SIB);
    k_gemm_in<<<dim3(18, 32, 2), 256, 0, stream>>>(SIB, INWF, INWB, Z0, Z1, XB0, XB1);
    k_conv<<<1024, 160, 0, stream>>>(XB0, XB1, f_cw, f_cb, f_dtb, f_al,
                                     b_cw, b_cb, b_dtb, b_al,
                                     XC0, XC1, dtF, dAF, dtB, dAB);
    k_ssd_state<<<2048, 256, 0, stream>>>(XC0, dtF, dAF, XC1, dtB, dAB, SBUF, APR);
    k_scan_carry<<<1024, 256, 0, stream>>>(SBUF, APR);
    k_ssd_y<<<2048, 256, 0, stream>>>(XC0, dtF, dAF, f_D, Y0,
                                      XC1, dtB, dAB, b_D, Y1, SBUF);
    k_gnorm<<<8192, 256, 0, stream>>>(Y0, Z0, f_gw, YG0, Y1, Z1, b_gw, YG1);
    // out-proj: M=4096, N=512, K=1024, 2 dirs -> 128x64 tiles, 512 blocks (2/CU)
    k_gemm12864<0><<<dim3(8, 32, 2), 256, 0, stream>>>(YG0, YG1, OWF, OWB, OP0, OP1, 512, 1024,
                                                       nullptr, nullptr, nullptr);
    k_add_rms<<<4096, 256, 0, stream>>>(x, OP0, OP1, mask, nfw, X2, X2B);
    // FFN1: M=4096, N=2048, K=512 -> 128x128 tiles, 512 blocks (2/CU)
    k_gemm128<1><<<dim3(16, 32, 1), 256, 0, stream>>>(X2B, X2B, W1B, W1B, HACT, HACT, 2048, 512,
                                                      b1, nullptr, nullptr);
    // FFN2: M=4096, N=512, K=2048 -> 128x64 tiles, 256 blocks (deep K amortizes)
    k_gemm12864<2><<<dim3(8, 32, 1), 256, 0, stream>>>(HACT, HACT, W2B, W2B, nullptr, nullptr,
                                                       512, 2048, b2, X2, out);
}

// Round 2
// 335.605 us; speedup vs baseline: 1.0209x; 1.0209x over previous
//
#include <hip/hip_runtime.h>
#include <hip/hip_bf16.h>

typedef unsigned short u16;
typedef unsigned int u32;
typedef __bf16 bf16x8 __attribute__((ext_vector_type(8)));
typedef float f32x4 __attribute__((ext_vector_type(4)));

typedef __attribute__((address_space(1))) void gvoid_t;
typedef __attribute__((address_space(3))) void lvoid_t;
__device__ __forceinline__ void lds_cp16(void* lds, const void* g) {
    __builtin_amdgcn_global_load_lds((gvoid_t*)g, (lvoid_t*)lds, 16, 0, 0);
}

__device__ __forceinline__ float bf2f(u16 v) {
    u32 x = (u32)v << 16;
    return __builtin_bit_cast(float, x);
}
__device__ __forceinline__ u16 f2bf(float f) {
    return __builtin_bit_cast(u16, (__bf16)f);
}

// ---------------- block reduction (256 threads = 4 waves) ----------------
__device__ __forceinline__ float block_sum_256(float v, float* red) {
    #pragma unroll
    for (int o = 32; o > 0; o >>= 1) v += __shfl_xor(v, o);
    int w = threadIdx.x >> 6;
    if ((threadIdx.x & 63) == 0) red[w] = v;
    __syncthreads();
    return red[0] + red[1] + red[2] + red[3];
}

// ---------------- fused: weight conversions + rms_pos (one launch) ----------------
__global__ __launch_bounds__(256) void k_prep(
    const float* __restrict__ f_inw, const float* __restrict__ b_inw,
    const float* __restrict__ f_ow, const float* __restrict__ b_ow,
    const float* __restrict__ w1, const float* __restrict__ w2,
    u16* __restrict__ INWF, u16* __restrict__ INWB,
    u16* __restrict__ OWF, u16* __restrict__ OWB,
    u16* __restrict__ W1B, u16* __restrict__ W2B,
    const float* __restrict__ x, const float* __restrict__ pe,
    const float* __restrict__ wrms, u16* __restrict__ sib) {
    if (blockIdx.x < 21504) {
        int i = blockIdx.x * 256 + threadIdx.x;
        if (i < 1179648) { int n = i >> 9; INWF[i] = (n < 2192) ? f2bf(f_inw[i]) : (u16)0; return; }
        i -= 1179648;
        if (i < 1179648) { int n = i >> 9; INWB[i] = (n < 2192) ? f2bf(b_inw[i]) : (u16)0; return; }
        i -= 1179648;
        if (i < 524288) { OWF[i] = f2bf(f_ow[i]); return; }
        i -= 524288;
        if (i < 524288) { OWB[i] = f2bf(b_ow[i]); return; }
        i -= 524288;
        if (i < 1048576) { W1B[i] = f2bf(w1[i]); return; }
        i -= 1048576;
        if (i < 1048576) W2B[i] = f2bf(w2[i]);
        return;
    }
    __shared__ float red[4];
    int row = blockIdx.x - 21504, t = threadIdx.x;
    size_t base = (size_t)row * 512 + t * 2;
    float2 xv = *(const float2*)(x + base);
    float ss = block_sum_256(xv.x * xv.x + xv.y * xv.y, red);
    float sc = rsqrtf(ss * (1.f / 512.f) + 1.1920929e-07f);
    float2 pv = *(const float2*)(pe + base);
    float2 wv = *(const float2*)(wrms + t * 2);
    sib[base] = f2bf(xv.x * sc * wv.x + pv.x);
    sib[base + 1] = f2bf(xv.y * sc * wv.y + pv.y);
}

// ---------------- in_proj GEMM, BK=32, double-buffered prefetch pipeline ----------------
__global__ __launch_bounds__(256) void k_gemm_in(
    const u16* __restrict__ A, const u16* __restrict__ W0, const u16* __restrict__ W1,
    u16* __restrict__ Z0, u16* __restrict__ Z1,
    u16* __restrict__ XB0, u16* __restrict__ XB1) {
    const int z = blockIdx.z;
    const u16* W = z ? W1 : W0;
    u16* Z = z ? Z1 : Z0;
    u16* XB = z ? XB1 : XB0;
    const int K = 512;

    __shared__ __align__(16) u16 As[2][128 * 32];
    __shared__ __align__(16) u16 Bs[2][128 * 32];

    const int t = threadIdx.x;
    const int lane = t & 63;
    const int w = t >> 6;
    const int m0 = blockIdx.y * 128;
    const int n0 = blockIdx.x * 128;
    const int wm = (w >> 1) * 64;
    const int wn = (w & 1) * 64;
    const int fr = lane & 15;
    const int fk = (lane >> 4) * 8;

    f32x4 acc[4][4];
    #pragma unroll
    for (int i = 0; i < 4; ++i)
        #pragma unroll
        for (int j = 0; j < 4; ++j) acc[i][j] = (f32x4){0.f, 0.f, 0.f, 0.f};

    auto STAGE = [&](int buf, int kt) {
        #pragma unroll
        for (int j = 0; j < 2; ++j) {
            int off16 = j * 256 + t;
            int row = off16 >> 2;
            int kc = (off16 & 3) * 8;
            int gm = m0 + row;
            if (z) gm = (gm & ~2047) | (2047 - (gm & 2047));
            lds_cp16(As[buf] + off16 * 8, A + (size_t)gm * K + kt + kc);
            lds_cp16(Bs[buf] + off16 * 8, W + (size_t)(n0 + row) * K + kt + kc);
        }
    };

    STAGE(0, 0);
    __syncthreads();
    int cur = 0;
    for (int kt = 0; kt < K; kt += 32) {
        if (kt + 32 < K) STAGE(cur ^ 1, kt + 32);
        bf16x8 af[4], bfr[4];
        #pragma unroll
        for (int i = 0; i < 4; ++i) af[i] = *(const bf16x8*)(As[cur] + (wm + i * 16 + fr) * 32 + fk);
        #pragma unroll
        for (int i = 0; i < 4; ++i) bfr[i] = *(const bf16x8*)(Bs[cur] + (wn + i * 16 + fr) * 32 + fk);
        #pragma unroll
        for (int i = 0; i < 4; ++i)
            #pragma unroll
            for (int j = 0; j < 4; ++j)
                acc[i][j] = __builtin_amdgcn_mfma_f32_16x16x32_bf16(af[i], bfr[j], acc[i][j], 0, 0, 0);
        __syncthreads();
        cur ^= 1;
    }
    #pragma unroll
    for (int i = 0; i < 4; ++i) {
        int rbase = m0 + wm + i * 16 + (lane >> 4) * 4;
        #pragma unroll
        for (int j = 0; j < 4; ++j) {
            int c = n0 + wn + j * 16 + fr;
            #pragma unroll
            for (int r = 0; r < 4; ++r) {
                u16 v = f2bf(acc[i][j][r]);
                int m = rbase + r;
                if (c < 1024) Z[(size_t)m * 1024 + c] = v;
                else if (c < 2192) XB[(size_t)m * 1184 + (c - 1024)] = v;
            }
        }
    }
}

// ---------------- generic 128x128-tile GEMM, double-buffered prefetch ----------------
// EPI 0: bf16 store; 1: gelu(acc+bias)->bf16; 2: f32 out = acc + bias + resid.
template <int EPI>
__global__ __launch_bounds__(256) void k_gemm128(
    const u16* __restrict__ A0, const u16* __restrict__ A1,
    const u16* __restrict__ W0, const u16* __restrict__ W1,
    u16* __restrict__ C0, u16* __restrict__ C1, int N, int K,
    const float* __restrict__ bias, const float* __restrict__ resid,
    float* __restrict__ outf) {
    const int z = blockIdx.z;
    const u16* A = z ? A1 : A0;
    const u16* W = z ? W1 : W0;
    u16* C = z ? C1 : C0;

    __shared__ __align__(16) u16 As[2][128 * 32];
    __shared__ __align__(16) u16 Bs[2][128 * 32];

    const int t = threadIdx.x;
    const int lane = t & 63;
    const int w = t >> 6;
    const int m0 = blockIdx.y * 128;
    const int n0 = blockIdx.x * 128;
    const int wm = (w >> 1) * 64;
    const int wn = (w & 1) * 64;
    const int fr = lane & 15;
    const int fk = (lane >> 4) * 8;

    f32x4 acc[4][4];
    #pragma unroll
    for (int i = 0; i < 4; ++i)
        #pragma unroll
        for (int j = 0; j < 4; ++j) acc[i][j] = (f32x4){0.f, 0.f, 0.f, 0.f};

    auto STAGE = [&](int buf, int kt) {
        #pragma unroll
        for (int j = 0; j < 2; ++j) {
            int off16 = j * 256 + t;
            int row = off16 >> 2;
            int kc = (off16 & 3) * 8;
            lds_cp16(As[buf] + off16 * 8, A + (size_t)(m0 + row) * K + kt + kc);
            lds_cp16(Bs[buf] + off16 * 8, W + (size_t)(n0 + row) * K + kt + kc);
        }
    };

    STAGE(0, 0);
    __syncthreads();
    int cur = 0;
    for (int kt = 0; kt < K; kt += 32) {
        if (kt + 32 < K) STAGE(cur ^ 1, kt + 32);
        bf16x8 af[4], bfr[4];
        #pragma unroll
        for (int i = 0; i < 4; ++i) af[i] = *(const bf16x8*)(As[cur] + (wm + i * 16 + fr) * 32 + fk);
        #pragma unroll
        for (int i = 0; i < 4; ++i) bfr[i] = *(const bf16x8*)(Bs[cur] + (wn + i * 16 + fr) * 32 + fk);
        #pragma unroll
        for (int i = 0; i < 4; ++i)
            #pragma unroll
            for (int j = 0; j < 4; ++j)
                acc[i][j] = __builtin_amdgcn_mfma_f32_16x16x32_bf16(af[i], bfr[j], acc[i][j], 0, 0, 0);
        __syncthreads();
        cur ^= 1;
    }
    #pragma unroll
    for (int i = 0; i < 4; ++i) {
        int rbase = m0 + wm + i * 16 + (lane >> 4) * 4;
        #pragma unroll
        for (int j = 0; j < 4; ++j) {
            int col = n0 + wn + j * 16 + fr;
            #pragma unroll
            for (int r = 0; r < 4; ++r) {
                int m = rbase + r;
                float v = acc[i][j][r];
                if (EPI == 0) {
                    C[(size_t)m * N + col] = f2bf(v);
                } else if (EPI == 1) {
                    float xg = v + bias[col];
                    C[(size_t)m * N + col] = f2bf(0.5f * xg * (1.f + erff(xg * 0.70710678118654752f)));
                } else {
                    outf[(size_t)m * N + col] = v + bias[col] + resid[(size_t)m * N + col];
                }
            }
        }
    }
}

// ---------------- 128x64-tile GEMM, double-buffered prefetch ----------------
template <int EPI>
__global__ __launch_bounds__(256) void k_gemm12864(
    const u16* __restrict__ A0, const u16* __restrict__ A1,
    const u16* __restrict__ W0, const u16* __restrict__ W1,
    u16* __restrict__ C0, u16* __restrict__ C1, int N, int K,
    const float* __restrict__ bias, const float* __restrict__ resid,
    float* __restrict__ outf) {
    const int z = blockIdx.z;
    const u16* A = z ? A1 : A0;
    const u16* W = z ? W1 : W0;
    u16* C = z ? C1 : C0;

    __shared__ __align__(16) u16 As[2][128 * 32];
    __shared__ __align__(16) u16 Bs[2][64 * 32];

    const int t = threadIdx.x;
    const int lane = t & 63;
    const int w = t >> 6;
    const int m0 = blockIdx.y * 128;
    const int n0 = blockIdx.x * 64;
    const int wm = w * 32;
    const int fr = lane & 15;
    const int fk = (lane >> 4) * 8;

    f32x4 acc[2][4];
    #pragma unroll
    for (int i = 0; i < 2; ++i)
        #pragma unroll
        for (int j = 0; j < 4; ++j) acc[i][j] = (f32x4){0.f, 0.f, 0.f, 0.f};

    auto STAGE = [&](int buf, int kt) {
        #pragma unroll
        for (int j = 0; j < 2; ++j) {
            int off16 = j * 256 + t;
            int row = off16 >> 2;
            int kc = (off16 & 3) * 8;
            lds_cp16(As[buf] + off16 * 8, A + (size_t)(m0 + row) * K + kt + kc);
        }
        lds_cp16(Bs[buf] + t * 8, W + (size_t)(n0 + (t >> 2)) * K + kt + (t & 3) * 8);
    };

    STAGE(0, 0);
    __syncthreads();
    int cur = 0;
    for (int kt = 0; kt < K; kt += 32) {
        if (kt + 32 < K) STAGE(cur ^ 1, kt + 32);
        bf16x8 af[2], bfr[4];
        #pragma unroll
        for (int i = 0; i < 2; ++i) af[i] = *(const bf16x8*)(As[cur] + (wm + i * 16 + fr) * 32 + fk);
        #pragma unroll
        for (int j = 0; j < 4; ++j) bfr[j] = *(const bf16x8*)(Bs[cur] + (j * 16 + fr) * 32 + fk);
        #pragma unroll
        for (int i = 0; i < 2; ++i)
            #pragma unroll
            for (int j = 0; j < 4; ++j)
                acc[i][j] = __builtin_amdgcn_mfma_f32_16x16x32_bf16(af[i], bfr[j], acc[i][j], 0, 0, 0);
        __syncthreads();
        cur ^= 1;
    }
    #pragma unroll
    for (int i = 0; i < 2; ++i) {
        int rbase = m0 + wm + i * 16 + (lane >> 4) * 4;
        #pragma unroll
        for (int j = 0; j < 4; ++j) {
            int col = n0 + j * 16 + fr;
            #pragma unroll
            for (int r = 0; r < 4; ++r) {
                int m = rbase + r;
                float v = acc[i][j][r];
                if (EPI == 0) {
                    C[(size_t)m * N + col] = f2bf(v);
                } else if (EPI == 1) {
                    float xg = v + bias[col];
                    C[(size_t)m * N + col] = f2bf(0.5f * xg * (1.f + erff(xg * 0.70710678118654752f)));
                } else {
                    outf[(size_t)m * N + col] = v + bias[col] + resid[(size_t)m * N + col];
                }
            }
        }
    }
}

// ---------------- 64x64-tile GEMM (high-occupancy), double-buffered prefetch ----------------
template <int EPI>
__global__ __launch_bounds__(256) void k_gemm64(
    const u16* __restrict__ A0, const u16* __restrict__ A1,
    const u16* __restrict__ W0, const u16* __restrict__ W1,
    u16* __restrict__ C0, u16* __restrict__ C1, int N, int K,
    const float* __restrict__ bias, const float* __restrict__ resid,
    float* __restrict__ outf) {
    const int z = blockIdx.z;
    const u16* A = z ? A1 : A0;
    const u16* W = z ? W1 : W0;
    u16* C = z ? C1 : C0;

    __shared__ __align__(16) u16 As[2][64 * 32];
    __shared__ __align__(16) u16 Bs[2][64 * 32];

    const int t = threadIdx.x;
    const int lane = t & 63;
    const int w = t >> 6;
    const int m0 = blockIdx.y * 64;
    const int n0 = blockIdx.x * 64;
    const int wm = (w >> 1) * 32;
    const int wn = (w & 1) * 32;
    const int fr = lane & 15;
    const int fk = (lane >> 4) * 8;

    f32x4 acc[2][2];
    #pragma unroll
    for (int i = 0; i < 2; ++i)
        #pragma unroll
        for (int j = 0; j < 2; ++j) acc[i][j] = (f32x4){0.f, 0.f, 0.f, 0.f};

    const int srow = t >> 2;
    const int skc = (t & 3) * 8;
    auto STAGE = [&](int buf, int kt) {
        lds_cp16(As[buf] + t * 8, A + (size_t)(m0 + srow) * K + kt + skc);
        lds_cp16(Bs[buf] + t * 8, W + (size_t)(n0 + srow) * K + kt + skc);
    };

    STAGE(0, 0);
    __syncthreads();
    int cur = 0;
    for (int kt = 0; kt < K; kt += 32) {
        if (kt + 32 < K) STAGE(cur ^ 1, kt + 32);
        bf16x8 af[2], bfr[2];
        #pragma unroll
        for (int i = 0; i < 2; ++i) af[i] = *(const bf16x8*)(As[cur] + (wm + i * 16 + fr) * 32 + fk);
        #pragma unroll
        for (int j = 0; j < 2; ++j) bfr[j] = *(const bf16x8*)(Bs[cur] + (wn + j * 16 + fr) * 32 + fk);
        #pragma unroll
        for (int i = 0; i < 2; ++i)
            #pragma unroll
            for (int j = 0; j < 2; ++j)
                acc[i][j] = __builtin_amdgcn_mfma_f32_16x16x32_bf16(af[i], bfr[j], acc[i][j], 0, 0, 0);
        __syncthreads();
        cur ^= 1;
    }
    #pragma unroll
    for (int i = 0; i < 2; ++i) {
        int rbase = m0 + wm + i * 16 + (lane >> 4) * 4;
        #pragma unroll
        for (int j = 0; j < 2; ++j) {
            int col = n0 + wn + j * 16 + fr;
            #pragma unroll
            for (int r = 0; r < 4; ++r) {
                int m = rbase + r;
                float v = acc[i][j][r];
                if (EPI == 0) {
                    C[(size_t)m * N + col] = f2bf(v);
                } else if (EPI == 1) {
                    float xg = v + bias[col];
                    C[(size_t)m * N + col] = f2bf(0.5f * xg * (1.f + erff(xg * 0.70710678118654752f)));
                } else {
                    outf[(size_t)m * N + col] = v + bias[col] + resid[(size_t)m * N + col];
                }
            }
        }
    }
}

// ---------------- causal conv4 + silu, 8 rows/block sliding window ----------------
__global__ __launch_bounds__(160) void k_conv(
    const u16* __restrict__ xb0, const u16* __restrict__ xb1,
    const float* __restrict__ cw0, const float* __restrict__ cb0,
    const float* __restrict__ dtb0, const float* __restrict__ al0,
    const float* __restrict__ cw1, const float* __restrict__ cb1,
    const float* __restrict__ dtb1, const float* __restrict__ al1,
    u16* __restrict__ xc0, u16* __restrict__ xc1,
    float* __restrict__ dtO0, float* __restrict__ dAO0,
    float* __restrict__ dtO1, float* __restrict__ dAO1) {
    int g = blockIdx.x;
    int dir = g >> 9;
    int row0 = (g & 511) * 8;
    const u16* xb = dir ? xb1 : xb0;
    const float* cw = dir ? cw1 : cw0;
    const float* cb = dir ? cb1 : cb0;
    const float* dtb = dir ? dtb1 : dtb0;
    const float* al = dir ? al1 : al0;
    u16* xc = dir ? xc1 : xc0;
    float* dtO = dir ? dtO1 : dtO0;
    float* dAO = dir ? dAO1 : dAO0;
    int tl0 = row0 & 2047;
    int rbatch = row0 - tl0;
    int t = threadIdx.x;
    if (t < 144) {
        int col = t * 8;
        float cwa[8][4];
        #pragma unroll
        for (int j = 0; j < 8; ++j) {
            float4 c4 = *(const float4*)(cw + (col + j) * 4);
            cwa[j][0] = c4.x; cwa[j][1] = c4.y; cwa[j][2] = c4.z; cwa[j][3] = c4.w;
        }
        float cbv[8];
        float4 cb0v = *(const float4*)(cb + col);
        float4 cb1v = *(const float4*)(cb + col + 4);
        cbv[0] = cb0v.x; cbv[1] = cb0v.y; cbv[2] = cb0v.z; cbv[3] = cb0v.w;
        cbv[4] = cb1v.x; cbv[5] = cb1v.y; cbv[6] = cb1v.z; cbv[7] = cb1v.w;
        uint4 win[4];
        win[0] = win[1] = win[2] = make_uint4(0, 0, 0, 0);
        #pragma unroll
        for (int i = 0; i < 3; ++i) {
            int tt = tl0 - 3 + i;
            if (tt >= 0) win[i] = *(const uint4*)(xb + (size_t)(rbatch + tt) * 1184 + col);
        }
        for (int s = 0; s < 8; ++s) {
            win[3] = *(const uint4*)(xb + (size_t)(rbatch + tl0 + s) * 1184 + col);
            const u16* w0 = (const u16*)&win[0];
            const u16* w1 = (const u16*)&win[1];
            const u16* w2 = (const u16*)&win[2];
            const u16* w3 = (const u16*)&win[3];
            u16 ov[8];
            #pragma unroll
            for (int j = 0; j < 8; ++j) {
                float a = cbv[j] + bf2f(w0[j]) * cwa[j][0] + bf2f(w1[j]) * cwa[j][1]
                        + bf2f(w2[j]) * cwa[j][2] + bf2f(w3[j]) * cwa[j][3];
                ov[j] = f2bf(a / (1.f + expf(-a)));
            }
            *(uint4*)(xc + (size_t)(row0 + s) * 1152 + col) = *(const uint4*)ov;
            win[0] = win[1]; win[1] = win[2]; win[2] = win[3];
        }
    } else if (t < 160) {
        int hh = t - 144;
        float nal = -expf(al[hh]);
        float dtbv = dtb[hh];
        for (int s = 0; s < 8; ++s) {
            int row = row0 + s;
            float v = bf2f(xb[(size_t)row * 1184 + 1152 + hh]) + dtbv;
            float sp = (v > 20.f) ? v : log1pf(expf(v));
            dtO[row * 16 + hh] = sp;
            dAO[row * 16 + hh] = nal * sp;
        }
    }
}

// ======== SSD chunked scan ========
__global__ __launch_bounds__(256) void k_ssd_state(
    const u16* __restrict__ xc0, const float* __restrict__ dt0, const float* __restrict__ ld0,
    const u16* __restrict__ xc1, const float* __restrict__ dt1, const float* __restrict__ ld1,
    float* __restrict__ S, float* __restrict__ Aprod) {
    int blk = blockIdx.x;
    int c = blk & 31, h = (blk >> 5) & 15, b = (blk >> 9) & 1, dir = blk >> 10;
    const u16* xc = dir ? xc1 : xc0;
    const float* dtp = dir ? dt1 : dt0;
    const float* ldp = dir ? ld1 : ld0;
    const int t = threadIdx.x, w = t >> 6, lane = t & 63;
    const int fr = lane & 15, fk = (lane >> 4) * 8;

    __shared__ __align__(16) u16 sBt[64 * 72];
    __shared__ __align__(16) u16 sXp[64 * 72];
    __shared__ float ssc[64];
    size_t row0 = (size_t)b * 2048 + c * 64;

    if (t < 64) {
        float v = ldp[(row0 + t) * 16 + h];
        float dtv = dtp[(row0 + t) * 16 + h];
        #pragma unroll
        for (int o = 1; o < 64; o <<= 1) {
            float u = __shfl_up(v, o);
            if (lane >= o) v += u;
        }
        float last = __shfl(v, 63);
        ssc[t] = dtv * expf(last - v);
        if (t == 63) Aprod[blk] = expf(v);
    }
    __syncthreads();
    #pragma unroll
    for (int i2 = t; i2 < 512; i2 += 256) {
        int r = i2 >> 3, e8 = (i2 & 7) * 8;
        size_t rb = (row0 + r) * 1152;
        uint4 bv = *(const uint4*)(xc + rb + 1024 + e8);
        uint4 xv = *(const uint4*)(xc + rb + h * 64 + e8);
        const u16* bs = (const u16*)&bv;
        const u16* xs = (const u16*)&xv;
        float sc = ssc[r];
        #pragma unroll
        for (int j = 0; j < 8; ++j) {
            sBt[(e8 + j) * 72 + r] = bs[j];
            sXp[(e8 + j) * 72 + r] = f2bf(bf2f(xs[j]) * sc);
        }
    }
    __syncthreads();

    f32x4 acc[4];
    #pragma unroll
    for (int j = 0; j < 4; ++j) acc[j] = (f32x4){0.f, 0.f, 0.f, 0.f};
    #pragma unroll
    for (int k0 = 0; k0 < 64; k0 += 32) {
        bf16x8 a = *(const bf16x8*)(sBt + (w * 16 + fr) * 72 + k0 + fk);
        #pragma unroll
        for (int j = 0; j < 4; ++j) {
            bf16x8 bb = *(const bf16x8*)(sXp + (j * 16 + fr) * 72 + k0 + fk);
            acc[j] = __builtin_amdgcn_mfma_f32_16x16x32_bf16(a, bb, acc[j], 0, 0, 0);
        }
    }
    float* Sb = S + (size_t)blk * 4096;
    int nb = w * 16 + (lane >> 4) * 4;
    #pragma unroll
    for (int j = 0; j < 4; ++j) {
        int p = j * 16 + fr;
        *(f32x4*)(Sb + p * 64 + nb) = acc[j];
    }
}

// ---- Pass B: fully-parallel carry. grid 1024 = 64 blk-groups x 16; 1 element/thread ----
__global__ __launch_bounds__(256) void k_scan_carry(float* __restrict__ S,
                                                    const float* __restrict__ Aprod) {
    int g = blockIdx.x;
    int blk = g >> 4;
    int e = (g & 15) * 256 + threadIdx.x;
    size_t base = (size_t)blk * 32 * 4096 + e;
    float sv[32];
    #pragma unroll
    for (int c = 0; c < 32; ++c) sv[c] = S[base + (size_t)c * 4096];
    float ap[32];
    #pragma unroll
    for (int c = 0; c < 32; ++c) ap[c] = Aprod[blk * 32 + c];
    float h = 0.f;
    #pragma unroll
    for (int c = 0; c < 32; ++c) {
        S[base + (size_t)c * 4096] = h;
        h = ap[c] * h + sv[c];
    }
}

__global__ __launch_bounds__(256) void k_ssd_y(
    const u16* __restrict__ xc0, const float* __restrict__ dt0, const float* __restrict__ ld0,
    const float* __restrict__ Dv0, u16* __restrict__ y0,
    const u16* __restrict__ xc1, const float* __restrict__ dt1, const float* __restrict__ ld1,
    const float* __restrict__ Dv1, u16* __restrict__ y1,
    const float* __restrict__ S) {
    int blk = blockIdx.x;
    int c = blk & 31, h = (blk >> 5) & 15, b = (blk >> 9) & 1, dir = blk >> 10;
    const u16* xc = dir ? xc1 : xc0;
    const float* dtp = dir ? dt1 : dt0;
    const float* ldp = dir ? ld1 : ld0;
    u16* y = dir ? y1 : y0;
    const float Dh = (dir ? Dv1 : Dv0)[h];
    const int t = threadIdx.x, w = t >> 6, lane = t & 63;
    const int fr = lane & 15, fk = (lane >> 4) * 8;

    __shared__ __align__(16) u16 sB[64 * 72];
    __shared__ __align__(16) u16 sC[64 * 72];
    __shared__ __align__(16) u16 sXp[64 * 72];
    __shared__ __align__(16) u16 sHi[64 * 72];
    __shared__ __align__(16) u16 sLo[64 * 72];
    __shared__ __align__(16) u16 sGl[64 * 72];
    __shared__ float scl[64], sdt[64];
    size_t row0 = (size_t)b * 2048 + c * 64;

    if (t < 64) {
        float v = ldp[(row0 + t) * 16 + h];
        float dtv = dtp[(row0 + t) * 16 + h];
        #pragma unroll
        for (int o = 1; o < 64; o <<= 1) {
            float u = __shfl_up(v, o);
            if (lane >= o) v += u;
        }
        scl[t] = v;
        sdt[t] = dtv;
    }
    __syncthreads();
    #pragma unroll
    for (int i2 = t; i2 < 512; i2 += 256) {
        int r = i2 >> 3, e8 = (i2 & 7) * 8;
        size_t rb = (row0 + r) * 1152;
        *(uint4*)(sB + r * 72 + e8) = *(const uint4*)(xc + rb + 1024 + e8);
        *(uint4*)(sC + r * 72 + e8) = *(const uint4*)(xc + rb + 1088 + e8);
        uint4 xv = *(const uint4*)(xc + rb + h * 64 + e8);
        const u16* xs = (const u16*)&xv;
        float dtv = sdt[r];
        #pragma unroll
        for (int j = 0; j < 8; ++j) sXp[(e8 + j) * 72 + r] = f2bf(bf2f(xs[j]) * dtv);
    }
    #pragma unroll
    for (int i4 = t; i4 < 1024; i4 += 256) {
        int p = i4 >> 4, n4 = (i4 & 15) * 4;
        float4 hv = *(const float4*)(S + (size_t)blk * 4096 + p * 64 + n4);
        ushort4 hi4, lo4;
        hi4.x = f2bf(hv.x); lo4.x = f2bf(hv.x - bf2f(hi4.x));
        hi4.y = f2bf(hv.y); lo4.y = f2bf(hv.y - bf2f(hi4.y));
        hi4.z = f2bf(hv.z); lo4.z = f2bf(hv.z - bf2f(hi4.z));
        hi4.w = f2bf(hv.w); lo4.w = f2bf(hv.w - bf2f(hi4.w));
        *(ushort4*)(sHi + p * 72 + n4) = hi4;
        *(ushort4*)(sLo + p * 72 + n4) = lo4;
    }
    __syncthreads();

    f32x4 g[4], acc2[4];
    #pragma unroll
    for (int j = 0; j < 4; ++j) { g[j] = (f32x4){0.f,0.f,0.f,0.f}; acc2[j] = (f32x4){0.f,0.f,0.f,0.f}; }
    #pragma unroll
    for (int k0 = 0; k0 < 64; k0 += 32) {
        bf16x8 a = *(const bf16x8*)(sC + (w * 16 + fr) * 72 + k0 + fk);
        #pragma unroll
        for (int j = 0; j < 4; ++j) {
            bf16x8 bb = *(const bf16x8*)(sB + (j * 16 + fr) * 72 + k0 + fk);
            g[j] = __builtin_amdgcn_mfma_f32_16x16x32_bf16(a, bb, g[j], 0, 0, 0);
            bf16x8 bh = *(const bf16x8*)(sHi + (j * 16 + fr) * 72 + k0 + fk);
            acc2[j] = __builtin_amdgcn_mfma_f32_16x16x32_bf16(a, bh, acc2[j], 0, 0, 0);
            bf16x8 bl = *(const bf16x8*)(sLo + (j * 16 + fr) * 72 + k0 + fk);
            acc2[j] = __builtin_amdgcn_mfma_f32_16x16x32_bf16(a, bl, acc2[j], 0, 0, 0);
        }
    }
    #pragma unroll
    for (int j = 0; j < 4; ++j) {
        int r = j * 16 + fr;
        #pragma unroll
        for (int reg = 0; reg < 4; ++reg) {
            int s = w * 16 + (lane >> 4) * 4 + reg;
            float val = (r <= s) ? expf(scl[s] - scl[r]) * g[j][reg] : 0.f;
            sGl[s * 72 + r] = f2bf(val);
        }
    }
    __syncthreads();

    f32x4 acc1[4];
    #pragma unroll
    for (int j = 0; j < 4; ++j) acc1[j] = (f32x4){0.f, 0.f, 0.f, 0.f};
    #pragma unroll
    for (int k0 = 0; k0 < 64; k0 += 32) {
        bf16x8 a = *(const bf16x8*)(sGl + (w * 16 + fr) * 72 + k0 + fk);
        #pragma unroll
        for (int j = 0; j < 4; ++j) {
            bf16x8 bb = *(const bf16x8*)(sXp + (j * 16 + fr) * 72 + k0 + fk);
            acc1[j] = __builtin_amdgcn_mfma_f32_16x16x32_bf16(a, bb, acc1[j], 0, 0, 0);
        }
    }
    #pragma unroll
    for (int reg = 0; reg < 4; ++reg) {
        int s = w * 16 + (lane >> 4) * 4 + reg;
        float es = expf(scl[s]);
        size_t yrb = (row0 + s) * 1024 + h * 64;
        size_t xrb = (row0 + s) * 1152 + h * 64;
        #pragma unroll
        for (int j = 0; j < 4; ++j) {
            int p = j * 16 + fr;
            float xv = bf2f(xc[xrb + p]);
            y[yrb + p] = f2bf(acc1[j][reg] + es * acc2[j][reg] + xv * Dh);
        }
    }
}

// ---------------- gated RMS norm ----------------
__global__ __launch_bounds__(256) void k_gnorm(
    const u16* __restrict__ y0, const u16* __restrict__ z0,
    const float* __restrict__ gw0, u16* __restrict__ o0,
    const u16* __restrict__ y1, const u16* __restrict__ z1,
    const float* __restrict__ gw1, u16* __restrict__ o1) {
    __shared__ float red[4];
    int r = blockIdx.x;
    int dir = r >> 12, row = r & 4095;
    int t = threadIdx.x;
    const u16* y = dir ? y1 : y0;
    const u16* zp = dir ? z1 : z0;
    const float* gw = dir ? gw1 : gw0;
    u16* o = dir ? o1 : o0;
    ushort4 yv = *(const ushort4*)(y + (size_t)row * 1024 + t * 4);
    ushort4 zr = *(const ushort4*)(zp + (size_t)row * 1024 + t * 4);
    float z0f = bf2f(zr.x), z1f = bf2f(zr.y), z2f = bf2f(zr.z), z3f = bf2f(zr.w);
    float v0 = bf2f(yv.x) * (z0f / (1.f + expf(-z0f)));
    float v1 = bf2f(yv.y) * (z1f / (1.f + expf(-z1f)));
    float v2 = bf2f(yv.z) * (z2f / (1.f + expf(-z2f)));
    float v3 = bf2f(yv.w) * (z3f / (1.f + expf(-z3f)));
    float ss = block_sum_256(v0 * v0 + v1 * v1 + v2 * v2 + v3 * v3, red);
    float sc = rsqrtf(ss * (1.f / 1024.f) + 1e-5f);
    float4 gv = *(const float4*)(gw + t * 4);
    size_t ob = (size_t)row * 1024 + t * 4;
    o[ob + 0] = f2bf(v0 * sc * gv.x);
    o[ob + 1] = f2bf(v1 * sc * gv.y);
    o[ob + 2] = f2bf(v2 * sc * gv.z);
    o[ob + 3] = f2bf(v3 * sc * gv.w);
}

// ---- fused: x2 = x + (fwd+flip(bwd))*mask; rms(x2)*nfw -> bf16 ----
__global__ __launch_bounds__(256) void k_add_rms(
    const float* __restrict__ x, const u16* __restrict__ of,
    const u16* __restrict__ ob, const float* __restrict__ mask,
    const float* __restrict__ wrms,
    float* __restrict__ x2, u16* __restrict__ o) {
    __shared__ float red[4];
    int row = blockIdx.x, t = threadIdx.x;
    int bb = row >> 11, tl = row & 2047;
    size_t fb = (size_t)((bb << 11) + (2047 - tl)) * 512;
    float m = mask[row];
    size_t base = (size_t)row * 512 + t * 2;
    size_t fo = fb + t * 2;
    float2 xv = *(const float2*)(x + base);
    float v0 = xv.x + (bf2f(of[base]) + bf2f(ob[fo])) * m;
    float v1 = xv.y + (bf2f(of[base + 1]) + bf2f(ob[fo + 1])) * m;
    x2[base] = v0;
    x2[base + 1] = v1;
    float ss = block_sum_256(v0 * v0 + v1 * v1, red);
    float sc = rsqrtf(ss * (1.f / 512.f) + 1.1920929e-07f);
    float2 wv = *(const float2*)(wrms + t * 2);
    o[base] = f2bf(v0 * sc * wv.x);
    o[base + 1] = f2bf(v1 * sc * wv.y);
}

extern "C" void kernel_launch(void* const* d_in, const int* in_sizes, int n_in,
                              void* d_out, int out_size, void* d_ws, size_t ws_size,
                              hipStream_t stream) {
    const float* x = (const float*)d_in[0];
    const float* pe = (const float*)d_in[1];
    const float* mask = (const float*)d_in[2];
    const float* nsw = (const float*)d_in[3];
    const float* nfw = (const float*)d_in[4];
    const float* w1 = (const float*)d_in[5];
    const float* b1 = (const float*)d_in[6];
    const float* w2 = (const float*)d_in[7];
    const float* b2 = (const float*)d_in[8];
    const float* f_inw = (const float*)d_in[9];
    const float* f_cw = (const float*)d_in[10];
    const float* f_cb = (const float*)d_in[11];
    const float* f_dtb = (const float*)d_in[12];
    const float* f_al = (const float*)d_in[13];
    const float* f_D = (const float*)d_in[14];
    const float* f_gw = (const float*)d_in[15];
    const float* f_ow = (const float*)d_in[16];
    const float* b_inw = (const float*)d_in[17];
    const float* b_cw = (const float*)d_in[18];
    const float* b_cb = (const float*)d_in[19];
    const float* b_dtb = (const float*)d_in[20];
    const float* b_al = (const float*)d_in[21];
    const float* b_D = (const float*)d_in[22];
    const float* b_gw = (const float*)d_in[23];
    const float* b_ow = (const float*)d_in[24];
    float* out = (float*)d_out;

    char* ws = (char*)d_ws;
    u16* Z0   = (u16*)(ws + 0);
    u16* Z1   = (u16*)(ws + 8388608);
    u16* XB0  = (u16*)(ws + 16777216);
    u16* XB1  = (u16*)(ws + 26476544);
    u16* INWF = (u16*)(ws + 36175872);
    u16* INWB = (u16*)(ws + 38535168);
    u16* SIB  = (u16*)(ws + 40894464);
    u16* XC0  = (u16*)(ws + 36175872);
    u16* XC1  = (u16*)(ws + 45613056);
    float* dtF = (float*)(ws + 55050240);
    float* dAF = (float*)(ws + 55312384);
    float* dtB = (float*)(ws + 55574528);
    float* dAB = (float*)(ws + 55836672);
    u16* Y0   = (u16*)(ws + 16777216);
    u16* Y1   = (u16*)(ws + 25165824);
    u16* YG0  = (u16*)(ws + 36175872);
    u16* YG1  = (u16*)(ws + 44564480);
    u16* OP0  = (u16*)(ws + 0);
    u16* OP1  = (u16*)(ws + 4194304);
    float* X2 = (float*)(ws + 8388608);
    u16* X2B  = (u16*)(ws + 0);
    u16* HACT = (u16*)(ws + 16777216);
    u16* OWF = (u16*)(ws + 56098816);
    u16* OWB = (u16*)(ws + 57147392);
    u16* W1B = (u16*)(ws + 58195968);
    u16* W2B = (u16*)(ws + 60293120);
    float* SBUF = (float*)(ws + 62390272);
    float* APR  = (float*)(ws + 95944704);

    k_prep<<<25600, 256, 0, stream>>>(f_inw, b_inw, f_ow, b_ow, w1, w2,
                                      INWF, INWB, OWF, OWB, W1B, W2B,
                                      x, pe, nsw, SIB);
    k_gemm_in<<<dim3(18, 32, 2), 256, 0, stream>>>(SIB, INWF, INWB, Z0, Z1, XB0, XB1);
    k_conv<<<1024, 160, 0, stream>>>(XB0, XB1, f_cw, f_cb, f_dtb, f_al,
                                     b_cw, b_cb, b_dtb, b_al,
                                     XC0, XC1, dtF, dAF, dtB, dAB);
    k_ssd_state<<<2048, 256, 0, stream>>>(XC0, dtF, dAF, XC1, dtB, dAB, SBUF, APR);
    k_scan_carry<<<1024, 256, 0, stream>>>(SBUF, APR);
    k_ssd_y<<<2048, 256, 0, stream>>>(XC0, dtF, dAF, f_D, Y0,
                                      XC1, dtB, dAB, b_D, Y1, SBUF);
    k_gnorm<<<8192, 256, 0, stream>>>(Y0, Z0, f_gw, YG0, Y1, Z1, b_gw, YG1);
    // out-proj: M=4096, N=512, K=1024, 2 dirs -> 128x64 tiles, 512 blocks (2/CU)
    k_gemm12864<0><<<dim3(8, 32, 2), 256, 0, stream>>>(YG0, YG1, OWF, OWB, OP0, OP1, 512, 1024,
                                                       nullptr, nullptr, nullptr);
    k_add_rms<<<4096, 256, 0, stream>>>(x, OP0, OP1, mask, nfw, X2, X2B);
    // FFN1: M=4096, N=2048, K=512 -> 128x128 tiles, 512 blocks (2/CU)
    k_gemm128<1><<<dim3(16, 32, 1), 256, 0, stream>>>(X2B, X2B, W1B, W1B, HACT, HACT, 2048, 512,
                                                      b1, nullptr, nullptr);
    // FFN2: M=4096, N=512, K=2048 -> 64x64 tiles, 512 blocks (2/CU, high occupancy)
    k_gemm64<2><<<dim3(8, 64, 1), 256, 0, stream>>>(HACT, HACT, W2B, W2B, nullptr, nullptr,
                                                    512, 2048, b2, X2, out);
}

// Round 3
// 328.736 us; speedup vs baseline: 1.0422x; 1.0209x over previous
//
#include <hip/hip_runtime.h>
#include <hip/hip_bf16.h>

typedef unsigned short u16;
typedef unsigned int u32;
typedef __bf16 bf16x8 __attribute__((ext_vector_type(8)));
typedef float f32x4 __attribute__((ext_vector_type(4)));

typedef __attribute__((address_space(1))) void gvoid_t;
typedef __attribute__((address_space(3))) void lvoid_t;
__device__ __forceinline__ void lds_cp16(void* lds, const void* g) {
    __builtin_amdgcn_global_load_lds((gvoid_t*)g, (lvoid_t*)lds, 16, 0, 0);
}

__device__ __forceinline__ float bf2f(u16 v) {
    u32 x = (u32)v << 16;
    return __builtin_bit_cast(float, x);
}
__device__ __forceinline__ u16 f2bf(float f) {
    return __builtin_bit_cast(u16, (__bf16)f);
}

__device__ __forceinline__ float wave_sum(float v) {
    #pragma unroll
    for (int o = 32; o > 0; o >>= 1) v += __shfl_xor(v, o);
    return v;
}

__device__ __forceinline__ void cvt4(const float* __restrict__ s, u16* __restrict__ d) {
    float4 v = *(const float4*)s;
    ushort4 o;
    o.x = f2bf(v.x); o.y = f2bf(v.y); o.z = f2bf(v.z); o.w = f2bf(v.w);
    *(ushort4*)d = o;
}

// ---------------- fused: weight conversions (x4 vectorized) + rms_pos (wave/row) ----------------
__global__ __launch_bounds__(256) void k_prep(
    const float* __restrict__ f_inw, const float* __restrict__ b_inw,
    const float* __restrict__ f_ow, const float* __restrict__ b_ow,
    const float* __restrict__ w1, const float* __restrict__ w2,
    u16* __restrict__ INWF, u16* __restrict__ INWB,
    u16* __restrict__ OWF, u16* __restrict__ OWB,
    u16* __restrict__ W1B, u16* __restrict__ W2B,
    const float* __restrict__ x, const float* __restrict__ pe,
    const float* __restrict__ wrms, u16* __restrict__ sib) {
    if (blockIdx.x < 5376) {
        int g = blockIdx.x * 256 + threadIdx.x;
        if (g < 294912) {
            int i = g * 4, n = i >> 9;
            if (n < 2192) cvt4(f_inw + i, INWF + i);
            else *(ushort4*)(INWF + i) = make_ushort4(0, 0, 0, 0);
            return;
        }
        g -= 294912;
        if (g < 294912) {
            int i = g * 4, n = i >> 9;
            if (n < 2192) cvt4(b_inw + i, INWB + i);
            else *(ushort4*)(INWB + i) = make_ushort4(0, 0, 0, 0);
            return;
        }
        g -= 294912;
        if (g < 131072) { cvt4(f_ow + g * 4, OWF + g * 4); return; }
        g -= 131072;
        if (g < 131072) { cvt4(b_ow + g * 4, OWB + g * 4); return; }
        g -= 131072;
        if (g < 262144) { cvt4(w1 + g * 4, W1B + g * 4); return; }
        g -= 262144;
        cvt4(w2 + g * 4, W2B + g * 4);
        return;
    }
    // rms+pos: one wave per row of 512
    int row = (blockIdx.x - 5376) * 4 + (threadIdx.x >> 6);
    int lane = threadIdx.x & 63;
    size_t base = (size_t)row * 512 + lane * 4;
    float4 xa = *(const float4*)(x + base);
    float4 xb = *(const float4*)(x + base + 256);
    float ss = xa.x * xa.x + xa.y * xa.y + xa.z * xa.z + xa.w * xa.w
             + xb.x * xb.x + xb.y * xb.y + xb.z * xb.z + xb.w * xb.w;
    ss = wave_sum(ss);
    float sc = rsqrtf(ss * (1.f / 512.f) + 1.1920929e-07f);
    float4 pa = *(const float4*)(pe + base);
    float4 pb = *(const float4*)(pe + base + 256);
    float4 wa = *(const float4*)(wrms + lane * 4);
    float4 wb = *(const float4*)(wrms + lane * 4 + 256);
    ushort4 oa, obv;
    oa.x = f2bf(xa.x * sc * wa.x + pa.x);
    oa.y = f2bf(xa.y * sc * wa.y + pa.y);
    oa.z = f2bf(xa.z * sc * wa.z + pa.z);
    oa.w = f2bf(xa.w * sc * wa.w + pa.w);
    obv.x = f2bf(xb.x * sc * wb.x + pb.x);
    obv.y = f2bf(xb.y * sc * wb.y + pb.y);
    obv.z = f2bf(xb.z * sc * wb.z + pb.z);
    obv.w = f2bf(xb.w * sc * wb.w + pb.w);
    *(ushort4*)(sib + base) = oa;
    *(ushort4*)(sib + base + 256) = obv;
}

// ---------------- in_proj GEMM, BK=32, dbuf + both-sides LDS swizzle ----------------
__global__ __launch_bounds__(256) void k_gemm_in(
    const u16* __restrict__ A, const u16* __restrict__ W0, const u16* __restrict__ W1,
    u16* __restrict__ Z0, u16* __restrict__ Z1,
    u16* __restrict__ XB0, u16* __restrict__ XB1) {
    const int z = blockIdx.z;
    const u16* W = z ? W1 : W0;
    u16* Z = z ? Z1 : Z0;
    u16* XB = z ? XB1 : XB0;
    const int K = 512;

    __shared__ __align__(16) u16 As[2][128 * 32];
    __shared__ __align__(16) u16 Bs[2][128 * 32];

    const int t = threadIdx.x;
    const int lane = t & 63;
    const int w = t >> 6;
    const int m0 = blockIdx.y * 128;
    const int n0 = blockIdx.x * 128;
    const int wm = (w >> 1) * 64;
    const int wn = (w & 1) * 64;
    const int fr = lane & 15;
    // swizzled k-chunk for fragment reads: chunk = (lane>>4) ^ ((fr>>1)&3)
    const int ksw = (((lane >> 4) ^ ((fr >> 1) & 3)) & 3) * 8;

    f32x4 acc[4][4];
    #pragma unroll
    for (int i = 0; i < 4; ++i)
        #pragma unroll
        for (int j = 0; j < 4; ++j) acc[i][j] = (f32x4){0.f, 0.f, 0.f, 0.f};

    auto STAGE = [&](int buf, int kt) {
        #pragma unroll
        for (int j = 0; j < 2; ++j) {
            int off16 = j * 256 + t;
            int row = off16 >> 2;
            int kc = (((off16 & 3) ^ ((row >> 1) & 3)) & 3) * 8;  // inverse-swizzled source
            int gm = m0 + row;
            if (z) gm = (gm & ~2047) | (2047 - (gm & 2047));
            lds_cp16(As[buf] + off16 * 8, A + (size_t)gm * K + kt + kc);
            lds_cp16(Bs[buf] + off16 * 8, W + (size_t)(n0 + row) * K + kt + kc);
        }
    };

    STAGE(0, 0);
    __syncthreads();
    int cur = 0;
    for (int kt = 0; kt < K; kt += 32) {
        if (kt + 32 < K) STAGE(cur ^ 1, kt + 32);
        bf16x8 af[4], bfr[4];
        #pragma unroll
        for (int i = 0; i < 4; ++i) af[i] = *(const bf16x8*)(As[cur] + (wm + i * 16 + fr) * 32 + ksw);
        #pragma unroll
        for (int i = 0; i < 4; ++i) bfr[i] = *(const bf16x8*)(Bs[cur] + (wn + i * 16 + fr) * 32 + ksw);
        #pragma unroll
        for (int i = 0; i < 4; ++i)
            #pragma unroll
            for (int j = 0; j < 4; ++j)
                acc[i][j] = __builtin_amdgcn_mfma_f32_16x16x32_bf16(af[i], bfr[j], acc[i][j], 0, 0, 0);
        __syncthreads();
        cur ^= 1;
    }
    #pragma unroll
    for (int i = 0; i < 4; ++i) {
        int rbase = m0 + wm + i * 16 + (lane >> 4) * 4;
        #pragma unroll
        for (int j = 0; j < 4; ++j) {
            int c = n0 + wn + j * 16 + fr;
            #pragma unroll
            for (int r = 0; r < 4; ++r) {
                u16 v = f2bf(acc[i][j][r]);
                int m = rbase + r;
                if (c < 1024) Z[(size_t)m * 1024 + c] = v;
                else if (c < 2192) XB[(size_t)m * 1184 + (c - 1024)] = v;
            }
        }
    }
}

// ---------------- generic 128x128-tile GEMM, dbuf + swizzle ----------------
template <int EPI>
__global__ __launch_bounds__(256) void k_gemm128(
    const u16* __restrict__ A0, const u16* __restrict__ A1,
    const u16* __restrict__ W0, const u16* __restrict__ W1,
    u16* __restrict__ C0, u16* __restrict__ C1, int N, int K,
    const float* __restrict__ bias, const float* __restrict__ resid,
    float* __restrict__ outf) {
    const int z = blockIdx.z;
    const u16* A = z ? A1 : A0;
    const u16* W = z ? W1 : W0;
    u16* C = z ? C1 : C0;

    __shared__ __align__(16) u16 As[2][128 * 32];
    __shared__ __align__(16) u16 Bs[2][128 * 32];

    const int t = threadIdx.x;
    const int lane = t & 63;
    const int w = t >> 6;
    const int m0 = blockIdx.y * 128;
    const int n0 = blockIdx.x * 128;
    const int wm = (w >> 1) * 64;
    const int wn = (w & 1) * 64;
    const int fr = lane & 15;
    const int ksw = (((lane >> 4) ^ ((fr >> 1) & 3)) & 3) * 8;

    f32x4 acc[4][4];
    #pragma unroll
    for (int i = 0; i < 4; ++i)
        #pragma unroll
        for (int j = 0; j < 4; ++j) acc[i][j] = (f32x4){0.f, 0.f, 0.f, 0.f};

    auto STAGE = [&](int buf, int kt) {
        #pragma unroll
        for (int j = 0; j < 2; ++j) {
            int off16 = j * 256 + t;
            int row = off16 >> 2;
            int kc = (((off16 & 3) ^ ((row >> 1) & 3)) & 3) * 8;
            lds_cp16(As[buf] + off16 * 8, A + (size_t)(m0 + row) * K + kt + kc);
            lds_cp16(Bs[buf] + off16 * 8, W + (size_t)(n0 + row) * K + kt + kc);
        }
    };

    STAGE(0, 0);
    __syncthreads();
    int cur = 0;
    for (int kt = 0; kt < K; kt += 32) {
        if (kt + 32 < K) STAGE(cur ^ 1, kt + 32);
        bf16x8 af[4], bfr[4];
        #pragma unroll
        for (int i = 0; i < 4; ++i) af[i] = *(const bf16x8*)(As[cur] + (wm + i * 16 + fr) * 32 + ksw);
        #pragma unroll
        for (int i = 0; i < 4; ++i) bfr[i] = *(const bf16x8*)(Bs[cur] + (wn + i * 16 + fr) * 32 + ksw);
        #pragma unroll
        for (int i = 0; i < 4; ++i)
            #pragma unroll
            for (int j = 0; j < 4; ++j)
                acc[i][j] = __builtin_amdgcn_mfma_f32_16x16x32_bf16(af[i], bfr[j], acc[i][j], 0, 0, 0);
        __syncthreads();
        cur ^= 1;
    }
    #pragma unroll
    for (int i = 0; i < 4; ++i) {
        int rbase = m0 + wm + i * 16 + (lane >> 4) * 4;
        #pragma unroll
        for (int j = 0; j < 4; ++j) {
            int col = n0 + wn + j * 16 + fr;
            #pragma unroll
            for (int r = 0; r < 4; ++r) {
                int m = rbase + r;
                float v = acc[i][j][r];
                if (EPI == 0) {
                    C[(size_t)m * N + col] = f2bf(v);
                } else if (EPI == 1) {
                    float xg = v + bias[col];
                    C[(size_t)m * N + col] = f2bf(0.5f * xg * (1.f + erff(xg * 0.70710678118654752f)));
                } else {
                    outf[(size_t)m * N + col] = v + bias[col] + resid[(size_t)m * N + col];
                }
            }
        }
    }
}

// ---------------- 128x64-tile GEMM, dbuf + swizzle ----------------
template <int EPI>
__global__ __launch_bounds__(256) void k_gemm12864(
    const u16* __restrict__ A0, const u16* __restrict__ A1,
    const u16* __restrict__ W0, const u16* __restrict__ W1,
    u16* __restrict__ C0, u16* __restrict__ C1, int N, int K,
    const float* __restrict__ bias, const float* __restrict__ resid,
    float* __restrict__ outf) {
    const int z = blockIdx.z;
    const u16* A = z ? A1 : A0;
    const u16* W = z ? W1 : W0;
    u16* C = z ? C1 : C0;

    __shared__ __align__(16) u16 As[2][128 * 32];
    __shared__ __align__(16) u16 Bs[2][64 * 32];

    const int t = threadIdx.x;
    const int lane = t & 63;
    const int w = t >> 6;
    const int m0 = blockIdx.y * 128;
    const int n0 = blockIdx.x * 64;
    const int wm = w * 32;
    const int fr = lane & 15;
    const int ksw = (((lane >> 4) ^ ((fr >> 1) & 3)) & 3) * 8;

    f32x4 acc[2][4];
    #pragma unroll
    for (int i = 0; i < 2; ++i)
        #pragma unroll
        for (int j = 0; j < 4; ++j) acc[i][j] = (f32x4){0.f, 0.f, 0.f, 0.f};

    auto STAGE = [&](int buf, int kt) {
        #pragma unroll
        for (int j = 0; j < 2; ++j) {
            int off16 = j * 256 + t;
            int row = off16 >> 2;
            int kc = (((off16 & 3) ^ ((row >> 1) & 3)) & 3) * 8;
            lds_cp16(As[buf] + off16 * 8, A + (size_t)(m0 + row) * K + kt + kc);
        }
        int brow = t >> 2;
        int bkc = (((t & 3) ^ ((brow >> 1) & 3)) & 3) * 8;
        lds_cp16(Bs[buf] + t * 8, W + (size_t)(n0 + brow) * K + kt + bkc);
    };

    STAGE(0, 0);
    __syncthreads();
    int cur = 0;
    for (int kt = 0; kt < K; kt += 32) {
        if (kt + 32 < K) STAGE(cur ^ 1, kt + 32);
        bf16x8 af[2], bfr[4];
        #pragma unroll
        for (int i = 0; i < 2; ++i) af[i] = *(const bf16x8*)(As[cur] + (wm + i * 16 + fr) * 32 + ksw);
        #pragma unroll
        for (int j = 0; j < 4; ++j) bfr[j] = *(const bf16x8*)(Bs[cur] + (j * 16 + fr) * 32 + ksw);
        #pragma unroll
        for (int i = 0; i < 2; ++i)
            #pragma unroll
            for (int j = 0; j < 4; ++j)
                acc[i][j] = __builtin_amdgcn_mfma_f32_16x16x32_bf16(af[i], bfr[j], acc[i][j], 0, 0, 0);
        __syncthreads();
        cur ^= 1;
    }
    #pragma unroll
    for (int i = 0; i < 2; ++i) {
        int rbase = m0 + wm + i * 16 + (lane >> 4) * 4;
        #pragma unroll
        for (int j = 0; j < 4; ++j) {
            int col = n0 + j * 16 + fr;
            #pragma unroll
            for (int r = 0; r < 4; ++r) {
                int m = rbase + r;
                float v = acc[i][j][r];
                if (EPI == 0) {
                    C[(size_t)m * N + col] = f2bf(v);
                } else if (EPI == 1) {
                    float xg = v + bias[col];
                    C[(size_t)m * N + col] = f2bf(0.5f * xg * (1.f + erff(xg * 0.70710678118654752f)));
                } else {
                    outf[(size_t)m * N + col] = v + bias[col] + resid[(size_t)m * N + col];
                }
            }
        }
    }
}

// ---------------- 64x64-tile GEMM (high-occupancy), dbuf + swizzle ----------------
template <int EPI>
__global__ __launch_bounds__(256) void k_gemm64(
    const u16* __restrict__ A0, const u16* __restrict__ A1,
    const u16* __restrict__ W0, const u16* __restrict__ W1,
    u16* __restrict__ C0, u16* __restrict__ C1, int N, int K,
    const float* __restrict__ bias, const float* __restrict__ resid,
    float* __restrict__ outf) {
    const int z = blockIdx.z;
    const u16* A = z ? A1 : A0;
    const u16* W = z ? W1 : W0;
    u16* C = z ? C1 : C0;

    __shared__ __align__(16) u16 As[2][64 * 32];
    __shared__ __align__(16) u16 Bs[2][64 * 32];

    const int t = threadIdx.x;
    const int lane = t & 63;
    const int w = t >> 6;
    const int m0 = blockIdx.y * 64;
    const int n0 = blockIdx.x * 64;
    const int wm = (w >> 1) * 32;
    const int wn = (w & 1) * 32;
    const int fr = lane & 15;
    const int ksw = (((lane >> 4) ^ ((fr >> 1) & 3)) & 3) * 8;

    f32x4 acc[2][2];
    #pragma unroll
    for (int i = 0; i < 2; ++i)
        #pragma unroll
        for (int j = 0; j < 2; ++j) acc[i][j] = (f32x4){0.f, 0.f, 0.f, 0.f};

    const int srow = t >> 2;
    const int skc = (((t & 3) ^ ((srow >> 1) & 3)) & 3) * 8;
    auto STAGE = [&](int buf, int kt) {
        lds_cp16(As[buf] + t * 8, A + (size_t)(m0 + srow) * K + kt + skc);
        lds_cp16(Bs[buf] + t * 8, W + (size_t)(n0 + srow) * K + kt + skc);
    };

    STAGE(0, 0);
    __syncthreads();
    int cur = 0;
    for (int kt = 0; kt < K; kt += 32) {
        if (kt + 32 < K) STAGE(cur ^ 1, kt + 32);
        bf16x8 af[2], bfr[2];
        #pragma unroll
        for (int i = 0; i < 2; ++i) af[i] = *(const bf16x8*)(As[cur] + (wm + i * 16 + fr) * 32 + ksw);
        #pragma unroll
        for (int j = 0; j < 2; ++j) bfr[j] = *(const bf16x8*)(Bs[cur] + (wn + j * 16 + fr) * 32 + ksw);
        #pragma unroll
        for (int i = 0; i < 2; ++i)
            #pragma unroll
            for (int j = 0; j < 2; ++j)
                acc[i][j] = __builtin_amdgcn_mfma_f32_16x16x32_bf16(af[i], bfr[j], acc[i][j], 0, 0, 0);
        __syncthreads();
        cur ^= 1;
    }
    #pragma unroll
    for (int i = 0; i < 2; ++i) {
        int rbase = m0 + wm + i * 16 + (lane >> 4) * 4;
        #pragma unroll
        for (int j = 0; j < 2; ++j) {
            int col = n0 + wn + j * 16 + fr;
            #pragma unroll
            for (int r = 0; r < 4; ++r) {
                int m = rbase + r;
                float v = acc[i][j][r];
                if (EPI == 0) {
                    C[(size_t)m * N + col] = f2bf(v);
                } else if (EPI == 1) {
                    float xg = v + bias[col];
                    C[(size_t)m * N + col] = f2bf(0.5f * xg * (1.f + erff(xg * 0.70710678118654752f)));
                } else {
                    outf[(size_t)m * N + col] = v + bias[col] + resid[(size_t)m * N + col];
                }
            }
        }
    }
}

// ---------------- causal conv4 + silu, 8 rows/block sliding window ----------------
__global__ __launch_bounds__(160) void k_conv(
    const u16* __restrict__ xb0, const u16* __restrict__ xb1,
    const float* __restrict__ cw0, const float* __restrict__ cb0,
    const float* __restrict__ dtb0, const float* __restrict__ al0,
    const float* __restrict__ cw1, const float* __restrict__ cb1,
    const float* __restrict__ dtb1, const float* __restrict__ al1,
    u16* __restrict__ xc0, u16* __restrict__ xc1,
    float* __restrict__ dtO0, float* __restrict__ dAO0,
    float* __restrict__ dtO1, float* __restrict__ dAO1) {
    int g = blockIdx.x;
    int dir = g >> 9;
    int row0 = (g & 511) * 8;
    const u16* xb = dir ? xb1 : xb0;
    const float* cw = dir ? cw1 : cw0;
    const float* cb = dir ? cb1 : cb0;
    const float* dtb = dir ? dtb1 : dtb0;
    const float* al = dir ? al1 : al0;
    u16* xc = dir ? xc1 : xc0;
    float* dtO = dir ? dtO1 : dtO0;
    float* dAO = dir ? dAO1 : dAO0;
    int tl0 = row0 & 2047;
    int rbatch = row0 - tl0;
    int t = threadIdx.x;
    if (t < 144) {
        int col = t * 8;
        float cwa[8][4];
        #pragma unroll
        for (int j = 0; j < 8; ++j) {
            float4 c4 = *(const float4*)(cw + (col + j) * 4);
            cwa[j][0] = c4.x; cwa[j][1] = c4.y; cwa[j][2] = c4.z; cwa[j][3] = c4.w;
        }
        float cbv[8];
        float4 cb0v = *(const float4*)(cb + col);
        float4 cb1v = *(const float4*)(cb + col + 4);
        cbv[0] = cb0v.x; cbv[1] = cb0v.y; cbv[2] = cb0v.z; cbv[3] = cb0v.w;
        cbv[4] = cb1v.x; cbv[5] = cb1v.y; cbv[6] = cb1v.z; cbv[7] = cb1v.w;
        uint4 win[4];
        win[0] = win[1] = win[2] = make_uint4(0, 0, 0, 0);
        #pragma unroll
        for (int i = 0; i < 3; ++i) {
            int tt = tl0 - 3 + i;
            if (tt >= 0) win[i] = *(const uint4*)(xb + (size_t)(rbatch + tt) * 1184 + col);
        }
        for (int s = 0; s < 8; ++s) {
            win[3] = *(const uint4*)(xb + (size_t)(rbatch + tl0 + s) * 1184 + col);
            const u16* w0 = (const u16*)&win[0];
            const u16* w1 = (const u16*)&win[1];
            const u16* w2 = (const u16*)&win[2];
            const u16* w3 = (const u16*)&win[3];
            u16 ov[8];
            #pragma unroll
            for (int j = 0; j < 8; ++j) {
                float a = cbv[j] + bf2f(w0[j]) * cwa[j][0] + bf2f(w1[j]) * cwa[j][1]
                        + bf2f(w2[j]) * cwa[j][2] + bf2f(w3[j]) * cwa[j][3];
                ov[j] = f2bf(a / (1.f + expf(-a)));
            }
            *(uint4*)(xc + (size_t)(row0 + s) * 1152 + col) = *(const uint4*)ov;
            win[0] = win[1]; win[1] = win[2]; win[2] = win[3];
        }
    } else if (t < 160) {
        int hh = t - 144;
        float nal = -expf(al[hh]);
        float dtbv = dtb[hh];
        for (int s = 0; s < 8; ++s) {
            int row = row0 + s;
            float v = bf2f(xb[(size_t)row * 1184 + 1152 + hh]) + dtbv;
            float sp = (v > 20.f) ? v : log1pf(expf(v));
            dtO[row * 16 + hh] = sp;
            dAO[row * 16 + hh] = nal * sp;
        }
    }
}

// ======== SSD chunked scan ========
__global__ __launch_bounds__(256) void k_ssd_state(
    const u16* __restrict__ xc0, const float* __restrict__ dt0, const float* __restrict__ ld0,
    const u16* __restrict__ xc1, const float* __restrict__ dt1, const float* __restrict__ ld1,
    float* __restrict__ S, float* __restrict__ Aprod) {
    int blk = blockIdx.x;
    int c = blk & 31, h = (blk >> 5) & 15, b = (blk >> 9) & 1, dir = blk >> 10;
    const u16* xc = dir ? xc1 : xc0;
    const float* dtp = dir ? dt1 : dt0;
    const float* ldp = dir ? ld1 : ld0;
    const int t = threadIdx.x, w = t >> 6, lane = t & 63;
    const int fr = lane & 15, fk = (lane >> 4) * 8;

    __shared__ __align__(16) u16 sBt[64 * 72];
    __shared__ __align__(16) u16 sXp[64 * 72];
    __shared__ float ssc[64];
    size_t row0 = (size_t)b * 2048 + c * 64;

    if (t < 64) {
        float v = ldp[(row0 + t) * 16 + h];
        float dtv = dtp[(row0 + t) * 16 + h];
        #pragma unroll
        for (int o = 1; o < 64; o <<= 1) {
            float u = __shfl_up(v, o);
            if (lane >= o) v += u;
        }
        float last = __shfl(v, 63);
        ssc[t] = dtv * expf(last - v);
        if (t == 63) Aprod[blk] = expf(v);
    }
    __syncthreads();
    #pragma unroll
    for (int i2 = t; i2 < 512; i2 += 256) {
        int r = i2 >> 3, e8 = (i2 & 7) * 8;
        size_t rb = (row0 + r) * 1152;
        uint4 bv = *(const uint4*)(xc + rb + 1024 + e8);
        uint4 xv = *(const uint4*)(xc + rb + h * 64 + e8);
        const u16* bs = (const u16*)&bv;
        const u16* xs = (const u16*)&xv;
        float sc = ssc[r];
        #pragma unroll
        for (int j = 0; j < 8; ++j) {
            sBt[(e8 + j) * 72 + r] = bs[j];
            sXp[(e8 + j) * 72 + r] = f2bf(bf2f(xs[j]) * sc);
        }
    }
    __syncthreads();

    f32x4 acc[4];
    #pragma unroll
    for (int j = 0; j < 4; ++j) acc[j] = (f32x4){0.f, 0.f, 0.f, 0.f};
    #pragma unroll
    for (int k0 = 0; k0 < 64; k0 += 32) {
        bf16x8 a = *(const bf16x8*)(sBt + (w * 16 + fr) * 72 + k0 + fk);
        #pragma unroll
        for (int j = 0; j < 4; ++j) {
            bf16x8 bb = *(const bf16x8*)(sXp + (j * 16 + fr) * 72 + k0 + fk);
            acc[j] = __builtin_amdgcn_mfma_f32_16x16x32_bf16(a, bb, acc[j], 0, 0, 0);
        }
    }
    float* Sb = S + (size_t)blk * 4096;
    int nb = w * 16 + (lane >> 4) * 4;
    #pragma unroll
    for (int j = 0; j < 4; ++j) {
        int p = j * 16 + fr;
        *(f32x4*)(Sb + p * 64 + nb) = acc[j];
    }
}

// ---- Pass B: fully-parallel carry. grid 1024 = 64 blk-groups x 16; 1 element/thread ----
__global__ __launch_bounds__(256) void k_scan_carry(float* __restrict__ S,
                                                    const float* __restrict__ Aprod) {
    int g = blockIdx.x;
    int blk = g >> 4;
    int e = (g & 15) * 256 + threadIdx.x;
    size_t base = (size_t)blk * 32 * 4096 + e;
    float sv[32];
    #pragma unroll
    for (int c = 0; c < 32; ++c) sv[c] = S[base + (size_t)c * 4096];
    float ap[32];
    #pragma unroll
    for (int c = 0; c < 32; ++c) ap[c] = Aprod[blk * 32 + c];
    float h = 0.f;
    #pragma unroll
    for (int c = 0; c < 32; ++c) {
        S[base + (size_t)c * 4096] = h;
        h = ap[c] * h + sv[c];
    }
}

__global__ __launch_bounds__(256) void k_ssd_y(
    const u16* __restrict__ xc0, const float* __restrict__ dt0, const float* __restrict__ ld0,
    const float* __restrict__ Dv0, u16* __restrict__ y0,
    const u16* __restrict__ xc1, const float* __restrict__ dt1, const float* __restrict__ ld1,
    const float* __restrict__ Dv1, u16* __restrict__ y1,
    const float* __restrict__ S) {
    int blk = blockIdx.x;
    int c = blk & 31, h = (blk >> 5) & 15, b = (blk >> 9) & 1, dir = blk >> 10;
    const u16* xc = dir ? xc1 : xc0;
    const float* dtp = dir ? dt1 : dt0;
    const float* ldp = dir ? ld1 : ld0;
    u16* y = dir ? y1 : y0;
    const float Dh = (dir ? Dv1 : Dv0)[h];
    const int t = threadIdx.x, w = t >> 6, lane = t & 63;
    const int fr = lane & 15, fk = (lane >> 4) * 8;

    __shared__ __align__(16) u16 sB[64 * 72];
    __shared__ __align__(16) u16 sC[64 * 72];
    __shared__ __align__(16) u16 sXp[64 * 72];
    __shared__ __align__(16) u16 sHi[64 * 72];
    __shared__ __align__(16) u16 sLo[64 * 72];
    __shared__ __align__(16) u16 sGl[64 * 72];
    __shared__ float scl[64], sdt[64];
    size_t row0 = (size_t)b * 2048 + c * 64;

    if (t < 64) {
        float v = ldp[(row0 + t) * 16 + h];
        float dtv = dtp[(row0 + t) * 16 + h];
        #pragma unroll
        for (int o = 1; o < 64; o <<= 1) {
            float u = __shfl_up(v, o);
            if (lane >= o) v += u;
        }
        scl[t] = v;
        sdt[t] = dtv;
    }
    __syncthreads();
    #pragma unroll
    for (int i2 = t; i2 < 512; i2 += 256) {
        int r = i2 >> 3, e8 = (i2 & 7) * 8;
        size_t rb = (row0 + r) * 1152;
        *(uint4*)(sB + r * 72 + e8) = *(const uint4*)(xc + rb + 1024 + e8);
        *(uint4*)(sC + r * 72 + e8) = *(const uint4*)(xc + rb + 1088 + e8);
        uint4 xv = *(const uint4*)(xc + rb + h * 64 + e8);
        const u16* xs = (const u16*)&xv;
        float dtv = sdt[r];
        #pragma unroll
        for (int j = 0; j < 8; ++j) sXp[(e8 + j) * 72 + r] = f2bf(bf2f(xs[j]) * dtv);
    }
    #pragma unroll
    for (int i4 = t; i4 < 1024; i4 += 256) {
        int p = i4 >> 4, n4 = (i4 & 15) * 4;
        float4 hv = *(const float4*)(S + (size_t)blk * 4096 + p * 64 + n4);
        ushort4 hi4, lo4;
        hi4.x = f2bf(hv.x); lo4.x = f2bf(hv.x - bf2f(hi4.x));
        hi4.y = f2bf(hv.y); lo4.y = f2bf(hv.y - bf2f(hi4.y));
        hi4.z = f2bf(hv.z); lo4.z = f2bf(hv.z - bf2f(hi4.z));
        hi4.w = f2bf(hv.w); lo4.w = f2bf(hv.w - bf2f(hi4.w));
        *(ushort4*)(sHi + p * 72 + n4) = hi4;
        *(ushort4*)(sLo + p * 72 + n4) = lo4;
    }
    __syncthreads();

    f32x4 g[4], acc2[4];
    #pragma unroll
    for (int j = 0; j < 4; ++j) { g[j] = (f32x4){0.f,0.f,0.f,0.f}; acc2[j] = (f32x4){0.f,0.f,0.f,0.f}; }
    #pragma unroll
    for (int k0 = 0; k0 < 64; k0 += 32) {
        bf16x8 a = *(const bf16x8*)(sC + (w * 16 + fr) * 72 + k0 + fk);
        #pragma unroll
        for (int j = 0; j < 4; ++j) {
            bf16x8 bb = *(const bf16x8*)(sB + (j * 16 + fr) * 72 + k0 + fk);
            g[j] = __builtin_amdgcn_mfma_f32_16x16x32_bf16(a, bb, g[j], 0, 0, 0);
            bf16x8 bh = *(const bf16x8*)(sHi + (j * 16 + fr) * 72 + k0 + fk);
            acc2[j] = __builtin_amdgcn_mfma_f32_16x16x32_bf16(a, bh, acc2[j], 0, 0, 0);
            bf16x8 bl = *(const bf16x8*)(sLo + (j * 16 + fr) * 72 + k0 + fk);
            acc2[j] = __builtin_amdgcn_mfma_f32_16x16x32_bf16(a, bl, acc2[j], 0, 0, 0);
        }
    }
    #pragma unroll
    for (int j = 0; j < 4; ++j) {
        int r = j * 16 + fr;
        #pragma unroll
        for (int reg = 0; reg < 4; ++reg) {
            int s = w * 16 + (lane >> 4) * 4 + reg;
            float val = (r <= s) ? expf(scl[s] - scl[r]) * g[j][reg] : 0.f;
            sGl[s * 72 + r] = f2bf(val);
        }
    }
    __syncthreads();

    f32x4 acc1[4];
    #pragma unroll
    for (int j = 0; j < 4; ++j) acc1[j] = (f32x4){0.f, 0.f, 0.f, 0.f};
    #pragma unroll
    for (int k0 = 0; k0 < 64; k0 += 32) {
        bf16x8 a = *(const bf16x8*)(sGl + (w * 16 + fr) * 72 + k0 + fk);
        #pragma unroll
        for (int j = 0; j < 4; ++j) {
            bf16x8 bb = *(const bf16x8*)(sXp + (j * 16 + fr) * 72 + k0 + fk);
            acc1[j] = __builtin_amdgcn_mfma_f32_16x16x32_bf16(a, bb, acc1[j], 0, 0, 0);
        }
    }
    #pragma unroll
    for (int reg = 0; reg < 4; ++reg) {
        int s = w * 16 + (lane >> 4) * 4 + reg;
        float es = expf(scl[s]);
        size_t yrb = (row0 + s) * 1024 + h * 64;
        size_t xrb = (row0 + s) * 1152 + h * 64;
        #pragma unroll
        for (int j = 0; j < 4; ++j) {
            int p = j * 16 + fr;
            float xv = bf2f(xc[xrb + p]);
            y[yrb + p] = f2bf(acc1[j][reg] + es * acc2[j][reg] + xv * Dh);
        }
    }
}

// ---------------- gated RMS norm: one wave per row, no barriers ----------------
__global__ __launch_bounds__(256) void k_gnorm(
    const u16* __restrict__ y0, const u16* __restrict__ z0,
    const float* __restrict__ gw0, u16* __restrict__ o0,
    const u16* __restrict__ y1, const u16* __restrict__ z1,
    const float* __restrict__ gw1, u16* __restrict__ o1) {
    int idx = blockIdx.x * 4 + (threadIdx.x >> 6);
    int dir = idx >> 12, row = idx & 4095;
    int lane = threadIdx.x & 63;
    const u16* y = dir ? y1 : y0;
    const u16* zp = dir ? z1 : z0;
    const float* gw = dir ? gw1 : gw0;
    u16* o = dir ? o1 : o0;
    size_t base = (size_t)row * 1024 + lane * 8;
    uint4 ya = *(const uint4*)(y + base);
    uint4 yb = *(const uint4*)(y + base + 512);
    uint4 za = *(const uint4*)(zp + base);
    uint4 zb = *(const uint4*)(zp + base + 512);
    const u16* yap = (const u16*)&ya;
    const u16* ybp = (const u16*)&yb;
    const u16* zap = (const u16*)&za;
    const u16* zbp = (const u16*)&zb;
    float v[16];
    float ss = 0.f;
    #pragma unroll
    for (int j = 0; j < 8; ++j) {
        float zf = bf2f(zap[j]);
        v[j] = bf2f(yap[j]) * (zf / (1.f + expf(-zf)));
        ss += v[j] * v[j];
    }
    #pragma unroll
    for (int j = 0; j < 8; ++j) {
        float zf = bf2f(zbp[j]);
        v[8 + j] = bf2f(ybp[j]) * (zf / (1.f + expf(-zf)));
        ss += v[8 + j] * v[8 + j];
    }
    ss = wave_sum(ss);
    float sc = rsqrtf(ss * (1.f / 1024.f) + 1e-5f);
    float4 g0 = *(const float4*)(gw + lane * 8);
    float4 g1 = *(const float4*)(gw + lane * 8 + 4);
    float4 g2 = *(const float4*)(gw + 512 + lane * 8);
    float4 g3 = *(const float4*)(gw + 512 + lane * 8 + 4);
    const float* gp0 = (const float*)&g0;
    const float* gp1 = (const float*)&g1;
    const float* gp2 = (const float*)&g2;
    const float* gp3 = (const float*)&g3;
    u16 oa[8], obv[8];
    #pragma unroll
    for (int j = 0; j < 4; ++j) {
        oa[j] = f2bf(v[j] * sc * gp0[j]);
        oa[4 + j] = f2bf(v[4 + j] * sc * gp1[j]);
        obv[j] = f2bf(v[8 + j] * sc * gp2[j]);
        obv[4 + j] = f2bf(v[12 + j] * sc * gp3[j]);
    }
    *(uint4*)(o + base) = *(const uint4*)oa;
    *(uint4*)(o + base + 512) = *(const uint4*)obv;
}

// ---- fused: x2 = x + (fwd+flip(bwd))*mask; rms(x2)*nfw -> bf16. One wave per row ----
__global__ __launch_bounds__(256) void k_add_rms(
    const float* __restrict__ x, const u16* __restrict__ of,
    const u16* __restrict__ ob, const float* __restrict__ mask,
    const float* __restrict__ wrms,
    float* __restrict__ x2, u16* __restrict__ o) {
    int row = blockIdx.x * 4 + (threadIdx.x >> 6);
    int lane = threadIdx.x & 63;
    int bb = row >> 11, tl = row & 2047;
    size_t fb = (size_t)((bb << 11) + (2047 - tl)) * 512;
    float m = mask[row];
    size_t base = (size_t)row * 512 + lane * 4;
    size_t fo = fb + lane * 4;
    float4 xa = *(const float4*)(x + base);
    float4 xb = *(const float4*)(x + base + 256);
    ushort4 fa = *(const ushort4*)(of + base);
    ushort4 fbv = *(const ushort4*)(of + base + 256);
    ushort4 ba = *(const ushort4*)(ob + fo);
    ushort4 bbv = *(const ushort4*)(ob + fo + 256);
    float va[4], vb[4];
    va[0] = xa.x + (bf2f(fa.x) + bf2f(ba.x)) * m;
    va[1] = xa.y + (bf2f(fa.y) + bf2f(ba.y)) * m;
    va[2] = xa.z + (bf2f(fa.z) + bf2f(ba.z)) * m;
    va[3] = xa.w + (bf2f(fa.w) + bf2f(ba.w)) * m;
    vb[0] = xb.x + (bf2f(fbv.x) + bf2f(bbv.x)) * m;
    vb[1] = xb.y + (bf2f(fbv.y) + bf2f(bbv.y)) * m;
    vb[2] = xb.z + (bf2f(fbv.z) + bf2f(bbv.z)) * m;
    vb[3] = xb.w + (bf2f(fbv.w) + bf2f(bbv.w)) * m;
    *(float4*)(x2 + base) = (float4){va[0], va[1], va[2], va[3]};
    *(float4*)(x2 + base + 256) = (float4){vb[0], vb[1], vb[2], vb[3]};
    float ss = va[0]*va[0] + va[1]*va[1] + va[2]*va[2] + va[3]*va[3]
             + vb[0]*vb[0] + vb[1]*vb[1] + vb[2]*vb[2] + vb[3]*vb[3];
    ss = wave_sum(ss);
    float sc = rsqrtf(ss * (1.f / 512.f) + 1.1920929e-07f);
    float4 wa = *(const float4*)(wrms + lane * 4);
    float4 wb = *(const float4*)(wrms + lane * 4 + 256);
    ushort4 oa, obv;
    oa.x = f2bf(va[0] * sc * wa.x);
    oa.y = f2bf(va[1] * sc * wa.y);
    oa.z = f2bf(va[2] * sc * wa.z);
    oa.w = f2bf(va[3] * sc * wa.w);
    obv.x = f2bf(vb[0] * sc * wb.x);
    obv.y = f2bf(vb[1] * sc * wb.y);
    obv.z = f2bf(vb[2] * sc * wb.z);
    obv.w = f2bf(vb[3] * sc * wb.w);
    *(ushort4*)(o + base) = oa;
    *(ushort4*)(o + base + 256) = obv;
}

extern "C" void kernel_launch(void* const* d_in, const int* in_sizes, int n_in,
                              void* d_out, int out_size, void* d_ws, size_t ws_size,
                              hipStream_t stream) {
    const float* x = (const float*)d_in[0];
    const float* pe = (const float*)d_in[1];
    const float* mask = (const float*)d_in[2];
    const float* nsw = (const float*)d_in[3];
    const float* nfw = (const float*)d_in[4];
    const float* w1 = (const float*)d_in[5];
    const float* b1 = (const float*)d_in[6];
    const float* w2 = (const float*)d_in[7];
    const float* b2 = (const float*)d_in[8];
    const float* f_inw = (const float*)d_in[9];
    const float* f_cw = (const float*)d_in[10];
    const float* f_cb = (const float*)d_in[11];
    const float* f_dtb = (const float*)d_in[12];
    const float* f_al = (const float*)d_in[13];
    const float* f_D = (const float*)d_in[14];
    const float* f_gw = (const float*)d_in[15];
    const float* f_ow = (const float*)d_in[16];
    const float* b_inw = (const float*)d_in[17];
    const float* b_cw = (const float*)d_in[18];
    const float* b_cb = (const float*)d_in[19];
    const float* b_dtb = (const float*)d_in[20];
    const float* b_al = (const float*)d_in[21];
    const float* b_D = (const float*)d_in[22];
    const float* b_gw = (const float*)d_in[23];
    const float* b_ow = (const float*)d_in[24];
    float* out = (float*)d_out;

    char* ws = (char*)d_ws;
    u16* Z0   = (u16*)(ws + 0);
    u16* Z1   = (u16*)(ws + 8388608);
    u16* XB0  = (u16*)(ws + 16777216);
    u16* XB1  = (u16*)(ws + 26476544);
    u16* INWF = (u16*)(ws + 36175872);
    u16* INWB = (u16*)(ws + 38535168);
    u16* SIB  = (u16*)(ws + 40894464);
    u16* XC0  = (u16*)(ws + 36175872);
    u16* XC1  = (u16*)(ws + 45613056);
    float* dtF = (float*)(ws + 55050240);
    float* dAF = (float*)(ws + 55312384);
    float* dtB = (float*)(ws + 55574528);
    float* dAB = (float*)(ws + 55836672);
    u16* Y0   = (u16*)(ws + 16777216);
    u16* Y1   = (u16*)(ws + 25165824);
    u16* YG0  = (u16*)(ws + 36175872);
    u16* YG1  = (u16*)(ws + 44564480);
    u16* OP0  = (u16*)(ws + 0);
    u16* OP1  = (u16*)(ws + 4194304);
    float* X2 = (float*)(ws + 8388608);
    u16* X2B  = (u16*)(ws + 0);
    u16* HACT = (u16*)(ws + 16777216);
    u16* OWF = (u16*)(ws + 56098816);
    u16* OWB = (u16*)(ws + 57147392);
    u16* W1B = (u16*)(ws + 58195968);
    u16* W2B = (u16*)(ws + 60293120);
    float* SBUF = (float*)(ws + 62390272);
    float* APR  = (float*)(ws + 95944704);

    // weights: 1376256 groups of 4 -> 5376 blocks; rms: 4096 rows / 4 waves -> 1024 blocks
    k_prep<<<6400, 256, 0, stream>>>(f_inw, b_inw, f_ow, b_ow, w1, w2,
                                     INWF, INWB, OWF, OWB, W1B, W2B,
                                     x, pe, nsw, SIB);
    k_gemm_in<<<dim3(18, 32, 2), 256, 0, stream>>>(SIB, INWF, INWB, Z0, Z1, XB0, XB1);
    k_conv<<<1024, 160, 0, stream>>>(XB0, XB1, f_cw, f_cb, f_dtb, f_al,
                                     b_cw, b_cb, b_dtb, b_al,
                                     XC0, XC1, dtF, dAF, dtB, dAB);
    k_ssd_state<<<2048, 256, 0, stream>>>(XC0, dtF, dAF, XC1, dtB, dAB, SBUF, APR);
    k_scan_carry<<<1024, 256, 0, stream>>>(SBUF, APR);
    k_ssd_y<<<2048, 256, 0, stream>>>(XC0, dtF, dAF, f_D, Y0,
                                      XC1, dtB, dAB, b_D, Y1, SBUF);
    k_gnorm<<<2048, 256, 0, stream>>>(Y0, Z0, f_gw, YG0, Y1, Z1, b_gw, YG1);
    // out-proj: M=4096, N=512, K=1024, 2 dirs -> 128x64 tiles, 512 blocks (2/CU)
    k_gemm12864<0><<<dim3(8, 32, 2), 256, 0, stream>>>(YG0, YG1, OWF, OWB, OP0, OP1, 512, 1024,
                                                       nullptr, nullptr, nullptr);
    k_add_rms<<<1024, 256, 0, stream>>>(x, OP0, OP1, mask, nfw, X2, X2B);
    // FFN1: M=4096, N=2048, K=512 -> 128x128 tiles, 512 blocks (2/CU)
    k_gemm128<1><<<dim3(16, 32, 1), 256, 0, stream>>>(X2B, X2B, W1B, W1B, HACT, HACT, 2048, 512,
                                                      b1, nullptr, nullptr);
    // FFN2: M=4096, N=512, K=2048 -> 64x64 tiles, 512 blocks (2/CU, high occupancy)
    k_gemm64<2><<<dim3(8, 64, 1), 256, 0, stream>>>(HACT, HACT, W2B, W2B, nullptr, nullptr,
                                                    512, 2048, b2, X2, out);
}

// Round 4
// 327.005 us; speedup vs baseline: 1.0477x; 1.0053x over previous
//
#include <hip/hip_runtime.h>
#include <hip/hip_bf16.h>

typedef unsigned short u16;
typedef unsigned int u32;
typedef __bf16 bf16x8 __attribute__((ext_vector_type(8)));
typedef float f32x4 __attribute__((ext_vector_type(4)));

typedef __attribute__((address_space(1))) void gvoid_t;
typedef __attribute__((address_space(3))) void lvoid_t;
__device__ __forceinline__ void lds_cp16(void* lds, const void* g) {
    __builtin_amdgcn_global_load_lds((gvoid_t*)g, (lvoid_t*)lds, 16, 0, 0);
}

__device__ __forceinline__ float bf2f(u16 v) {
    u32 x = (u32)v << 16;
    return __builtin_bit_cast(float, x);
}
__device__ __forceinline__ u16 f2bf(float f) {
    return __builtin_bit_cast(u16, (__bf16)f);
}

__device__ __forceinline__ float wave_sum(float v) {
    #pragma unroll
    for (int o = 32; o > 0; o >>= 1) v += __shfl_xor(v, o);
    return v;
}

__device__ __forceinline__ void cvt4(const float* __restrict__ s, u16* __restrict__ d) {
    float4 v = *(const float4*)s;
    ushort4 o;
    o.x = f2bf(v.x); o.y = f2bf(v.y); o.z = f2bf(v.z); o.w = f2bf(v.w);
    *(ushort4*)d = o;
}

// ---------------- fused: weight conversions (x4 vectorized) + rms_pos (wave/row) ----------------
__global__ __launch_bounds__(256) void k_prep(
    const float* __restrict__ f_inw, const float* __restrict__ b_inw,
    const float* __restrict__ f_ow, const float* __restrict__ b_ow,
    const float* __restrict__ w1, const float* __restrict__ w2,
    u16* __restrict__ INWF, u16* __restrict__ INWB,
    u16* __restrict__ OWF, u16* __restrict__ OWB,
    u16* __restrict__ W1B, u16* __restrict__ W2B,
    const float* __restrict__ x, const float* __restrict__ pe,
    const float* __restrict__ wrms, u16* __restrict__ sib) {
    if (blockIdx.x < 5376) {
        int g = blockIdx.x * 256 + threadIdx.x;
        if (g < 294912) {
            int i = g * 4, n = i >> 9;
            if (n < 2192) cvt4(f_inw + i, INWF + i);
            else *(ushort4*)(INWF + i) = make_ushort4(0, 0, 0, 0);
            return;
        }
        g -= 294912;
        if (g < 294912) {
            int i = g * 4, n = i >> 9;
            if (n < 2192) cvt4(b_inw + i, INWB + i);
            else *(ushort4*)(INWB + i) = make_ushort4(0, 0, 0, 0);
            return;
        }
        g -= 294912;
        if (g < 131072) { cvt4(f_ow + g * 4, OWF + g * 4); return; }
        g -= 131072;
        if (g < 131072) { cvt4(b_ow + g * 4, OWB + g * 4); return; }
        g -= 131072;
        if (g < 262144) { cvt4(w1 + g * 4, W1B + g * 4); return; }
        g -= 262144;
        cvt4(w2 + g * 4, W2B + g * 4);
        return;
    }
    // rms+pos: one wave per row of 512
    int row = (blockIdx.x - 5376) * 4 + (threadIdx.x >> 6);
    int lane = threadIdx.x & 63;
    size_t base = (size_t)row * 512 + lane * 4;
    float4 xa = *(const float4*)(x + base);
    float4 xb = *(const float4*)(x + base + 256);
    float ss = xa.x * xa.x + xa.y * xa.y + xa.z * xa.z + xa.w * xa.w
             + xb.x * xb.x + xb.y * xb.y + xb.z * xb.z + xb.w * xb.w;
    ss = wave_sum(ss);
    float sc = rsqrtf(ss * (1.f / 512.f) + 1.1920929e-07f);
    float4 pa = *(const float4*)(pe + base);
    float4 pb = *(const float4*)(pe + base + 256);
    float4 wa = *(const float4*)(wrms + lane * 4);
    float4 wb = *(const float4*)(wrms + lane * 4 + 256);
    ushort4 oa, obv;
    oa.x = f2bf(xa.x * sc * wa.x + pa.x);
    oa.y = f2bf(xa.y * sc * wa.y + pa.y);
    oa.z = f2bf(xa.z * sc * wa.z + pa.z);
    oa.w = f2bf(xa.w * sc * wa.w + pa.w);
    obv.x = f2bf(xb.x * sc * wb.x + pb.x);
    obv.y = f2bf(xb.y * sc * wb.y + pb.y);
    obv.z = f2bf(xb.z * sc * wb.z + pb.z);
    obv.w = f2bf(xb.w * sc * wb.w + pb.w);
    *(ushort4*)(sib + base) = oa;
    *(ushort4*)(sib + base + 256) = obv;
}

// ---------------- in_proj GEMM, BK=32, 3-buf pipeline + counted vmcnt + swizzle ----------------
__global__ __launch_bounds__(256) void k_gemm_in(
    const u16* __restrict__ A, const u16* __restrict__ W0, const u16* __restrict__ W1,
    u16* __restrict__ Z0, u16* __restrict__ Z1,
    u16* __restrict__ XB0, u16* __restrict__ XB1) {
    const int z = blockIdx.z;
    const u16* W = z ? W1 : W0;
    u16* Z = z ? Z1 : Z0;
    u16* XB = z ? XB1 : XB0;
    const int K = 512;

    __shared__ __align__(16) u16 As[3][128 * 32];
    __shared__ __align__(16) u16 Bs[3][128 * 32];

    const int t = threadIdx.x;
    const int lane = t & 63;
    const int w = t >> 6;
    const int m0 = blockIdx.y * 128;
    const int n0 = blockIdx.x * 128;
    const int wm = (w >> 1) * 64;
    const int wn = (w & 1) * 64;
    const int fr = lane & 15;
    const int ksw = (((lane >> 4) ^ ((fr >> 1) & 3)) & 3) * 8;

    f32x4 acc[4][4];
    #pragma unroll
    for (int i = 0; i < 4; ++i)
        #pragma unroll
        for (int j = 0; j < 4; ++j) acc[i][j] = (f32x4){0.f, 0.f, 0.f, 0.f};

    auto STAGE = [&](int buf, int kt) {
        #pragma unroll
        for (int j = 0; j < 2; ++j) {
            int off16 = j * 256 + t;
            int row = off16 >> 2;
            int kc = (((off16 & 3) ^ ((row >> 1) & 3)) & 3) * 8;
            int gm = m0 + row;
            if (z) gm = (gm & ~2047) | (2047 - (gm & 2047));
            lds_cp16(As[buf] + off16 * 8, A + (size_t)gm * K + kt + kc);
            lds_cp16(Bs[buf] + off16 * 8, W + (size_t)(n0 + row) * K + kt + kc);
        }
    };

    const int NS = 16;  // K/32
    STAGE(0, 0);
    STAGE(1, 32);
    asm volatile("s_waitcnt vmcnt(4)" ::: "memory");
    __builtin_amdgcn_s_barrier();
    __builtin_amdgcn_sched_barrier(0);
    int b0 = 0, b1 = 1, b2 = 2;
    for (int i = 0; i < NS; ++i) {
        if (i + 2 < NS) STAGE(b2, (i + 2) << 5);
        const u16* Ac = As[b0];
        const u16* Bc = Bs[b0];
        bf16x8 af[4], bfr[4];
        #pragma unroll
        for (int ii = 0; ii < 4; ++ii) af[ii] = *(const bf16x8*)(Ac + (wm + ii * 16 + fr) * 32 + ksw);
        #pragma unroll
        for (int ii = 0; ii < 4; ++ii) bfr[ii] = *(const bf16x8*)(Bc + (wn + ii * 16 + fr) * 32 + ksw);
        #pragma unroll
        for (int ii = 0; ii < 4; ++ii)
            #pragma unroll
            for (int jj = 0; jj < 4; ++jj)
                acc[ii][jj] = __builtin_amdgcn_mfma_f32_16x16x32_bf16(af[ii], bfr[jj], acc[ii][jj], 0, 0, 0);
        if (i + 1 < NS) {
            if (i + 2 < NS) asm volatile("s_waitcnt vmcnt(4) lgkmcnt(0)" ::: "memory");
            else            asm volatile("s_waitcnt vmcnt(0) lgkmcnt(0)" ::: "memory");
            __builtin_amdgcn_s_barrier();
            __builtin_amdgcn_sched_barrier(0);
        }
        int bt = b0; b0 = b1; b1 = b2; b2 = bt;
    }
    if (n0 < 1024) {
        #pragma unroll
        for (int i = 0; i < 4; ++i) {
            int rbase = m0 + wm + i * 16 + (lane >> 4) * 4;
            #pragma unroll
            for (int j = 0; j < 4; ++j) {
                int c = n0 + wn + j * 16 + fr;
                #pragma unroll
                for (int r = 0; r < 4; ++r)
                    Z[(size_t)(rbase + r) * 1024 + c] = f2bf(acc[i][j][r]);
            }
        }
    } else {
        #pragma unroll
        for (int i = 0; i < 4; ++i) {
            int rbase = m0 + wm + i * 16 + (lane >> 4) * 4;
            #pragma unroll
            for (int j = 0; j < 4; ++j) {
                int cx = n0 - 1024 + wn + j * 16 + fr;
                if (cx < 1168) {
                    #pragma unroll
                    for (int r = 0; r < 4; ++r)
                        XB[(size_t)(rbase + r) * 1184 + cx] = f2bf(acc[i][j][r]);
                }
            }
        }
    }
}

// ---------------- generic 128x128-tile GEMM, 3-buf pipeline + counted vmcnt ----------------
// EPI 0: bf16 store; 1: gelu(acc+bias)->bf16; 2: f32 out = acc + bias + resid.
template <int EPI>
__global__ __launch_bounds__(256) void k_gemm128(
    const u16* __restrict__ A0, const u16* __restrict__ A1,
    const u16* __restrict__ W0, const u16* __restrict__ W1,
    u16* __restrict__ C0, u16* __restrict__ C1, int N, int K,
    const float* __restrict__ bias, const float* __restrict__ resid,
    float* __restrict__ outf) {
    const int z = blockIdx.z;
    const u16* A = z ? A1 : A0;
    const u16* W = z ? W1 : W0;
    u16* C = z ? C1 : C0;

    __shared__ __align__(16) u16 As[3][128 * 32];
    __shared__ __align__(16) u16 Bs[3][128 * 32];

    const int t = threadIdx.x;
    const int lane = t & 63;
    const int w = t >> 6;
    const int m0 = blockIdx.y * 128;
    const int n0 = blockIdx.x * 128;
    const int wm = (w >> 1) * 64;
    const int wn = (w & 1) * 64;
    const int fr = lane & 15;
    const int ksw = (((lane >> 4) ^ ((fr >> 1) & 3)) & 3) * 8;

    f32x4 acc[4][4];
    #pragma unroll
    for (int i = 0; i < 4; ++i)
        #pragma unroll
        for (int j = 0; j < 4; ++j) acc[i][j] = (f32x4){0.f, 0.f, 0.f, 0.f};

    auto STAGE = [&](int buf, int kt) {
        #pragma unroll
        for (int j = 0; j < 2; ++j) {
            int off16 = j * 256 + t;
            int row = off16 >> 2;
            int kc = (((off16 & 3) ^ ((row >> 1) & 3)) & 3) * 8;
            lds_cp16(As[buf] + off16 * 8, A + (size_t)(m0 + row) * K + kt + kc);
            lds_cp16(Bs[buf] + off16 * 8, W + (size_t)(n0 + row) * K + kt + kc);
        }
    };

    const int NS = K >> 5;
    STAGE(0, 0);
    STAGE(1, 32);
    asm volatile("s_waitcnt vmcnt(4)" ::: "memory");
    __builtin_amdgcn_s_barrier();
    __builtin_amdgcn_sched_barrier(0);
    int b0 = 0, b1 = 1, b2 = 2;
    for (int i = 0; i < NS; ++i) {
        if (i + 2 < NS) STAGE(b2, (i + 2) << 5);
        const u16* Ac = As[b0];
        const u16* Bc = Bs[b0];
        bf16x8 af[4], bfr[4];
        #pragma unroll
        for (int ii = 0; ii < 4; ++ii) af[ii] = *(const bf16x8*)(Ac + (wm + ii * 16 + fr) * 32 + ksw);
        #pragma unroll
        for (int ii = 0; ii < 4; ++ii) bfr[ii] = *(const bf16x8*)(Bc + (wn + ii * 16 + fr) * 32 + ksw);
        #pragma unroll
        for (int ii = 0; ii < 4; ++ii)
            #pragma unroll
            for (int jj = 0; jj < 4; ++jj)
                acc[ii][jj] = __builtin_amdgcn_mfma_f32_16x16x32_bf16(af[ii], bfr[jj], acc[ii][jj], 0, 0, 0);
        if (i + 1 < NS) {
            if (i + 2 < NS) asm volatile("s_waitcnt vmcnt(4) lgkmcnt(0)" ::: "memory");
            else            asm volatile("s_waitcnt vmcnt(0) lgkmcnt(0)" ::: "memory");
            __builtin_amdgcn_s_barrier();
            __builtin_amdgcn_sched_barrier(0);
        }
        int bt = b0; b0 = b1; b1 = b2; b2 = bt;
    }
    #pragma unroll
    for (int i = 0; i < 4; ++i) {
        int rbase = m0 + wm + i * 16 + (lane >> 4) * 4;
        #pragma unroll
        for (int j = 0; j < 4; ++j) {
            int col = n0 + wn + j * 16 + fr;
            #pragma unroll
            for (int r = 0; r < 4; ++r) {
                int m = rbase + r;
                float v = acc[i][j][r];
                if (EPI == 0) {
                    C[(size_t)m * N + col] = f2bf(v);
                } else if (EPI == 1) {
                    float xg = v + bias[col];
                    C[(size_t)m * N + col] = f2bf(0.5f * xg * (1.f + erff(xg * 0.70710678118654752f)));
                } else {
                    outf[(size_t)m * N + col] = v + bias[col] + resid[(size_t)m * N + col];
                }
            }
        }
    }
}

// ---------------- 128x64-tile GEMM, 3-buf pipeline + counted vmcnt ----------------
template <int EPI>
__global__ __launch_bounds__(256) void k_gemm12864(
    const u16* __restrict__ A0, const u16* __restrict__ A1,
    const u16* __restrict__ W0, const u16* __restrict__ W1,
    u16* __restrict__ C0, u16* __restrict__ C1, int N, int K,
    const float* __restrict__ bias, const float* __restrict__ resid,
    float* __restrict__ outf) {
    const int z = blockIdx.z;
    const u16* A = z ? A1 : A0;
    const u16* W = z ? W1 : W0;
    u16* C = z ? C1 : C0;

    __shared__ __align__(16) u16 As[3][128 * 32];
    __shared__ __align__(16) u16 Bs[3][64 * 32];

    const int t = threadIdx.x;
    const int lane = t & 63;
    const int w = t >> 6;
    const int m0 = blockIdx.y * 128;
    const int n0 = blockIdx.x * 64;
    const int wm = w * 32;
    const int fr = lane & 15;
    const int ksw = (((lane >> 4) ^ ((fr >> 1) & 3)) & 3) * 8;

    f32x4 acc[2][4];
    #pragma unroll
    for (int i = 0; i < 2; ++i)
        #pragma unroll
        for (int j = 0; j < 4; ++j) acc[i][j] = (f32x4){0.f, 0.f, 0.f, 0.f};

    auto STAGE = [&](int buf, int kt) {
        #pragma unroll
        for (int j = 0; j < 2; ++j) {
            int off16 = j * 256 + t;
            int row = off16 >> 2;
            int kc = (((off16 & 3) ^ ((row >> 1) & 3)) & 3) * 8;
            lds_cp16(As[buf] + off16 * 8, A + (size_t)(m0 + row) * K + kt + kc);
        }
        int brow = t >> 2;
        int bkc = (((t & 3) ^ ((brow >> 1) & 3)) & 3) * 8;
        lds_cp16(Bs[buf] + t * 8, W + (size_t)(n0 + brow) * K + kt + bkc);
    };

    const int NS = K >> 5;
    STAGE(0, 0);
    STAGE(1, 32);
    asm volatile("s_waitcnt vmcnt(3)" ::: "memory");
    __builtin_amdgcn_s_barrier();
    __builtin_amdgcn_sched_barrier(0);
    int b0 = 0, b1 = 1, b2 = 2;
    for (int i = 0; i < NS; ++i) {
        if (i + 2 < NS) STAGE(b2, (i + 2) << 5);
        const u16* Ac = As[b0];
        const u16* Bc = Bs[b0];
        bf16x8 af[2], bfr[4];
        #pragma unroll
        for (int ii = 0; ii < 2; ++ii) af[ii] = *(const bf16x8*)(Ac + (wm + ii * 16 + fr) * 32 + ksw);
        #pragma unroll
        for (int jj = 0; jj < 4; ++jj) bfr[jj] = *(const bf16x8*)(Bc + (jj * 16 + fr) * 32 + ksw);
        #pragma unroll
        for (int ii = 0; ii < 2; ++ii)
            #pragma unroll
            for (int jj = 0; jj < 4; ++jj)
                acc[ii][jj] = __builtin_amdgcn_mfma_f32_16x16x32_bf16(af[ii], bfr[jj], acc[ii][jj], 0, 0, 0);
        if (i + 1 < NS) {
            if (i + 2 < NS) asm volatile("s_waitcnt vmcnt(3) lgkmcnt(0)" ::: "memory");
            else            asm volatile("s_waitcnt vmcnt(0) lgkmcnt(0)" ::: "memory");
            __builtin_amdgcn_s_barrier();
            __builtin_amdgcn_sched_barrier(0);
        }
        int bt = b0; b0 = b1; b1 = b2; b2 = bt;
    }
    #pragma unroll
    for (int i = 0; i < 2; ++i) {
        int rbase = m0 + wm + i * 16 + (lane >> 4) * 4;
        #pragma unroll
        for (int j = 0; j < 4; ++j) {
            int col = n0 + j * 16 + fr;
            #pragma unroll
            for (int r = 0; r < 4; ++r) {
                int m = rbase + r;
                float v = acc[i][j][r];
                if (EPI == 0) {
                    C[(size_t)m * N + col] = f2bf(v);
                } else if (EPI == 1) {
                    float xg = v + bias[col];
                    C[(size_t)m * N + col] = f2bf(0.5f * xg * (1.f + erff(xg * 0.70710678118654752f)));
                } else {
                    outf[(size_t)m * N + col] = v + bias[col] + resid[(size_t)m * N + col];
                }
            }
        }
    }
}

// ---------------- 64x64-tile GEMM (high-occupancy), 3-buf pipeline + counted vmcnt ----------------
template <int EPI>
__global__ __launch_bounds__(256) void k_gemm64(
    const u16* __restrict__ A0, const u16* __restrict__ A1,
    const u16* __restrict__ W0, const u16* __restrict__ W1,
    u16* __restrict__ C0, u16* __restrict__ C1, int N, int K,
    const float* __restrict__ bias, const float* __restrict__ resid,
    float* __restrict__ outf) {
    const int z = blockIdx.z;
    const u16* A = z ? A1 : A0;
    const u16* W = z ? W1 : W0;
    u16* C = z ? C1 : C0;

    __shared__ __align__(16) u16 As[3][64 * 32];
    __shared__ __align__(16) u16 Bs[3][64 * 32];

    const int t = threadIdx.x;
    const int lane = t & 63;
    const int w = t >> 6;
    const int m0 = blockIdx.y * 64;
    const int n0 = blockIdx.x * 64;
    const int wm = (w >> 1) * 32;
    const int wn = (w & 1) * 32;
    const int fr = lane & 15;
    const int ksw = (((lane >> 4) ^ ((fr >> 1) & 3)) & 3) * 8;

    f32x4 acc[2][2];
    #pragma unroll
    for (int i = 0; i < 2; ++i)
        #pragma unroll
        for (int j = 0; j < 2; ++j) acc[i][j] = (f32x4){0.f, 0.f, 0.f, 0.f};

    const int srow = t >> 2;
    const int skc = (((t & 3) ^ ((srow >> 1) & 3)) & 3) * 8;
    auto STAGE = [&](int buf, int kt) {
        lds_cp16(As[buf] + t * 8, A + (size_t)(m0 + srow) * K + kt + skc);
        lds_cp16(Bs[buf] + t * 8, W + (size_t)(n0 + srow) * K + kt + skc);
    };

    const int NS = K >> 5;
    STAGE(0, 0);
    STAGE(1, 32);
    asm volatile("s_waitcnt vmcnt(2)" ::: "memory");
    __builtin_amdgcn_s_barrier();
    __builtin_amdgcn_sched_barrier(0);
    int b0 = 0, b1 = 1, b2 = 2;
    for (int i = 0; i < NS; ++i) {
        if (i + 2 < NS) STAGE(b2, (i + 2) << 5);
        const u16* Ac = As[b0];
        const u16* Bc = Bs[b0];
        bf16x8 af[2], bfr[2];
        #pragma unroll
        for (int ii = 0; ii < 2; ++ii) af[ii] = *(const bf16x8*)(Ac + (wm + ii * 16 + fr) * 32 + ksw);
        #pragma unroll
        for (int jj = 0; jj < 2; ++jj) bfr[jj] = *(const bf16x8*)(Bc + (wn + jj * 16 + fr) * 32 + ksw);
        #pragma unroll
        for (int ii = 0; ii < 2; ++ii)
            #pragma unroll
            for (int jj = 0; jj < 2; ++jj)
                acc[ii][jj] = __builtin_amdgcn_mfma_f32_16x16x32_bf16(af[ii], bfr[jj], acc[ii][jj], 0, 0, 0);
        if (i + 1 < NS) {
            if (i + 2 < NS) asm volatile("s_waitcnt vmcnt(2) lgkmcnt(0)" ::: "memory");
            else            asm volatile("s_waitcnt vmcnt(0) lgkmcnt(0)" ::: "memory");
            __builtin_amdgcn_s_barrier();
            __builtin_amdgcn_sched_barrier(0);
        }
        int bt = b0; b0 = b1; b1 = b2; b2 = bt;
    }
    #pragma unroll
    for (int i = 0; i < 2; ++i) {
        int rbase = m0 + wm + i * 16 + (lane >> 4) * 4;
        #pragma unroll
        for (int j = 0; j < 2; ++j) {
            int col = n0 + wn + j * 16 + fr;
            #pragma unroll
            for (int r = 0; r < 4; ++r) {
                int m = rbase + r;
                float v = acc[i][j][r];
                if (EPI == 0) {
                    C[(size_t)m * N + col] = f2bf(v);
                } else if (EPI == 1) {
                    float xg = v + bias[col];
                    C[(size_t)m * N + col] = f2bf(0.5f * xg * (1.f + erff(xg * 0.70710678118654752f)));
                } else {
                    outf[(size_t)m * N + col] = v + bias[col] + resid[(size_t)m * N + col];
                }
            }
        }
    }
}

// ---------------- causal conv4 + silu, 8 rows/block sliding window ----------------
__global__ __launch_bounds__(160) void k_conv(
    const u16* __restrict__ xb0, const u16* __restrict__ xb1,
    const float* __restrict__ cw0, const float* __restrict__ cb0,
    const float* __restrict__ dtb0, const float* __restrict__ al0,
    const float* __restrict__ cw1, const float* __restrict__ cb1,
    const float* __restrict__ dtb1, const float* __restrict__ al1,
    u16* __restrict__ xc0, u16* __restrict__ xc1,
    float* __restrict__ dtO0, float* __restrict__ dAO0,
    float* __restrict__ dtO1, float* __restrict__ dAO1) {
    int g = blockIdx.x;
    int dir = g >> 9;
    int row0 = (g & 511) * 8;
    const u16* xb = dir ? xb1 : xb0;
    const float* cw = dir ? cw1 : cw0;
    const float* cb = dir ? cb1 : cb0;
    const float* dtb = dir ? dtb1 : dtb0;
    const float* al = dir ? al1 : al0;
    u16* xc = dir ? xc1 : xc0;
    float* dtO = dir ? dtO1 : dtO0;
    float* dAO = dir ? dAO1 : dAO0;
    int tl0 = row0 & 2047;
    int rbatch = row0 - tl0;
    int t = threadIdx.x;
    if (t < 144) {
        int col = t * 8;
        float cwa[8][4];
        #pragma unroll
        for (int j = 0; j < 8; ++j) {
            float4 c4 = *(const float4*)(cw + (col + j) * 4);
            cwa[j][0] = c4.x; cwa[j][1] = c4.y; cwa[j][2] = c4.z; cwa[j][3] = c4.w;
        }
        float cbv[8];
        float4 cb0v = *(const float4*)(cb + col);
        float4 cb1v = *(const float4*)(cb + col + 4);
        cbv[0] = cb0v.x; cbv[1] = cb0v.y; cbv[2] = cb0v.z; cbv[3] = cb0v.w;
        cbv[4] = cb1v.x; cbv[5] = cb1v.y; cbv[6] = cb1v.z; cbv[7] = cb1v.w;
        uint4 win[4];
        win[0] = win[1] = win[2] = make_uint4(0, 0, 0, 0);
        #pragma unroll
        for (int i = 0; i < 3; ++i) {
            int tt = tl0 - 3 + i;
            if (tt >= 0) win[i] = *(const uint4*)(xb + (size_t)(rbatch + tt) * 1184 + col);
        }
        for (int s = 0; s < 8; ++s) {
            win[3] = *(const uint4*)(xb + (size_t)(rbatch + tl0 + s) * 1184 + col);
            const u16* w0 = (const u16*)&win[0];
            const u16* w1 = (const u16*)&win[1];
            const u16* w2 = (const u16*)&win[2];
            const u16* w3 = (const u16*)&win[3];
            u16 ov[8];
            #pragma unroll
            for (int j = 0; j < 8; ++j) {
                float a = cbv[j] + bf2f(w0[j]) * cwa[j][0] + bf2f(w1[j]) * cwa[j][1]
                        + bf2f(w2[j]) * cwa[j][2] + bf2f(w3[j]) * cwa[j][3];
                ov[j] = f2bf(a / (1.f + expf(-a)));
            }
            *(uint4*)(xc + (size_t)(row0 + s) * 1152 + col) = *(const uint4*)ov;
            win[0] = win[1]; win[1] = win[2]; win[2] = win[3];
        }
    } else if (t < 160) {
        int hh = t - 144;
        float nal = -expf(al[hh]);
        float dtbv = dtb[hh];
        for (int s = 0; s < 8; ++s) {
            int row = row0 + s;
            float v = bf2f(xb[(size_t)row * 1184 + 1152 + hh]) + dtbv;
            float sp = (v > 20.f) ? v : log1pf(expf(v));
            dtO[row * 16 + hh] = sp;
            dAO[row * 16 + hh] = nal * sp;
        }
    }
}

// ======== SSD chunked scan ========
__global__ __launch_bounds__(256) void k_ssd_state(
    const u16* __restrict__ xc0, const float* __restrict__ dt0, const float* __restrict__ ld0,
    const u16* __restrict__ xc1, const float* __restrict__ dt1, const float* __restrict__ ld1,
    float* __restrict__ S, float* __restrict__ Aprod) {
    int blk = blockIdx.x;
    int c = blk & 31, h = (blk >> 5) & 15, b = (blk >> 9) & 1, dir = blk >> 10;
    const u16* xc = dir ? xc1 : xc0;
    const float* dtp = dir ? dt1 : dt0;
    const float* ldp = dir ? ld1 : ld0;
    const int t = threadIdx.x, w = t >> 6, lane = t & 63;
    const int fr = lane & 15, fk = (lane >> 4) * 8;

    __shared__ __align__(16) u16 sBt[64 * 72];
    __shared__ __align__(16) u16 sXp[64 * 72];
    __shared__ float ssc[64];
    size_t row0 = (size_t)b * 2048 + c * 64;

    if (t < 64) {
        float v = ldp[(row0 + t) * 16 + h];
        float dtv = dtp[(row0 + t) * 16 + h];
        #pragma unroll
        for (int o = 1; o < 64; o <<= 1) {
            float u = __shfl_up(v, o);
            if (lane >= o) v += u;
        }
        float last = __shfl(v, 63);
        ssc[t] = dtv * expf(last - v);
        if (t == 63) Aprod[blk] = expf(v);
    }
    __syncthreads();
    #pragma unroll
    for (int i2 = t; i2 < 512; i2 += 256) {
        int r = i2 >> 3, e8 = (i2 & 7) * 8;
        size_t rb = (row0 + r) * 1152;
        uint4 bv = *(const uint4*)(xc + rb + 1024 + e8);
        uint4 xv = *(const uint4*)(xc + rb + h * 64 + e8);
        const u16* bs = (const u16*)&bv;
        const u16* xs = (const u16*)&xv;
        float sc = ssc[r];
        #pragma unroll
        for (int j = 0; j < 8; ++j) {
            sBt[(e8 + j) * 72 + r] = bs[j];
            sXp[(e8 + j) * 72 + r] = f2bf(bf2f(xs[j]) * sc);
        }
    }
    __syncthreads();

    f32x4 acc[4];
    #pragma unroll
    for (int j = 0; j < 4; ++j) acc[j] = (f32x4){0.f, 0.f, 0.f, 0.f};
    #pragma unroll
    for (int k0 = 0; k0 < 64; k0 += 32) {
        bf16x8 a = *(const bf16x8*)(sBt + (w * 16 + fr) * 72 + k0 + fk);
        #pragma unroll
        for (int j = 0; j < 4; ++j) {
            bf16x8 bb = *(const bf16x8*)(sXp + (j * 16 + fr) * 72 + k0 + fk);
            acc[j] = __builtin_amdgcn_mfma_f32_16x16x32_bf16(a, bb, acc[j], 0, 0, 0);
        }
    }
    float* Sb = S + (size_t)blk * 4096;
    int nb = w * 16 + (lane >> 4) * 4;
    #pragma unroll
    for (int j = 0; j < 4; ++j) {
        int p = j * 16 + fr;
        *(f32x4*)(Sb + p * 64 + nb) = acc[j];
    }
}

// ---- Pass B: fully-parallel carry. grid 1024 = 64 blk-groups x 16; 1 element/thread ----
__global__ __launch_bounds__(256) void k_scan_carry(float* __restrict__ S,
                                                    const float* __restrict__ Aprod) {
    int g = blockIdx.x;
    int blk = g >> 4;
    int e = (g & 15) * 256 + threadIdx.x;
    size_t base = (size_t)blk * 32 * 4096 + e;
    float sv[32];
    #pragma unroll
    for (int c = 0; c < 32; ++c) sv[c] = S[base + (size_t)c * 4096];
    float ap[32];
    #pragma unroll
    for (int c = 0; c < 32; ++c) ap[c] = Aprod[blk * 32 + c];
    float h = 0.f;
    #pragma unroll
    for (int c = 0; c < 32; ++c) {
        S[base + (size_t)c * 4096] = h;
        h = ap[c] * h + sv[c];
    }
}

__global__ __launch_bounds__(256) void k_ssd_y(
    const u16* __restrict__ xc0, const float* __restrict__ dt0, const float* __restrict__ ld0,
    const float* __restrict__ Dv0, u16* __restrict__ y0,
    const u16* __restrict__ xc1, const float* __restrict__ dt1, const float* __restrict__ ld1,
    const float* __restrict__ Dv1, u16* __restrict__ y1,
    const float* __restrict__ S) {
    int blk = blockIdx.x;
    int c = blk & 31, h = (blk >> 5) & 15, b = (blk >> 9) & 1, dir = blk >> 10;
    const u16* xc = dir ? xc1 : xc0;
    const float* dtp = dir ? dt1 : dt0;
    const float* ldp = dir ? ld1 : ld0;
    u16* y = dir ? y1 : y0;
    const float Dh = (dir ? Dv1 : Dv0)[h];
    const int t = threadIdx.x, w = t >> 6, lane = t & 63;
    const int fr = lane & 15, fk = (lane >> 4) * 8;

    __shared__ __align__(16) u16 sB[64 * 72];
    __shared__ __align__(16) u16 sC[64 * 72];
    __shared__ __align__(16) u16 sXp[64 * 72];
    __shared__ __align__(16) u16 sHi[64 * 72];
    __shared__ __align__(16) u16 sLo[64 * 72];
    __shared__ __align__(16) u16 sGl[64 * 72];
    __shared__ float scl[64], sdt[64];
    size_t row0 = (size_t)b * 2048 + c * 64;

    if (t < 64) {
        float v = ldp[(row0 + t) * 16 + h];
        float dtv = dtp[(row0 + t) * 16 + h];
        #pragma unroll
        for (int o = 1; o < 64; o <<= 1) {
            float u = __shfl_up(v, o);
            if (lane >= o) v += u;
        }
        scl[t] = v;
        sdt[t] = dtv;
    }
    __syncthreads();
    #pragma unroll
    for (int i2 = t; i2 < 512; i2 += 256) {
        int r = i2 >> 3, e8 = (i2 & 7) * 8;
        size_t rb = (row0 + r) * 1152;
        *(uint4*)(sB + r * 72 + e8) = *(const uint4*)(xc + rb + 1024 + e8);
        *(uint4*)(sC + r * 72 + e8) = *(const uint4*)(xc + rb + 1088 + e8);
        uint4 xv = *(const uint4*)(xc + rb + h * 64 + e8);
        const u16* xs = (const u16*)&xv;
        float dtv = sdt[r];
        #pragma unroll
        for (int j = 0; j < 8; ++j) sXp[(e8 + j) * 72 + r] = f2bf(bf2f(xs[j]) * dtv);
    }
    #pragma unroll
    for (int i4 = t; i4 < 1024; i4 += 256) {
        int p = i4 >> 4, n4 = (i4 & 15) * 4;
        float4 hv = *(const float4*)(S + (size_t)blk * 4096 + p * 64 + n4);
        ushort4 hi4, lo4;
        hi4.x = f2bf(hv.x); lo4.x = f2bf(hv.x - bf2f(hi4.x));
        hi4.y = f2bf(hv.y); lo4.y = f2bf(hv.y - bf2f(hi4.y));
        hi4.z = f2bf(hv.z); lo4.z = f2bf(hv.z - bf2f(hi4.z));
        hi4.w = f2bf(hv.w); lo4.w = f2bf(hv.w - bf2f(hi4.w));
        *(ushort4*)(sHi + p * 72 + n4) = hi4;
        *(ushort4*)(sLo + p * 72 + n4) = lo4;
    }
    __syncthreads();

    f32x4 g[4], acc2[4];
    #pragma unroll
    for (int j = 0; j < 4; ++j) { g[j] = (f32x4){0.f,0.f,0.f,0.f}; acc2[j] = (f32x4){0.f,0.f,0.f,0.f}; }
    #pragma unroll
    for (int k0 = 0; k0 < 64; k0 += 32) {
        bf16x8 a = *(const bf16x8*)(sC + (w * 16 + fr) * 72 + k0 + fk);
        #pragma unroll
        for (int j = 0; j < 4; ++j) {
            bf16x8 bb = *(const bf16x8*)(sB + (j * 16 + fr) * 72 + k0 + fk);
            g[j] = __builtin_amdgcn_mfma_f32_16x16x32_bf16(a, bb, g[j], 0, 0, 0);
            bf16x8 bh = *(const bf16x8*)(sHi + (j * 16 + fr) * 72 + k0 + fk);
            acc2[j] = __builtin_amdgcn_mfma_f32_16x16x32_bf16(a, bh, acc2[j], 0, 0, 0);
            bf16x8 bl = *(const bf16x8*)(sLo + (j * 16 + fr) * 72 + k0 + fk);
            acc2[j] = __builtin_amdgcn_mfma_f32_16x16x32_bf16(a, bl, acc2[j], 0, 0, 0);
        }
    }
    #pragma unroll
    for (int j = 0; j < 4; ++j) {
        int r = j * 16 + fr;
        #pragma unroll
        for (int reg = 0; reg < 4; ++reg) {
            int s = w * 16 + (lane >> 4) * 4 + reg;
            float val = (r <= s) ? expf(scl[s] - scl[r]) * g[j][reg] : 0.f;
            sGl[s * 72 + r] = f2bf(val);
        }
    }
    __syncthreads();

    f32x4 acc1[4];
    #pragma unroll
    for (int j = 0; j < 4; ++j) acc1[j] = (f32x4){0.f, 0.f, 0.f, 0.f};
    #pragma unroll
    for (int k0 = 0; k0 < 64; k0 += 32) {
        bf16x8 a = *(const bf16x8*)(sGl + (w * 16 + fr) * 72 + k0 + fk);
        #pragma unroll
        for (int j = 0; j < 4; ++j) {
            bf16x8 bb = *(const bf16x8*)(sXp + (j * 16 + fr) * 72 + k0 + fk);
            acc1[j] = __builtin_amdgcn_mfma_f32_16x16x32_bf16(a, bb, acc1[j], 0, 0, 0);
        }
    }
    #pragma unroll
    for (int reg = 0; reg < 4; ++reg) {
        int s = w * 16 + (lane >> 4) * 4 + reg;
        float es = expf(scl[s]);
        size_t yrb = (row0 + s) * 1024 + h * 64;
        size_t xrb = (row0 + s) * 1152 + h * 64;
        #pragma unroll
        for (int j = 0; j < 4; ++j) {
            int p = j * 16 + fr;
            float xv = bf2f(xc[xrb + p]);
            y[yrb + p] = f2bf(acc1[j][reg] + es * acc2[j][reg] + xv * Dh);
        }
    }
}

// ---------------- gated RMS norm: one wave per row, no barriers ----------------
__global__ __launch_bounds__(256) void k_gnorm(
    const u16* __restrict__ y0, const u16* __restrict__ z0,
    const float* __restrict__ gw0, u16* __restrict__ o0,
    const u16* __restrict__ y1, const u16* __restrict__ z1,
    const float* __restrict__ gw1, u16* __restrict__ o1) {
    int idx = blockIdx.x * 4 + (threadIdx.x >> 6);
    int dir = idx >> 12, row = idx & 4095;
    int lane = threadIdx.x & 63;
    const u16* y = dir ? y1 : y0;
    const u16* zp = dir ? z1 : z0;
    const float* gw = dir ? gw1 : gw0;
    u16* o = dir ? o1 : o0;
    size_t base = (size_t)row * 1024 + lane * 8;
    uint4 ya = *(const uint4*)(y + base);
    uint4 yb = *(const uint4*)(y + base + 512);
    uint4 za = *(const uint4*)(zp + base);
    uint4 zb = *(const uint4*)(zp + base + 512);
    const u16* yap = (const u16*)&ya;
    const u16* ybp = (const u16*)&yb;
    const u16* zap = (const u16*)&za;
    const u16* zbp = (const u16*)&zb;
    float v[16];
    float ss = 0.f;
    #pragma unroll
    for (int j = 0; j < 8; ++j) {
        float zf = bf2f(zap[j]);
        v[j] = bf2f(yap[j]) * (zf / (1.f + expf(-zf)));
        ss += v[j] * v[j];
    }
    #pragma unroll
    for (int j = 0; j < 8; ++j) {
        float zf = bf2f(zbp[j]);
        v[8 + j] = bf2f(ybp[j]) * (zf / (1.f + expf(-zf)));
        ss += v[8 + j] * v[8 + j];
    }
    ss = wave_sum(ss);
    float sc = rsqrtf(ss * (1.f / 1024.f) + 1e-5f);
    float4 g0 = *(const float4*)(gw + lane * 8);
    float4 g1 = *(const float4*)(gw + lane * 8 + 4);
    float4 g2 = *(const float4*)(gw + 512 + lane * 8);
    float4 g3 = *(const float4*)(gw + 512 + lane * 8 + 4);
    const float* gp0 = (const float*)&g0;
    const float* gp1 = (const float*)&g1;
    const float* gp2 = (const float*)&g2;
    const float* gp3 = (const float*)&g3;
    u16 oa[8], obv[8];
    #pragma unroll
    for (int j = 0; j < 4; ++j) {
        oa[j] = f2bf(v[j] * sc * gp0[j]);
        oa[4 + j] = f2bf(v[4 + j] * sc * gp1[j]);
        obv[j] = f2bf(v[8 + j] * sc * gp2[j]);
        obv[4 + j] = f2bf(v[12 + j] * sc * gp3[j]);
    }
    *(uint4*)(o + base) = *(const uint4*)oa;
    *(uint4*)(o + base + 512) = *(const uint4*)obv;
}

// ---- fused: x2 = x + (fwd+flip(bwd))*mask; rms(x2)*nfw -> bf16. One wave per row ----
__global__ __launch_bounds__(256) void k_add_rms(
    const float* __restrict__ x, const u16* __restrict__ of,
    const u16* __restrict__ ob, const float* __restrict__ mask,
    const float* __restrict__ wrms,
    float* __restrict__ x2, u16* __restrict__ o) {
    int row = blockIdx.x * 4 + (threadIdx.x >> 6);
    int lane = threadIdx.x & 63;
    int bb = row >> 11, tl = row & 2047;
    size_t fb = (size_t)((bb << 11) + (2047 - tl)) * 512;
    float m = mask[row];
    size_t base = (size_t)row * 512 + lane * 4;
    size_t fo = fb + lane * 4;
    float4 xa = *(const float4*)(x + base);
    float4 xb = *(const float4*)(x + base + 256);
    ushort4 fa = *(const ushort4*)(of + base);
    ushort4 fbv = *(const ushort4*)(of + base + 256);
    ushort4 ba = *(const ushort4*)(ob + fo);
    ushort4 bbv = *(const ushort4*)(ob + fo + 256);
    float va[4], vb[4];
    va[0] = xa.x + (bf2f(fa.x) + bf2f(ba.x)) * m;
    va[1] = xa.y + (bf2f(fa.y) + bf2f(ba.y)) * m;
    va[2] = xa.z + (bf2f(fa.z) + bf2f(ba.z)) * m;
    va[3] = xa.w + (bf2f(fa.w) + bf2f(ba.w)) * m;
    vb[0] = xb.x + (bf2f(fbv.x) + bf2f(bbv.x)) * m;
    vb[1] = xb.y + (bf2f(fbv.y) + bf2f(bbv.y)) * m;
    vb[2] = xb.z + (bf2f(fbv.z) + bf2f(bbv.z)) * m;
    vb[3] = xb.w + (bf2f(fbv.w) + bf2f(bbv.w)) * m;
    *(float4*)(x2 + base) = (float4){va[0], va[1], va[2], va[3]};
    *(float4*)(x2 + base + 256) = (float4){vb[0], vb[1], vb[2], vb[3]};
    float ss = va[0]*va[0] + va[1]*va[1] + va[2]*va[2] + va[3]*va[3]
             + vb[0]*vb[0] + vb[1]*vb[1] + vb[2]*vb[2] + vb[3]*vb[3];
    ss = wave_sum(ss);
    float sc = rsqrtf(ss * (1.f / 512.f) + 1.1920929e-07f);
    float4 wa = *(const float4*)(wrms + lane * 4);
    float4 wb = *(const float4*)(wrms + lane * 4 + 256);
    ushort4 oa, obv;
    oa.x = f2bf(va[0] * sc * wa.x);
    oa.y = f2bf(va[1] * sc * wa.y);
    oa.z = f2bf(va[2] * sc * wa.z);
    oa.w = f2bf(va[3] * sc * wa.w);
    obv.x = f2bf(vb[0] * sc * wb.x);
    obv.y = f2bf(vb[1] * sc * wb.y);
    obv.z = f2bf(vb[2] * sc * wb.z);
    obv.w = f2bf(vb[3] * sc * wb.w);
    *(ushort4*)(o + base) = oa;
    *(ushort4*)(o + base + 256) = obv;
}

extern "C" void kernel_launch(void* const* d_in, const int* in_sizes, int n_in,
                              void* d_out, int out_size, void* d_ws, size_t ws_size,
                              hipStream_t stream) {
    const float* x = (const float*)d_in[0];
    const float* pe = (const float*)d_in[1];
    const float* mask = (const float*)d_in[2];
    const float* nsw = (const float*)d_in[3];
    const float* nfw = (const float*)d_in[4];
    const float* w1 = (const float*)d_in[5];
    const float* b1 = (const float*)d_in[6];
    const float* w2 = (const float*)d_in[7];
    const float* b2 = (const float*)d_in[8];
    const float* f_inw = (const float*)d_in[9];
    const float* f_cw = (const float*)d_in[10];
    const float* f_cb = (const float*)d_in[11];
    const float* f_dtb = (const float*)d_in[12];
    const float* f_al = (const float*)d_in[13];
    const float* f_D = (const float*)d_in[14];
    const float* f_gw = (const float*)d_in[15];
    const float* f_ow = (const float*)d_in[16];
    const float* b_inw = (const float*)d_in[17];
    const float* b_cw = (const float*)d_in[18];
    const float* b_cb = (const float*)d_in[19];
    const float* b_dtb = (const float*)d_in[20];
    const float* b_al = (const float*)d_in[21];
    const float* b_D = (const float*)d_in[22];
    const float* b_gw = (const float*)d_in[23];
    const float* b_ow = (const float*)d_in[24];
    float* out = (float*)d_out;

    char* ws = (char*)d_ws;
    u16* Z0   = (u16*)(ws + 0);
    u16* Z1   = (u16*)(ws + 8388608);
    u16* XB0  = (u16*)(ws + 16777216);
    u16* XB1  = (u16*)(ws + 26476544);
    u16* INWF = (u16*)(ws + 36175872);
    u16* INWB = (u16*)(ws + 38535168);
    u16* SIB  = (u16*)(ws + 40894464);
    u16* XC0  = (u16*)(ws + 36175872);
    u16* XC1  = (u16*)(ws + 45613056);
    float* dtF = (float*)(ws + 55050240);
    float* dAF = (float*)(ws + 55312384);
    float* dtB = (float*)(ws + 55574528);
    float* dAB = (float*)(ws + 55836672);
    u16* Y0   = (u16*)(ws + 16777216);
    u16* Y1   = (u16*)(ws + 25165824);
    u16* YG0  = (u16*)(ws + 36175872);
    u16* YG1  = (u16*)(ws + 44564480);
    u16* OP0  = (u16*)(ws + 0);
    u16* OP1  = (u16*)(ws + 4194304);
    float* X2 = (float*)(ws + 8388608);
    u16* X2B  = (u16*)(ws + 0);
    u16* HACT = (u16*)(ws + 16777216);
    u16* OWF = (u16*)(ws + 56098816);
    u16* OWB = (u16*)(ws + 57147392);
    u16* W1B = (u16*)(ws + 58195968);
    u16* W2B = (u16*)(ws + 60293120);
    float* SBUF = (float*)(ws + 62390272);
    float* APR  = (float*)(ws + 95944704);

    // weights: 1376256 groups of 4 -> 5376 blocks; rms: 4096 rows / 4 waves -> 1024 blocks
    k_prep<<<6400, 256, 0, stream>>>(f_inw, b_inw, f_ow, b_ow, w1, w2,
                                     INWF, INWB, OWF, OWB, W1B, W2B,
                                     x, pe, nsw, SIB);
    k_gemm_in<<<dim3(18, 32, 2), 256, 0, stream>>>(SIB, INWF, INWB, Z0, Z1, XB0, XB1);
    k_conv<<<1024, 160, 0, stream>>>(XB0, XB1, f_cw, f_cb, f_dtb, f_al,
                                     b_cw, b_cb, b_dtb, b_al,
                                     XC0, XC1, dtF, dAF, dtB, dAB);
    k_ssd_state<<<2048, 256, 0, stream>>>(XC0, dtF, dAF, XC1, dtB, dAB, SBUF, APR);
    k_scan_carry<<<1024, 256, 0, stream>>>(SBUF, APR);
    k_ssd_y<<<2048, 256, 0, stream>>>(XC0, dtF, dAF, f_D, Y0,
                                      XC1, dtB, dAB, b_D, Y1, SBUF);
    k_gnorm<<<2048, 256, 0, stream>>>(Y0, Z0, f_gw, YG0, Y1, Z1, b_gw, YG1);
    // out-proj: M=4096, N=512, K=1024, 2 dirs -> 128x64 tiles, 512 blocks (2/CU)
    k_gemm12864<0><<<dim3(8, 32, 2), 256, 0, stream>>>(YG0, YG1, OWF, OWB, OP0, OP1, 512, 1024,
                                                       nullptr, nullptr, nullptr);
    k_add_rms<<<1024, 256, 0, stream>>>(x, OP0, OP1, mask, nfw, X2, X2B);
    // FFN1: M=4096, N=2048, K=512 -> 128x128 tiles, 512 blocks (2/CU)
    k_gemm128<1><<<dim3(16, 32, 1), 256, 0, stream>>>(X2B, X2B, W1B, W1B, HACT, HACT, 2048, 512,
                                                      b1, nullptr, nullptr);
    // FFN2: M=4096, N=512, K=2048 -> 64x64 tiles, 512 blocks (2/CU, high occupancy)
    k_gemm64<2><<<dim3(8, 64, 1), 256, 0, stream>>>(HACT, HACT, W2B, W2B, nullptr, nullptr,
                                                    512, 2048, b2, X2, out);
}

// Round 5
// 305.910 us; speedup vs baseline: 1.1200x; 1.0690x over previous
//
#include <hip/hip_runtime.h>
#include <hip/hip_bf16.h>

typedef unsigned short u16;
typedef unsigned int u32;
typedef __bf16 bf16x8 __attribute__((ext_vector_type(8)));
typedef float f32x4 __attribute__((ext_vector_type(4)));

typedef __attribute__((address_space(1))) void gvoid_t;
typedef __attribute__((address_space(3))) void lvoid_t;
__device__ __forceinline__ void lds_cp16(void* lds, const void* g) {
    __builtin_amdgcn_global_load_lds((gvoid_t*)g, (lvoid_t*)lds, 16, 0, 0);
}

__device__ __forceinline__ float bf2f(u16 v) {
    u32 x = (u32)v << 16;
    return __builtin_bit_cast(float, x);
}
__device__ __forceinline__ u16 f2bf(float f) {
    return __builtin_bit_cast(u16, (__bf16)f);
}

__device__ __forceinline__ float wave_sum(float v) {
    #pragma unroll
    for (int o = 32; o > 0; o >>= 1) v += __shfl_xor(v, o);
    return v;
}

__device__ __forceinline__ void cvt4(const float* __restrict__ s, u16* __restrict__ d) {
    float4 v = *(const float4*)s;
    ushort4 o;
    o.x = f2bf(v.x); o.y = f2bf(v.y); o.z = f2bf(v.z); o.w = f2bf(v.w);
    *(ushort4*)d = o;
}

// ---------------- fused: weight conversions (x4 vectorized) + rms_pos (wave/row) ----------------
__global__ __launch_bounds__(256) void k_prep(
    const float* __restrict__ f_inw, const float* __restrict__ b_inw,
    const float* __restrict__ f_ow, const float* __restrict__ b_ow,
    const float* __restrict__ w1, const float* __restrict__ w2,
    u16* __restrict__ INWF, u16* __restrict__ INWB,
    u16* __restrict__ OWF, u16* __restrict__ OWB,
    u16* __restrict__ W1B, u16* __restrict__ W2B,
    const float* __restrict__ x, const float* __restrict__ pe,
    const float* __restrict__ wrms, u16* __restrict__ sib) {
    if (blockIdx.x < 5376) {
        int g = blockIdx.x * 256 + threadIdx.x;
        if (g < 294912) {
            int i = g * 4, n = i >> 9;
            if (n < 2192) cvt4(f_inw + i, INWF + i);
            else *(ushort4*)(INWF + i) = make_ushort4(0, 0, 0, 0);
            return;
        }
        g -= 294912;
        if (g < 294912) {
            int i = g * 4, n = i >> 9;
            if (n < 2192) cvt4(b_inw + i, INWB + i);
            else *(ushort4*)(INWB + i) = make_ushort4(0, 0, 0, 0);
            return;
        }
        g -= 294912;
        if (g < 131072) { cvt4(f_ow + g * 4, OWF + g * 4); return; }
        g -= 131072;
        if (g < 131072) { cvt4(b_ow + g * 4, OWB + g * 4); return; }
        g -= 131072;
        if (g < 262144) { cvt4(w1 + g * 4, W1B + g * 4); return; }
        g -= 262144;
        cvt4(w2 + g * 4, W2B + g * 4);
        return;
    }
    // rms+pos: one wave per row of 512
    int row = (blockIdx.x - 5376) * 4 + (threadIdx.x >> 6);
    int lane = threadIdx.x & 63;
    size_t base = (size_t)row * 512 + lane * 4;
    float4 xa = *(const float4*)(x + base);
    float4 xb = *(const float4*)(x + base + 256);
    float ss = xa.x * xa.x + xa.y * xa.y + xa.z * xa.z + xa.w * xa.w
             + xb.x * xb.x + xb.y * xb.y + xb.z * xb.z + xb.w * xb.w;
    ss = wave_sum(ss);
    float sc = rsqrtf(ss * (1.f / 512.f) + 1.1920929e-07f);
    float4 pa = *(const float4*)(pe + base);
    float4 pb = *(const float4*)(pe + base + 256);
    float4 wa = *(const float4*)(wrms + lane * 4);
    float4 wb = *(const float4*)(wrms + lane * 4 + 256);
    ushort4 oa, obv;
    oa.x = f2bf(xa.x * sc * wa.x + pa.x);
    oa.y = f2bf(xa.y * sc * wa.y + pa.y);
    oa.z = f2bf(xa.z * sc * wa.z + pa.z);
    oa.w = f2bf(xa.w * sc * wa.w + pa.w);
    obv.x = f2bf(xb.x * sc * wb.x + pb.x);
    obv.y = f2bf(xb.y * sc * wb.y + pb.y);
    obv.z = f2bf(xb.z * sc * wb.z + pb.z);
    obv.w = f2bf(xb.w * sc * wb.w + pb.w);
    *(ushort4*)(sib + base) = oa;
    *(ushort4*)(sib + base + 256) = obv;
}

// ---------------- in_proj GEMM, BK=32, 3-buf counted-vmcnt pipeline + LDS epilogue ----------------
__global__ __launch_bounds__(256) void k_gemm_in(
    const u16* __restrict__ A, const u16* __restrict__ W0, const u16* __restrict__ W1,
    u16* __restrict__ Z0, u16* __restrict__ Z1,
    u16* __restrict__ XB0, u16* __restrict__ XB1) {
    const int z = blockIdx.z;
    const u16* W = z ? W1 : W0;
    u16* Z = z ? Z1 : Z0;
    u16* XB = z ? XB1 : XB0;
    const int K = 512;

    __shared__ __align__(16) u16 SMEM[24576];  // As 3x4096 | Bs 3x4096 ; epilogue reuses [128][136]
    u16* As = SMEM;
    u16* Bs = SMEM + 12288;

    const int t = threadIdx.x;
    const int lane = t & 63;
    const int w = t >> 6;
    const int m0 = blockIdx.y * 128;
    const int n0 = blockIdx.x * 128;
    const int wm = (w >> 1) * 64;
    const int wn = (w & 1) * 64;
    const int fr = lane & 15;
    const int ksw = (((lane >> 4) ^ ((fr >> 1) & 3)) & 3) * 8;

    f32x4 acc[4][4];
    #pragma unroll
    for (int i = 0; i < 4; ++i)
        #pragma unroll
        for (int j = 0; j < 4; ++j) acc[i][j] = (f32x4){0.f, 0.f, 0.f, 0.f};

    auto STAGE = [&](int buf, int kt) {
        #pragma unroll
        for (int j = 0; j < 2; ++j) {
            int off16 = j * 256 + t;
            int row = off16 >> 2;
            int kc = (((off16 & 3) ^ ((row >> 1) & 3)) & 3) * 8;
            int gm = m0 + row;
            if (z) gm = (gm & ~2047) | (2047 - (gm & 2047));
            lds_cp16(As + buf * 4096 + off16 * 8, A + (size_t)gm * K + kt + kc);
            lds_cp16(Bs + buf * 4096 + off16 * 8, W + (size_t)(n0 + row) * K + kt + kc);
        }
    };

    const int NS = 16;
    STAGE(0, 0);
    STAGE(1, 32);
    asm volatile("s_waitcnt vmcnt(4)" ::: "memory");
    __builtin_amdgcn_s_barrier();
    __builtin_amdgcn_sched_barrier(0);
    int b0 = 0, b1 = 1, b2 = 2;
    for (int i = 0; i < NS; ++i) {
        if (i + 2 < NS) STAGE(b2, (i + 2) << 5);
        const u16* Ac = As + b0 * 4096;
        const u16* Bc = Bs + b0 * 4096;
        bf16x8 af[4], bfr[4];
        #pragma unroll
        for (int ii = 0; ii < 4; ++ii) af[ii] = *(const bf16x8*)(Ac + (wm + ii * 16 + fr) * 32 + ksw);
        #pragma unroll
        for (int ii = 0; ii < 4; ++ii) bfr[ii] = *(const bf16x8*)(Bc + (wn + ii * 16 + fr) * 32 + ksw);
        #pragma unroll
        for (int ii = 0; ii < 4; ++ii)
            #pragma unroll
            for (int jj = 0; jj < 4; ++jj)
                acc[ii][jj] = __builtin_amdgcn_mfma_f32_16x16x32_bf16(af[ii], bfr[jj], acc[ii][jj], 0, 0, 0);
        if (i + 1 < NS) {
            if (i + 2 < NS) asm volatile("s_waitcnt vmcnt(4) lgkmcnt(0)" ::: "memory");
            else            asm volatile("s_waitcnt vmcnt(0) lgkmcnt(0)" ::: "memory");
            __builtin_amdgcn_s_barrier();
            __builtin_amdgcn_sched_barrier(0);
        }
        int bt = b0; b0 = b1; b1 = b2; b2 = bt;
    }
    // ---- LDS-staged coalesced epilogue ----
    __syncthreads();
    const int PAD = 136;
    #pragma unroll
    for (int i = 0; i < 4; ++i) {
        int rloc = wm + i * 16 + (lane >> 4) * 4;
        #pragma unroll
        for (int j = 0; j < 4; ++j) {
            int cloc = wn + j * 16 + fr;
            #pragma unroll
            for (int r = 0; r < 4; ++r)
                SMEM[(rloc + r) * PAD + cloc] = f2bf(acc[i][j][r]);
        }
    }
    __syncthreads();
    if (n0 < 1024) {
        #pragma unroll
        for (int it = 0; it < 4; ++it) {
            int row = it * 32 + w * 8 + (lane >> 3);
            #pragma unroll
            for (int half = 0; half < 2; ++half) {
                int col = half * 64 + (lane & 7) * 8;
                uint4 v = *(const uint4*)(SMEM + row * PAD + col);
                *(uint4*)(Z + (size_t)(m0 + row) * 1024 + n0 + col) = v;
            }
        }
    } else {
        #pragma unroll
        for (int it = 0; it < 4; ++it) {
            int row = it * 32 + w * 8 + (lane >> 3);
            #pragma unroll
            for (int half = 0; half < 2; ++half) {
                int col = half * 64 + (lane & 7) * 8;
                int cx = n0 - 1024 + col;
                if (cx < 1168) {
                    uint4 v = *(const uint4*)(SMEM + row * PAD + col);
                    *(uint4*)(XB + (size_t)(m0 + row) * 1184 + cx) = v;
                }
            }
        }
    }
}

// ---------------- generic 128x128-tile GEMM, 3-buf pipeline + LDS epilogue ----------------
// EPI 0: bf16 store; 1: gelu(acc+bias)->bf16.
template <int EPI>
__global__ __launch_bounds__(256) void k_gemm128(
    const u16* __restrict__ A0, const u16* __restrict__ A1,
    const u16* __restrict__ W0, const u16* __restrict__ W1,
    u16* __restrict__ C0, u16* __restrict__ C1, int N, int K,
    const float* __restrict__ bias, const float* __restrict__ resid,
    float* __restrict__ outf) {
    const int z = blockIdx.z;
    const u16* A = z ? A1 : A0;
    const u16* W = z ? W1 : W0;
    u16* C = z ? C1 : C0;

    __shared__ __align__(16) u16 SMEM[24576];
    u16* As = SMEM;
    u16* Bs = SMEM + 12288;

    const int t = threadIdx.x;
    const int lane = t & 63;
    const int w = t >> 6;
    const int m0 = blockIdx.y * 128;
    const int n0 = blockIdx.x * 128;
    const int wm = (w >> 1) * 64;
    const int wn = (w & 1) * 64;
    const int fr = lane & 15;
    const int ksw = (((lane >> 4) ^ ((fr >> 1) & 3)) & 3) * 8;

    f32x4 acc[4][4];
    #pragma unroll
    for (int i = 0; i < 4; ++i)
        #pragma unroll
        for (int j = 0; j < 4; ++j) acc[i][j] = (f32x4){0.f, 0.f, 0.f, 0.f};

    auto STAGE = [&](int buf, int kt) {
        #pragma unroll
        for (int j = 0; j < 2; ++j) {
            int off16 = j * 256 + t;
            int row = off16 >> 2;
            int kc = (((off16 & 3) ^ ((row >> 1) & 3)) & 3) * 8;
            lds_cp16(As + buf * 4096 + off16 * 8, A + (size_t)(m0 + row) * K + kt + kc);
            lds_cp16(Bs + buf * 4096 + off16 * 8, W + (size_t)(n0 + row) * K + kt + kc);
        }
    };

    const int NS = K >> 5;
    STAGE(0, 0);
    STAGE(1, 32);
    asm volatile("s_waitcnt vmcnt(4)" ::: "memory");
    __builtin_amdgcn_s_barrier();
    __builtin_amdgcn_sched_barrier(0);
    int b0 = 0, b1 = 1, b2 = 2;
    for (int i = 0; i < NS; ++i) {
        if (i + 2 < NS) STAGE(b2, (i + 2) << 5);
        const u16* Ac = As + b0 * 4096;
        const u16* Bc = Bs + b0 * 4096;
        bf16x8 af[4], bfr[4];
        #pragma unroll
        for (int ii = 0; ii < 4; ++ii) af[ii] = *(const bf16x8*)(Ac + (wm + ii * 16 + fr) * 32 + ksw);
        #pragma unroll
        for (int ii = 0; ii < 4; ++ii) bfr[ii] = *(const bf16x8*)(Bc + (wn + ii * 16 + fr) * 32 + ksw);
        #pragma unroll
        for (int ii = 0; ii < 4; ++ii)
            #pragma unroll
            for (int jj = 0; jj < 4; ++jj)
                acc[ii][jj] = __builtin_amdgcn_mfma_f32_16x16x32_bf16(af[ii], bfr[jj], acc[ii][jj], 0, 0, 0);
        if (i + 1 < NS) {
            if (i + 2 < NS) asm volatile("s_waitcnt vmcnt(4) lgkmcnt(0)" ::: "memory");
            else            asm volatile("s_waitcnt vmcnt(0) lgkmcnt(0)" ::: "memory");
            __builtin_amdgcn_s_barrier();
            __builtin_amdgcn_sched_barrier(0);
        }
        int bt = b0; b0 = b1; b1 = b2; b2 = bt;
    }
    __syncthreads();
    const int PAD = 136;
    #pragma unroll
    for (int i = 0; i < 4; ++i) {
        int rloc = wm + i * 16 + (lane >> 4) * 4;
        #pragma unroll
        for (int j = 0; j < 4; ++j) {
            int cloc = wn + j * 16 + fr;
            float bv = (EPI == 1) ? bias[n0 + cloc] : 0.f;
            #pragma unroll
            for (int r = 0; r < 4; ++r) {
                float v = acc[i][j][r];
                if (EPI == 1) {
                    float xg = v + bv;
                    v = 0.5f * xg * (1.f + erff(xg * 0.70710678118654752f));
                }
                SMEM[(rloc + r) * PAD + cloc] = f2bf(v);
            }
        }
    }
    __syncthreads();
    #pragma unroll
    for (int it = 0; it < 4; ++it) {
        int row = it * 32 + w * 8 + (lane >> 3);
        #pragma unroll
        for (int half = 0; half < 2; ++half) {
            int col = half * 64 + (lane & 7) * 8;
            uint4 v = *(const uint4*)(SMEM + row * PAD + col);
            *(uint4*)(C + (size_t)(m0 + row) * N + n0 + col) = v;
        }
    }
}

// ---------------- 128x64-tile GEMM, 3-buf pipeline + LDS epilogue (bf16 out) ----------------
template <int EPI>
__global__ __launch_bounds__(256) void k_gemm12864(
    const u16* __restrict__ A0, const u16* __restrict__ A1,
    const u16* __restrict__ W0, const u16* __restrict__ W1,
    u16* __restrict__ C0, u16* __restrict__ C1, int N, int K,
    const float* __restrict__ bias, const float* __restrict__ resid,
    float* __restrict__ outf) {
    const int z = blockIdx.z;
    const u16* A = z ? A1 : A0;
    const u16* W = z ? W1 : W0;
    u16* C = z ? C1 : C0;

    __shared__ __align__(16) u16 SMEM[18432];  // As 3x4096 | Bs 3x2048 ; epilogue [128][72]
    u16* As = SMEM;
    u16* Bs = SMEM + 12288;

    const int t = threadIdx.x;
    const int lane = t & 63;
    const int w = t >> 6;
    const int m0 = blockIdx.y * 128;
    const int n0 = blockIdx.x * 64;
    const int wm = w * 32;
    const int fr = lane & 15;
    const int ksw = (((lane >> 4) ^ ((fr >> 1) & 3)) & 3) * 8;

    f32x4 acc[2][4];
    #pragma unroll
    for (int i = 0; i < 2; ++i)
        #pragma unroll
        for (int j = 0; j < 4; ++j) acc[i][j] = (f32x4){0.f, 0.f, 0.f, 0.f};

    auto STAGE = [&](int buf, int kt) {
        #pragma unroll
        for (int j = 0; j < 2; ++j) {
            int off16 = j * 256 + t;
            int row = off16 >> 2;
            int kc = (((off16 & 3) ^ ((row >> 1) & 3)) & 3) * 8;
            lds_cp16(As + buf * 4096 + off16 * 8, A + (size_t)(m0 + row) * K + kt + kc);
        }
        int brow = t >> 2;
        int bkc = (((t & 3) ^ ((brow >> 1) & 3)) & 3) * 8;
        lds_cp16(Bs + buf * 2048 + t * 8, W + (size_t)(n0 + brow) * K + kt + bkc);
    };

    const int NS = K >> 5;
    STAGE(0, 0);
    STAGE(1, 32);
    asm volatile("s_waitcnt vmcnt(3)" ::: "memory");
    __builtin_amdgcn_s_barrier();
    __builtin_amdgcn_sched_barrier(0);
    int b0 = 0, b1 = 1, b2 = 2;
    for (int i = 0; i < NS; ++i) {
        if (i + 2 < NS) STAGE(b2, (i + 2) << 5);
        const u16* Ac = As + b0 * 4096;
        const u16* Bc = Bs + b0 * 2048;
        bf16x8 af[2], bfr[4];
        #pragma unroll
        for (int ii = 0; ii < 2; ++ii) af[ii] = *(const bf16x8*)(Ac + (wm + ii * 16 + fr) * 32 + ksw);
        #pragma unroll
        for (int jj = 0; jj < 4; ++jj) bfr[jj] = *(const bf16x8*)(Bc + (jj * 16 + fr) * 32 + ksw);
        #pragma unroll
        for (int ii = 0; ii < 2; ++ii)
            #pragma unroll
            for (int jj = 0; jj < 4; ++jj)
                acc[ii][jj] = __builtin_amdgcn_mfma_f32_16x16x32_bf16(af[ii], bfr[jj], acc[ii][jj], 0, 0, 0);
        if (i + 1 < NS) {
            if (i + 2 < NS) asm volatile("s_waitcnt vmcnt(3) lgkmcnt(0)" ::: "memory");
            else            asm volatile("s_waitcnt vmcnt(0) lgkmcnt(0)" ::: "memory");
            __builtin_amdgcn_s_barrier();
            __builtin_amdgcn_sched_barrier(0);
        }
        int bt = b0; b0 = b1; b1 = b2; b2 = bt;
    }
    __syncthreads();
    const int PAD = 72;
    #pragma unroll
    for (int i = 0; i < 2; ++i) {
        int rloc = wm + i * 16 + (lane >> 4) * 4;
        #pragma unroll
        for (int j = 0; j < 4; ++j) {
            int cloc = j * 16 + fr;
            float bv = (EPI == 1) ? bias[n0 + cloc] : 0.f;
            #pragma unroll
            for (int r = 0; r < 4; ++r) {
                float v = acc[i][j][r];
                if (EPI == 1) {
                    float xg = v + bv;
                    v = 0.5f * xg * (1.f + erff(xg * 0.70710678118654752f));
                }
                SMEM[(rloc + r) * PAD + cloc] = f2bf(v);
            }
        }
    }
    __syncthreads();
    #pragma unroll
    for (int it = 0; it < 4; ++it) {
        int row = it * 32 + w * 8 + (lane >> 3);
        int col = (lane & 7) * 8;
        uint4 v = *(const uint4*)(SMEM + row * PAD + col);
        *(uint4*)(C + (size_t)(m0 + row) * N + n0 + col) = v;
    }
}

// ---------------- 64x64-tile GEMM, 3-buf pipeline; EPI2: f32 LDS epilogue ----------------
template <int EPI>
__global__ __launch_bounds__(256) void k_gemm64(
    const u16* __restrict__ A0, const u16* __restrict__ A1,
    const u16* __restrict__ W0, const u16* __restrict__ W1,
    u16* __restrict__ C0, u16* __restrict__ C1, int N, int K,
    const float* __restrict__ bias, const float* __restrict__ resid,
    float* __restrict__ outf) {
    const int z = blockIdx.z;
    const u16* A = z ? A1 : A0;
    const u16* W = z ? W1 : W0;
    u16* C = z ? C1 : C0;

    __shared__ __align__(16) u16 SMEM[12288];  // As 3x2048 | Bs 3x2048 ; epilogue f32 [64][68]
    u16* As = SMEM;
    u16* Bs = SMEM + 6144;

    const int t = threadIdx.x;
    const int lane = t & 63;
    const int w = t >> 6;
    const int m0 = blockIdx.y * 64;
    const int n0 = blockIdx.x * 64;
    const int wm = (w >> 1) * 32;
    const int wn = (w & 1) * 32;
    const int fr = lane & 15;
    const int ksw = (((lane >> 4) ^ ((fr >> 1) & 3)) & 3) * 8;

    f32x4 acc[2][2];
    #pragma unroll
    for (int i = 0; i < 2; ++i)
        #pragma unroll
        for (int j = 0; j < 2; ++j) acc[i][j] = (f32x4){0.f, 0.f, 0.f, 0.f};

    const int srow = t >> 2;
    const int skc = (((t & 3) ^ ((srow >> 1) & 3)) & 3) * 8;
    auto STAGE = [&](int buf, int kt) {
        lds_cp16(As + buf * 2048 + t * 8, A + (size_t)(m0 + srow) * K + kt + skc);
        lds_cp16(Bs + buf * 2048 + t * 8, W + (size_t)(n0 + srow) * K + kt + skc);
    };

    const int NS = K >> 5;
    STAGE(0, 0);
    STAGE(1, 32);
    asm volatile("s_waitcnt vmcnt(2)" ::: "memory");
    __builtin_amdgcn_s_barrier();
    __builtin_amdgcn_sched_barrier(0);
    int b0 = 0, b1 = 1, b2 = 2;
    for (int i = 0; i < NS; ++i) {
        if (i + 2 < NS) STAGE(b2, (i + 2) << 5);
        const u16* Ac = As + b0 * 2048;
        const u16* Bc = Bs + b0 * 2048;
        bf16x8 af[2], bfr[2];
        #pragma unroll
        for (int ii = 0; ii < 2; ++ii) af[ii] = *(const bf16x8*)(Ac + (wm + ii * 16 + fr) * 32 + ksw);
        #pragma unroll
        for (int jj = 0; jj < 2; ++jj) bfr[jj] = *(const bf16x8*)(Bc + (wn + jj * 16 + fr) * 32 + ksw);
        #pragma unroll
        for (int ii = 0; ii < 2; ++ii)
            #pragma unroll
            for (int jj = 0; jj < 2; ++jj)
                acc[ii][jj] = __builtin_amdgcn_mfma_f32_16x16x32_bf16(af[ii], bfr[jj], acc[ii][jj], 0, 0, 0);
        if (i + 1 < NS) {
            if (i + 2 < NS) asm volatile("s_waitcnt vmcnt(2) lgkmcnt(0)" ::: "memory");
            else            asm volatile("s_waitcnt vmcnt(0) lgkmcnt(0)" ::: "memory");
            __builtin_amdgcn_s_barrier();
            __builtin_amdgcn_sched_barrier(0);
        }
        int bt = b0; b0 = b1; b1 = b2; b2 = bt;
    }
    if (EPI == 2) {
        __syncthreads();
        float* EPF = (float*)SMEM;
        const int PADF = 68;
        #pragma unroll
        for (int i = 0; i < 2; ++i) {
            int rloc = wm + i * 16 + (lane >> 4) * 4;
            #pragma unroll
            for (int j = 0; j < 2; ++j) {
                int cloc = wn + j * 16 + fr;
                #pragma unroll
                for (int r = 0; r < 4; ++r)
                    EPF[(rloc + r) * PADF + cloc] = acc[i][j][r];
            }
        }
        __syncthreads();
        #pragma unroll
        for (int it = 0; it < 4; ++it) {
            int row = it * 16 + w * 4 + (lane >> 4);
            int col = (lane & 15) * 4;
            float4 v = *(const float4*)(EPF + row * PADF + col);
            int gcol = n0 + col;
            float4 bz = *(const float4*)(bias + gcol);
            float4 rv = *(const float4*)(resid + (size_t)(m0 + row) * N + gcol);
            float4 o;
            o.x = v.x + bz.x + rv.x;
            o.y = v.y + bz.y + rv.y;
            o.z = v.z + bz.z + rv.z;
            o.w = v.w + bz.w + rv.w;
            *(float4*)(outf + (size_t)(m0 + row) * N + gcol) = o;
        }
    } else {
        #pragma unroll
        for (int i = 0; i < 2; ++i) {
            int rbase = m0 + wm + i * 16 + (lane >> 4) * 4;
            #pragma unroll
            for (int j = 0; j < 2; ++j) {
                int col = n0 + wn + j * 16 + fr;
                #pragma unroll
                for (int r = 0; r < 4; ++r) {
                    int m = rbase + r;
                    float v = acc[i][j][r];
                    if (EPI == 0) {
                        C[(size_t)m * N + col] = f2bf(v);
                    } else {
                        float xg = v + bias[col];
                        C[(size_t)m * N + col] = f2bf(0.5f * xg * (1.f + erff(xg * 0.70710678118654752f)));
                    }
                }
            }
        }
    }
}

// ---------------- causal conv4 + silu, 8 rows/block sliding window ----------------
__global__ __launch_bounds__(160) void k_conv(
    const u16* __restrict__ xb0, const u16* __restrict__ xb1,
    const float* __restrict__ cw0, const float* __restrict__ cb0,
    const float* __restrict__ dtb0, const float* __restrict__ al0,
    const float* __restrict__ cw1, const float* __restrict__ cb1,
    const float* __restrict__ dtb1, const float* __restrict__ al1,
    u16* __restrict__ xc0, u16* __restrict__ xc1,
    float* __restrict__ dtO0, float* __restrict__ dAO0,
    float* __restrict__ dtO1, float* __restrict__ dAO1) {
    int g = blockIdx.x;
    int dir = g >> 9;
    int row0 = (g & 511) * 8;
    const u16* xb = dir ? xb1 : xb0;
    const float* cw = dir ? cw1 : cw0;
    const float* cb = dir ? cb1 : cb0;
    const float* dtb = dir ? dtb1 : dtb0;
    const float* al = dir ? al1 : al0;
    u16* xc = dir ? xc1 : xc0;
    float* dtO = dir ? dtO1 : dtO0;
    float* dAO = dir ? dAO1 : dAO0;
    int tl0 = row0 & 2047;
    int rbatch = row0 - tl0;
    int t = threadIdx.x;
    if (t < 144) {
        int col = t * 8;
        float cwa[8][4];
        #pragma unroll
        for (int j = 0; j < 8; ++j) {
            float4 c4 = *(const float4*)(cw + (col + j) * 4);
            cwa[j][0] = c4.x; cwa[j][1] = c4.y; cwa[j][2] = c4.z; cwa[j][3] = c4.w;
        }
        float cbv[8];
        float4 cb0v = *(const float4*)(cb + col);
        float4 cb1v = *(const float4*)(cb + col + 4);
        cbv[0] = cb0v.x; cbv[1] = cb0v.y; cbv[2] = cb0v.z; cbv[3] = cb0v.w;
        cbv[4] = cb1v.x; cbv[5] = cb1v.y; cbv[6] = cb1v.z; cbv[7] = cb1v.w;
        uint4 win[4];
        win[0] = win[1] = win[2] = make_uint4(0, 0, 0, 0);
        #pragma unroll
        for (int i = 0; i < 3; ++i) {
            int tt = tl0 - 3 + i;
            if (tt >= 0) win[i] = *(const uint4*)(xb + (size_t)(rbatch + tt) * 1184 + col);
        }
        for (int s = 0; s < 8; ++s) {
            win[3] = *(const uint4*)(xb + (size_t)(rbatch + tl0 + s) * 1184 + col);
            const u16* w0 = (const u16*)&win[0];
            const u16* w1 = (const u16*)&win[1];
            const u16* w2 = (const u16*)&win[2];
            const u16* w3 = (const u16*)&win[3];
            u16 ov[8];
            #pragma unroll
            for (int j = 0; j < 8; ++j) {
                float a = cbv[j] + bf2f(w0[j]) * cwa[j][0] + bf2f(w1[j]) * cwa[j][1]
                        + bf2f(w2[j]) * cwa[j][2] + bf2f(w3[j]) * cwa[j][3];
                ov[j] = f2bf(a / (1.f + expf(-a)));
            }
            *(uint4*)(xc + (size_t)(row0 + s) * 1152 + col) = *(const uint4*)ov;
            win[0] = win[1]; win[1] = win[2]; win[2] = win[3];
        }
    } else if (t < 160) {
        int hh = t - 144;
        float nal = -expf(al[hh]);
        float dtbv = dtb[hh];
        for (int s = 0; s < 8; ++s) {
            int row = row0 + s;
            float v = bf2f(xb[(size_t)row * 1184 + 1152 + hh]) + dtbv;
            float sp = (v > 20.f) ? v : log1pf(expf(v));
            dtO[row * 16 + hh] = sp;
            dAO[row * 16 + hh] = nal * sp;
        }
    }
}

// ======== SSD chunked scan ========
__global__ __launch_bounds__(256) void k_ssd_state(
    const u16* __restrict__ xc0, const float* __restrict__ dt0, const float* __restrict__ ld0,
    const u16* __restrict__ xc1, const float* __restrict__ dt1, const float* __restrict__ ld1,
    float* __restrict__ S, float* __restrict__ Aprod) {
    int blk = blockIdx.x;
    int c = blk & 31, h = (blk >> 5) & 15, b = (blk >> 9) & 1, dir = blk >> 10;
    const u16* xc = dir ? xc1 : xc0;
    const float* dtp = dir ? dt1 : dt0;
    const float* ldp = dir ? ld1 : ld0;
    const int t = threadIdx.x, w = t >> 6, lane = t & 63;
    const int fr = lane & 15, fk = (lane >> 4) * 8;

    __shared__ __align__(16) u16 sBt[64 * 72];
    __shared__ __align__(16) u16 sXp[64 * 72];
    __shared__ float ssc[64];
    size_t row0 = (size_t)b * 2048 + c * 64;

    if (t < 64) {
        float v = ldp[(row0 + t) * 16 + h];
        float dtv = dtp[(row0 + t) * 16 + h];
        #pragma unroll
        for (int o = 1; o < 64; o <<= 1) {
            float u = __shfl_up(v, o);
            if (lane >= o) v += u;
        }
        float last = __shfl(v, 63);
        ssc[t] = dtv * expf(last - v);
        if (t == 63) Aprod[blk] = expf(v);
    }
    __syncthreads();
    #pragma unroll
    for (int i2 = t; i2 < 512; i2 += 256) {
        int r = i2 >> 3, e8 = (i2 & 7) * 8;
        size_t rb = (row0 + r) * 1152;
        uint4 bv = *(const uint4*)(xc + rb + 1024 + e8);
        uint4 xv = *(const uint4*)(xc + rb + h * 64 + e8);
        const u16* bs = (const u16*)&bv;
        const u16* xs = (const u16*)&xv;
        float sc = ssc[r];
        #pragma unroll
        for (int j = 0; j < 8; ++j) {
            sBt[(e8 + j) * 72 + r] = bs[j];
            sXp[(e8 + j) * 72 + r] = f2bf(bf2f(xs[j]) * sc);
        }
    }
    __syncthreads();

    f32x4 acc[4];
    #pragma unroll
    for (int j = 0; j < 4; ++j) acc[j] = (f32x4){0.f, 0.f, 0.f, 0.f};
    #pragma unroll
    for (int k0 = 0; k0 < 64; k0 += 32) {
        bf16x8 a = *(const bf16x8*)(sBt + (w * 16 + fr) * 72 + k0 + fk);
        #pragma unroll
        for (int j = 0; j < 4; ++j) {
            bf16x8 bb = *(const bf16x8*)(sXp + (j * 16 + fr) * 72 + k0 + fk);
            acc[j] = __builtin_amdgcn_mfma_f32_16x16x32_bf16(a, bb, acc[j], 0, 0, 0);
        }
    }
    float* Sb = S + (size_t)blk * 4096;
    int nb = w * 16 + (lane >> 4) * 4;
    #pragma unroll
    for (int j = 0; j < 4; ++j) {
        int p = j * 16 + fr;
        *(f32x4*)(Sb + p * 64 + nb) = acc[j];
    }
}

// ---- Pass B: fully-parallel carry. grid 1024 = 64 blk-groups x 16; 1 element/thread ----
__global__ __launch_bounds__(256) void k_scan_carry(float* __restrict__ S,
                                                    const float* __restrict__ Aprod) {
    int g = blockIdx.x;
    int blk = g >> 4;
    int e = (g & 15) * 256 + threadIdx.x;
    size_t base = (size_t)blk * 32 * 4096 + e;
    float sv[32];
    #pragma unroll
    for (int c = 0; c < 32; ++c) sv[c] = S[base + (size_t)c * 4096];
    float ap[32];
    #pragma unroll
    for (int c = 0; c < 32; ++c) ap[c] = Aprod[blk * 32 + c];
    float h = 0.f;
    #pragma unroll
    for (int c = 0; c < 32; ++c) {
        S[base + (size_t)c * 4096] = h;
        h = ap[c] * h + sv[c];
    }
}

__global__ __launch_bounds__(256) void k_ssd_y(
    const u16* __restrict__ xc0, const float* __restrict__ dt0, const float* __restrict__ ld0,
    const float* __restrict__ Dv0, u16* __restrict__ y0,
    const u16* __restrict__ xc1, const float* __restrict__ dt1, const float* __restrict__ ld1,
    const float* __restrict__ Dv1, u16* __restrict__ y1,
    const float* __restrict__ S) {
    int blk = blockIdx.x;
    int c = blk & 31, h = (blk >> 5) & 15, b = (blk >> 9) & 1, dir = blk >> 10;
    const u16* xc = dir ? xc1 : xc0;
    const float* dtp = dir ? dt1 : dt0;
    const float* ldp = dir ? ld1 : ld0;
    u16* y = dir ? y1 : y0;
    const float Dh = (dir ? Dv1 : Dv0)[h];
    const int t = threadIdx.x, w = t >> 6, lane = t & 63;
    const int fr = lane & 15, fk = (lane >> 4) * 8;

    // sC doubles as sGl after first MFMA pass; sB/sHi double as result hi/lo after second pass.
    __shared__ __align__(16) u16 sB[64 * 72];
    __shared__ __align__(16) u16 sC[64 * 72];
    __shared__ __align__(16) u16 sXp[64 * 72];
    __shared__ __align__(16) u16 sHi[64 * 72];
    __shared__ __align__(16) u16 sLo[64 * 72];
    __shared__ float scl[64], sdt[64];
    size_t row0 = (size_t)b * 2048 + c * 64;

    if (t < 64) {
        float v = ldp[(row0 + t) * 16 + h];
        float dtv = dtp[(row0 + t) * 16 + h];
        #pragma unroll
        for (int o = 1; o < 64; o <<= 1) {
            float u = __shfl_up(v, o);
            if (lane >= o) v += u;
        }
        scl[t] = v;
        sdt[t] = dtv;
    }
    __syncthreads();
    #pragma unroll
    for (int i2 = t; i2 < 512; i2 += 256) {
        int r = i2 >> 3, e8 = (i2 & 7) * 8;
        size_t rb = (row0 + r) * 1152;
        *(uint4*)(sB + r * 72 + e8) = *(const uint4*)(xc + rb + 1024 + e8);
        *(uint4*)(sC + r * 72 + e8) = *(const uint4*)(xc + rb + 1088 + e8);
        uint4 xv = *(const uint4*)(xc + rb + h * 64 + e8);
        const u16* xs = (const u16*)&xv;
        float dtv = sdt[r];
        #pragma unroll
        for (int j = 0; j < 8; ++j) sXp[(e8 + j) * 72 + r] = f2bf(bf2f(xs[j]) * dtv);
    }
    #pragma unroll
    for (int i4 = t; i4 < 1024; i4 += 256) {
        int p = i4 >> 4, n4 = (i4 & 15) * 4;
        float4 hv = *(const float4*)(S + (size_t)blk * 4096 + p * 64 + n4);
        ushort4 hi4, lo4;
        hi4.x = f2bf(hv.x); lo4.x = f2bf(hv.x - bf2f(hi4.x));
        hi4.y = f2bf(hv.y); lo4.y = f2bf(hv.y - bf2f(hi4.y));
        hi4.z = f2bf(hv.z); lo4.z = f2bf(hv.z - bf2f(hi4.z));
        hi4.w = f2bf(hv.w); lo4.w = f2bf(hv.w - bf2f(hi4.w));
        *(ushort4*)(sHi + p * 72 + n4) = hi4;
        *(ushort4*)(sLo + p * 72 + n4) = lo4;
    }
    __syncthreads();

    f32x4 g[4], acc2[4];
    #pragma unroll
    for (int j = 0; j < 4; ++j) { g[j] = (f32x4){0.f,0.f,0.f,0.f}; acc2[j] = (f32x4){0.f,0.f,0.f,0.f}; }
    #pragma unroll
    for (int k0 = 0; k0 < 64; k0 += 32) {
        bf16x8 a = *(const bf16x8*)(sC + (w * 16 + fr) * 72 + k0 + fk);
        #pragma unroll
        for (int j = 0; j < 4; ++j) {
            bf16x8 bb = *(const bf16x8*)(sB + (j * 16 + fr) * 72 + k0 + fk);
            g[j] = __builtin_amdgcn_mfma_f32_16x16x32_bf16(a, bb, g[j], 0, 0, 0);
            bf16x8 bh = *(const bf16x8*)(sHi + (j * 16 + fr) * 72 + k0 + fk);
            acc2[j] = __builtin_amdgcn_mfma_f32_16x16x32_bf16(a, bh, acc2[j], 0, 0, 0);
            bf16x8 bl = *(const bf16x8*)(sLo + (j * 16 + fr) * 72 + k0 + fk);
            acc2[j] = __builtin_amdgcn_mfma_f32_16x16x32_bf16(a, bl, acc2[j], 0, 0, 0);
        }
    }
    __syncthreads();  // all reads of sC/sB/sHi/sLo done before sGl(=sC) overwrite
    #pragma unroll
    for (int j = 0; j < 4; ++j) {
        int r = j * 16 + fr;
        #pragma unroll
        for (int reg = 0; reg < 4; ++reg) {
            int s = w * 16 + (lane >> 4) * 4 + reg;
            float val = (r <= s) ? expf(scl[s] - scl[r]) * g[j][reg] : 0.f;
            sC[s * 72 + r] = f2bf(val);
        }
    }
    __syncthreads();

    f32x4 acc1[4];
    #pragma unroll
    for (int j = 0; j < 4; ++j) acc1[j] = (f32x4){0.f, 0.f, 0.f, 0.f};
    #pragma unroll
    for (int k0 = 0; k0 < 64; k0 += 32) {
        bf16x8 a = *(const bf16x8*)(sC + (w * 16 + fr) * 72 + k0 + fk);
        #pragma unroll
        for (int j = 0; j < 4; ++j) {
            bf16x8 bb = *(const bf16x8*)(sXp + (j * 16 + fr) * 72 + k0 + fk);
            acc1[j] = __builtin_amdgcn_mfma_f32_16x16x32_bf16(a, bb, acc1[j], 0, 0, 0);
        }
    }
    // stage partial result (hi/lo bf16 split for precision) into sB/sHi (dead after pass 1)
    #pragma unroll
    for (int reg = 0; reg < 4; ++reg) {
        int s = w * 16 + (lane >> 4) * 4 + reg;
        float es = expf(scl[s]);
        #pragma unroll
        for (int j = 0; j < 4; ++j) {
            int p = j * 16 + fr;
            float val = acc1[j][reg] + es * acc2[j][reg];
            u16 vh = f2bf(val);
            sB[s * 72 + p] = vh;
            sHi[s * 72 + p] = f2bf(val - bf2f(vh));
        }
    }
    __syncthreads();
    // coalesced: y = partial + x*Dh, 16B loads/stores
    {
        int row = t >> 2;
        int cseg = (t & 3) * 16;
        size_t yrb = (row0 + row) * 1024 + h * 64 + cseg;
        size_t xrb = (row0 + row) * 1152 + h * 64 + cseg;
        #pragma unroll
        for (int u = 0; u < 2; ++u) {
            uint4 svh = *(const uint4*)(sB + row * 72 + cseg + u * 8);
            uint4 svl = *(const uint4*)(sHi + row * 72 + cseg + u * 8);
            uint4 xv = *(const uint4*)(xc + xrb + u * 8);
            const u16* ph = (const u16*)&svh;
            const u16* pl = (const u16*)&svl;
            const u16* px = (const u16*)&xv;
            u16 ov[8];
            #pragma unroll
            for (int e = 0; e < 8; ++e)
                ov[e] = f2bf(bf2f(ph[e]) + bf2f(pl[e]) + bf2f(px[e]) * Dh);
            *(uint4*)(y + yrb + u * 8) = *(const uint4*)ov;
        }
    }
}

// ---------------- gated RMS norm: one wave per row, no barriers ----------------
__global__ __launch_bounds__(256) void k_gnorm(
    const u16* __restrict__ y0, const u16* __restrict__ z0,
    const float* __restrict__ gw0, u16* __restrict__ o0,
    const u16* __restrict__ y1, const u16* __restrict__ z1,
    const float* __restrict__ gw1, u16* __restrict__ o1) {
    int idx = blockIdx.x * 4 + (threadIdx.x >> 6);
    int dir = idx >> 12, row = idx & 4095;
    int lane = threadIdx.x & 63;
    const u16* y = dir ? y1 : y0;
    const u16* zp = dir ? z1 : z0;
    const float* gw = dir ? gw1 : gw0;
    u16* o = dir ? o1 : o0;
    size_t base = (size_t)row * 1024 + lane * 8;
    uint4 ya = *(const uint4*)(y + base);
    uint4 yb = *(const uint4*)(y + base + 512);
    uint4 za = *(const uint4*)(zp + base);
    uint4 zb = *(const uint4*)(zp + base + 512);
    const u16* yap = (const u16*)&ya;
    const u16* ybp = (const u16*)&yb;
    const u16* zap = (const u16*)&za;
    const u16* zbp = (const u16*)&zb;
    float v[16];
    float ss = 0.f;
    #pragma unroll
    for (int j = 0; j < 8; ++j) {
        float zf = bf2f(zap[j]);
        v[j] = bf2f(yap[j]) * (zf / (1.f + expf(-zf)));
        ss += v[j] * v[j];
    }
    #pragma unroll
    for (int j = 0; j < 8; ++j) {
        float zf = bf2f(zbp[j]);
        v[8 + j] = bf2f(ybp[j]) * (zf / (1.f + expf(-zf)));
        ss += v[8 + j] * v[8 + j];
    }
    ss = wave_sum(ss);
    float sc = rsqrtf(ss * (1.f / 1024.f) + 1e-5f);
    float4 g0 = *(const float4*)(gw + lane * 8);
    float4 g1 = *(const float4*)(gw + lane * 8 + 4);
    float4 g2 = *(const float4*)(gw + 512 + lane * 8);
    float4 g3 = *(const float4*)(gw + 512 + lane * 8 + 4);
    const float* gp0 = (const float*)&g0;
    const float* gp1 = (const float*)&g1;
    const float* gp2 = (const float*)&g2;
    const float* gp3 = (const float*)&g3;
    u16 oa[8], obv[8];
    #pragma unroll
    for (int j = 0; j < 4; ++j) {
        oa[j] = f2bf(v[j] * sc * gp0[j]);
        oa[4 + j] = f2bf(v[4 + j] * sc * gp1[j]);
        obv[j] = f2bf(v[8 + j] * sc * gp2[j]);
        obv[4 + j] = f2bf(v[12 + j] * sc * gp3[j]);
    }
    *(uint4*)(o + base) = *(const uint4*)oa;
    *(uint4*)(o + base + 512) = *(const uint4*)obv;
}

// ---- fused: x2 = x + (fwd+flip(bwd))*mask; rms(x2)*nfw -> bf16. One wave per row ----
__global__ __launch_bounds__(256) void k_add_rms(
    const float* __restrict__ x, const u16* __restrict__ of,
    const u16* __restrict__ ob, const float* __restrict__ mask,
    const float* __restrict__ wrms,
    float* __restrict__ x2, u16* __restrict__ o) {
    int row = blockIdx.x * 4 + (threadIdx.x >> 6);
    int lane = threadIdx.x & 63;
    int bb = row >> 11, tl = row & 2047;
    size_t fb = (size_t)((bb << 11) + (2047 - tl)) * 512;
    float m = mask[row];
    size_t base = (size_t)row * 512 + lane * 4;
    size_t fo = fb + lane * 4;
    float4 xa = *(const float4*)(x + base);
    float4 xb = *(const float4*)(x + base + 256);
    ushort4 fa = *(const ushort4*)(of + base);
    ushort4 fbv = *(const ushort4*)(of + base + 256);
    ushort4 ba = *(const ushort4*)(ob + fo);
    ushort4 bbv = *(const ushort4*)(ob + fo + 256);
    float va[4], vb[4];
    va[0] = xa.x + (bf2f(fa.x) + bf2f(ba.x)) * m;
    va[1] = xa.y + (bf2f(fa.y) + bf2f(ba.y)) * m;
    va[2] = xa.z + (bf2f(fa.z) + bf2f(ba.z)) * m;
    va[3] = xa.w + (bf2f(fa.w) + bf2f(ba.w)) * m;
    vb[0] = xb.x + (bf2f(fbv.x) + bf2f(bbv.x)) * m;
    vb[1] = xb.y + (bf2f(fbv.y) + bf2f(bbv.y)) * m;
    vb[2] = xb.z + (bf2f(fbv.z) + bf2f(bbv.z)) * m;
    vb[3] = xb.w + (bf2f(fbv.w) + bf2f(bbv.w)) * m;
    *(float4*)(x2 + base) = (float4){va[0], va[1], va[2], va[3]};
    *(float4*)(x2 + base + 256) = (float4){vb[0], vb[1], vb[2], vb[3]};
    float ss = va[0]*va[0] + va[1]*va[1] + va[2]*va[2] + va[3]*va[3]
             + vb[0]*vb[0] + vb[1]*vb[1] + vb[2]*vb[2] + vb[3]*vb[3];
    ss = wave_sum(ss);
    float sc = rsqrtf(ss * (1.f / 512.f) + 1.1920929e-07f);
    float4 wa = *(const float4*)(wrms + lane * 4);
    float4 wb = *(const float4*)(wrms + lane * 4 + 256);
    ushort4 oa, obv;
    oa.x = f2bf(va[0] * sc * wa.x);
    oa.y = f2bf(va[1] * sc * wa.y);
    oa.z = f2bf(va[2] * sc * wa.z);
    oa.w = f2bf(va[3] * sc * wa.w);
    obv.x = f2bf(vb[0] * sc * wb.x);
    obv.y = f2bf(vb[1] * sc * wb.y);
    obv.z = f2bf(vb[2] * sc * wb.z);
    obv.w = f2bf(vb[3] * sc * wb.w);
    *(ushort4*)(o + base) = oa;
    *(ushort4*)(o + base + 256) = obv;
}

extern "C" void kernel_launch(void* const* d_in, const int* in_sizes, int n_in,
                              void* d_out, int out_size, void* d_ws, size_t ws_size,
                              hipStream_t stream) {
    const float* x = (const float*)d_in[0];
    const float* pe = (const float*)d_in[1];
    const float* mask = (const float*)d_in[2];
    const float* nsw = (const float*)d_in[3];
    const float* nfw = (const float*)d_in[4];
    const float* w1 = (const float*)d_in[5];
    const float* b1 = (const float*)d_in[6];
    const float* w2 = (const float*)d_in[7];
    const float* b2 = (const float*)d_in[8];
    const float* f_inw = (const float*)d_in[9];
    const float* f_cw = (const float*)d_in[10];
    const float* f_cb = (const float*)d_in[11];
    const float* f_dtb = (const float*)d_in[12];
    const float* f_al = (const float*)d_in[13];
    const float* f_D = (const float*)d_in[14];
    const float* f_gw = (const float*)d_in[15];
    const float* f_ow = (const float*)d_in[16];
    const float* b_inw = (const float*)d_in[17];
    const float* b_cw = (const float*)d_in[18];
    const float* b_cb = (const float*)d_in[19];
    const float* b_dtb = (const float*)d_in[20];
    const float* b_al = (const float*)d_in[21];
    const float* b_D = (const float*)d_in[22];
    const float* b_gw = (const float*)d_in[23];
    const float* b_ow = (const float*)d_in[24];
    float* out = (float*)d_out;

    char* ws = (char*)d_ws;
    u16* Z0   = (u16*)(ws + 0);
    u16* Z1   = (u16*)(ws + 8388608);
    u16* XB0  = (u16*)(ws + 16777216);
    u16* XB1  = (u16*)(ws + 26476544);
    u16* INWF = (u16*)(ws + 36175872);
    u16* INWB = (u16*)(ws + 38535168);
    u16* SIB  = (u16*)(ws + 40894464);
    u16* XC0  = (u16*)(ws + 36175872);
    u16* XC1  = (u16*)(ws + 45613056);
    float* dtF = (float*)(ws + 55050240);
    float* dAF = (float*)(ws + 55312384);
    float* dtB = (float*)(ws + 55574528);
    float* dAB = (float*)(ws + 55836672);
    u16* Y0   = (u16*)(ws + 16777216);
    u16* Y1   = (u16*)(ws + 25165824);
    u16* YG0  = (u16*)(ws + 36175872);
    u16* YG1  = (u16*)(ws + 44564480);
    u16* OP0  = (u16*)(ws + 0);
    u16* OP1  = (u16*)(ws + 4194304);
    float* X2 = (float*)(ws + 8388608);
    u16* X2B  = (u16*)(ws + 0);
    u16* HACT = (u16*)(ws + 16777216);
    u16* OWF = (u16*)(ws + 56098816);
    u16* OWB = (u16*)(ws + 57147392);
    u16* W1B = (u16*)(ws + 58195968);
    u16* W2B = (u16*)(ws + 60293120);
    float* SBUF = (float*)(ws + 62390272);
    float* APR  = (float*)(ws + 95944704);

    k_prep<<<6400, 256, 0, stream>>>(f_inw, b_inw, f_ow, b_ow, w1, w2,
                                     INWF, INWB, OWF, OWB, W1B, W2B,
                                     x, pe, nsw, SIB);
    k_gemm_in<<<dim3(18, 32, 2), 256, 0, stream>>>(SIB, INWF, INWB, Z0, Z1, XB0, XB1);
    k_conv<<<1024, 160, 0, stream>>>(XB0, XB1, f_cw, f_cb, f_dtb, f_al,
                                     b_cw, b_cb, b_dtb, b_al,
                                     XC0, XC1, dtF, dAF, dtB, dAB);
    k_ssd_state<<<2048, 256, 0, stream>>>(XC0, dtF, dAF, XC1, dtB, dAB, SBUF, APR);
    k_scan_carry<<<1024, 256, 0, stream>>>(SBUF, APR);
    k_ssd_y<<<2048, 256, 0, stream>>>(XC0, dtF, dAF, f_D, Y0,
                                      XC1, dtB, dAB, b_D, Y1, SBUF);
    k_gnorm<<<2048, 256, 0, stream>>>(Y0, Z0, f_gw, YG0, Y1, Z1, b_gw, YG1);
    // out-proj: M=4096, N=512, K=1024, 2 dirs -> 128x64 tiles, 512 blocks (2/CU)
    k_gemm12864<0><<<dim3(8, 32, 2), 256, 0, stream>>>(YG0, YG1, OWF, OWB, OP0, OP1, 512, 1024,
                                                       nullptr, nullptr, nullptr);
    k_add_rms<<<1024, 256, 0, stream>>>(x, OP0, OP1, mask, nfw, X2, X2B);
    // FFN1: M=4096, N=2048, K=512 -> 128x128 tiles, 512 blocks (2/CU)
    k_gemm128<1><<<dim3(16, 32, 1), 256, 0, stream>>>(X2B, X2B, W1B, W1B, HACT, HACT, 2048, 512,
                                                      b1, nullptr, nullptr);
    // FFN2: M=4096, N=512, K=2048 -> 64x64 tiles, 512 blocks (2/CU, high occupancy)
    k_gemm64<2><<<dim3(8, 64, 1), 256, 0, stream>>>(HACT, HACT, W2B, W2B, nullptr, nullptr,
                                                    512, 2048, b2, X2, out);
}

// Round 6
// 288.119 us; speedup vs baseline: 1.1892x; 1.0617x over previous
//
#include <hip/hip_runtime.h>
#include <hip/hip_bf16.h>

typedef unsigned short u16;
typedef unsigned int u32;
typedef __bf16 bf16x8 __attribute__((ext_vector_type(8)));
typedef float f32x4 __attribute__((ext_vector_type(4)));

typedef __attribute__((address_space(1))) void gvoid_t;
typedef __attribute__((address_space(3))) void lvoid_t;
__device__ __forceinline__ void lds_cp16(void* lds, const void* g) {
    __builtin_amdgcn_global_load_lds((gvoid_t*)g, (lvoid_t*)lds, 16, 0, 0);
}

__device__ __forceinline__ float bf2f(u16 v) {
    u32 x = (u32)v << 16;
    return __builtin_bit_cast(float, x);
}
__device__ __forceinline__ u16 f2bf(float f) {
    return __builtin_bit_cast(u16, (__bf16)f);
}

__device__ __forceinline__ float wave_sum(float v) {
    #pragma unroll
    for (int o = 32; o > 0; o >>= 1) v += __shfl_xor(v, o);
    return v;
}

__device__ __forceinline__ void cvt4(const float* __restrict__ s, u16* __restrict__ d) {
    float4 v = *(const float4*)s;
    ushort4 o;
    o.x = f2bf(v.x); o.y = f2bf(v.y); o.z = f2bf(v.z); o.w = f2bf(v.w);
    *(ushort4*)d = o;
}

// ---------------- fused: weight conversions (x4 vectorized) + rms_pos (wave/row) ----------------
__global__ __launch_bounds__(256) void k_prep(
    const float* __restrict__ f_inw, const float* __restrict__ b_inw,
    const float* __restrict__ f_ow, const float* __restrict__ b_ow,
    const float* __restrict__ w1, const float* __restrict__ w2,
    u16* __restrict__ INWF, u16* __restrict__ INWB,
    u16* __restrict__ OWF, u16* __restrict__ OWB,
    u16* __restrict__ W1B, u16* __restrict__ W2B,
    const float* __restrict__ x, const float* __restrict__ pe,
    const float* __restrict__ wrms, u16* __restrict__ sib) {
    if (blockIdx.x < 5376) {
        int g = blockIdx.x * 256 + threadIdx.x;
        if (g < 294912) {
            int i = g * 4, n = i >> 9;
            if (n < 2192) cvt4(f_inw + i, INWF + i);
            else *(ushort4*)(INWF + i) = make_ushort4(0, 0, 0, 0);
            return;
        }
        g -= 294912;
        if (g < 294912) {
            int i = g * 4, n = i >> 9;
            if (n < 2192) cvt4(b_inw + i, INWB + i);
            else *(ushort4*)(INWB + i) = make_ushort4(0, 0, 0, 0);
            return;
        }
        g -= 294912;
        if (g < 131072) { cvt4(f_ow + g * 4, OWF + g * 4); return; }
        g -= 131072;
        if (g < 131072) { cvt4(b_ow + g * 4, OWB + g * 4); return; }
        g -= 131072;
        if (g < 262144) { cvt4(w1 + g * 4, W1B + g * 4); return; }
        g -= 262144;
        cvt4(w2 + g * 4, W2B + g * 4);
        return;
    }
    // rms+pos: one wave per row of 512
    int row = (blockIdx.x - 5376) * 4 + (threadIdx.x >> 6);
    int lane = threadIdx.x & 63;
    size_t base = (size_t)row * 512 + lane * 4;
    float4 xa = *(const float4*)(x + base);
    float4 xb = *(const float4*)(x + base + 256);
    float ss = xa.x * xa.x + xa.y * xa.y + xa.z * xa.z + xa.w * xa.w
             + xb.x * xb.x + xb.y * xb.y + xb.z * xb.z + xb.w * xb.w;
    ss = wave_sum(ss);
    float sc = rsqrtf(ss * (1.f / 512.f) + 1.1920929e-07f);
    float4 pa = *(const float4*)(pe + base);
    float4 pb = *(const float4*)(pe + base + 256);
    float4 wa = *(const float4*)(wrms + lane * 4);
    float4 wb = *(const float4*)(wrms + lane * 4 + 256);
    ushort4 oa, obv;
    oa.x = f2bf(xa.x * sc * wa.x + pa.x);
    oa.y = f2bf(xa.y * sc * wa.y + pa.y);
    oa.z = f2bf(xa.z * sc * wa.z + pa.z);
    oa.w = f2bf(xa.w * sc * wa.w + pa.w);
    obv.x = f2bf(xb.x * sc * wb.x + pb.x);
    obv.y = f2bf(xb.y * sc * wb.y + pb.y);
    obv.z = f2bf(xb.z * sc * wb.z + pb.z);
    obv.w = f2bf(xb.w * sc * wb.w + pb.w);
    *(ushort4*)(sib + base) = oa;
    *(ushort4*)(sib + base + 256) = obv;
}

// ---------------- in_proj GEMM, BK=32, 3-buf pipeline + XCD swizzle + LDS epilogue ----------------
__global__ __launch_bounds__(256) void k_gemm_in(
    const u16* __restrict__ A, const u16* __restrict__ W0, const u16* __restrict__ W1,
    u16* __restrict__ Z0, u16* __restrict__ Z1,
    u16* __restrict__ XB0, u16* __restrict__ XB1) {
    const int z = blockIdx.z;
    const u16* W = z ? W1 : W0;
    u16* Z = z ? Z1 : Z0;
    u16* XB = z ? XB1 : XB0;
    const int K = 512;

    __shared__ __align__(16) u16 SMEM[24576];  // As 3x4096 | Bs 3x4096 ; epilogue reuses [128][136]
    u16* As = SMEM;
    u16* Bs = SMEM + 12288;

    const int t = threadIdx.x;
    const int lane = t & 63;
    const int w = t >> 6;
    // XCD-aware bijective swizzle (nwg = 18*32 = 576, 576%8==0)
    const int nwg = gridDim.x * gridDim.y;
    const int wg = blockIdx.y * gridDim.x + blockIdx.x;
    const int swz = (wg & 7) * (nwg >> 3) + (wg >> 3);
    const int m0 = (swz / gridDim.x) * 128;
    const int n0 = (swz % gridDim.x) * 128;
    const int wm = (w >> 1) * 64;
    const int wn = (w & 1) * 64;
    const int fr = lane & 15;
    const int ksw = (((lane >> 4) ^ ((fr >> 1) & 3)) & 3) * 8;

    f32x4 acc[4][4];
    #pragma unroll
    for (int i = 0; i < 4; ++i)
        #pragma unroll
        for (int j = 0; j < 4; ++j) acc[i][j] = (f32x4){0.f, 0.f, 0.f, 0.f};

    auto STAGE = [&](int buf, int kt) {
        #pragma unroll
        for (int j = 0; j < 2; ++j) {
            int off16 = j * 256 + t;
            int row = off16 >> 2;
            int kc = (((off16 & 3) ^ ((row >> 1) & 3)) & 3) * 8;
            int gm = m0 + row;
            if (z) gm = (gm & ~2047) | (2047 - (gm & 2047));
            lds_cp16(As + buf * 4096 + off16 * 8, A + (size_t)gm * K + kt + kc);
            lds_cp16(Bs + buf * 4096 + off16 * 8, W + (size_t)(n0 + row) * K + kt + kc);
        }
    };

    const int NS = 16;
    STAGE(0, 0);
    STAGE(1, 32);
    asm volatile("s_waitcnt vmcnt(4)" ::: "memory");
    __builtin_amdgcn_s_barrier();
    __builtin_amdgcn_sched_barrier(0);
    int b0 = 0, b1 = 1, b2 = 2;
    for (int i = 0; i < NS; ++i) {
        if (i + 2 < NS) STAGE(b2, (i + 2) << 5);
        const u16* Ac = As + b0 * 4096;
        const u16* Bc = Bs + b0 * 4096;
        bf16x8 af[4], bfr[4];
        #pragma unroll
        for (int ii = 0; ii < 4; ++ii) af[ii] = *(const bf16x8*)(Ac + (wm + ii * 16 + fr) * 32 + ksw);
        #pragma unroll
        for (int ii = 0; ii < 4; ++ii) bfr[ii] = *(const bf16x8*)(Bc + (wn + ii * 16 + fr) * 32 + ksw);
        #pragma unroll
        for (int ii = 0; ii < 4; ++ii)
            #pragma unroll
            for (int jj = 0; jj < 4; ++jj)
                acc[ii][jj] = __builtin_amdgcn_mfma_f32_16x16x32_bf16(af[ii], bfr[jj], acc[ii][jj], 0, 0, 0);
        if (i + 1 < NS) {
            if (i + 2 < NS) asm volatile("s_waitcnt vmcnt(4) lgkmcnt(0)" ::: "memory");
            else            asm volatile("s_waitcnt vmcnt(0) lgkmcnt(0)" ::: "memory");
            __builtin_amdgcn_s_barrier();
            __builtin_amdgcn_sched_barrier(0);
        }
        int bt = b0; b0 = b1; b1 = b2; b2 = bt;
    }
    // ---- LDS-staged coalesced epilogue ----
    __syncthreads();
    const int PAD = 136;
    #pragma unroll
    for (int i = 0; i < 4; ++i) {
        int rloc = wm + i * 16 + (lane >> 4) * 4;
        #pragma unroll
        for (int j = 0; j < 4; ++j) {
            int cloc = wn + j * 16 + fr;
            #pragma unroll
            for (int r = 0; r < 4; ++r)
                SMEM[(rloc + r) * PAD + cloc] = f2bf(acc[i][j][r]);
        }
    }
    __syncthreads();
    if (n0 < 1024) {
        #pragma unroll
        for (int it = 0; it < 4; ++it) {
            int row = it * 32 + w * 8 + (lane >> 3);
            #pragma unroll
            for (int half = 0; half < 2; ++half) {
                int col = half * 64 + (lane & 7) * 8;
                uint4 v = *(const uint4*)(SMEM + row * PAD + col);
                *(uint4*)(Z + (size_t)(m0 + row) * 1024 + n0 + col) = v;
            }
        }
    } else {
        #pragma unroll
        for (int it = 0; it < 4; ++it) {
            int row = it * 32 + w * 8 + (lane >> 3);
            #pragma unroll
            for (int half = 0; half < 2; ++half) {
                int col = half * 64 + (lane & 7) * 8;
                int cx = n0 - 1024 + col;
                if (cx < 1168) {
                    uint4 v = *(const uint4*)(SMEM + row * PAD + col);
                    *(uint4*)(XB + (size_t)(m0 + row) * 1184 + cx) = v;
                }
            }
        }
    }
}

// ---------------- generic 128x128-tile GEMM, 3-buf pipeline + XCD swizzle + LDS epilogue ----------------
// EPI 0: bf16 store; 1: gelu(acc+bias)->bf16.
template <int EPI>
__global__ __launch_bounds__(256) void k_gemm128(
    const u16* __restrict__ A0, const u16* __restrict__ A1,
    const u16* __restrict__ W0, const u16* __restrict__ W1,
    u16* __restrict__ C0, u16* __restrict__ C1, int N, int K,
    const float* __restrict__ bias, const float* __restrict__ resid,
    float* __restrict__ outf) {
    const int z = blockIdx.z;
    const u16* A = z ? A1 : A0;
    const u16* W = z ? W1 : W0;
    u16* C = z ? C1 : C0;

    __shared__ __align__(16) u16 SMEM[24576];
    u16* As = SMEM;
    u16* Bs = SMEM + 12288;

    const int t = threadIdx.x;
    const int lane = t & 63;
    const int w = t >> 6;
    const int nwg = gridDim.x * gridDim.y;
    const int wg = blockIdx.y * gridDim.x + blockIdx.x;
    const int swz = (wg & 7) * (nwg >> 3) + (wg >> 3);
    const int m0 = (swz / gridDim.x) * 128;
    const int n0 = (swz % gridDim.x) * 128;
    const int wm = (w >> 1) * 64;
    const int wn = (w & 1) * 64;
    const int fr = lane & 15;
    const int ksw = (((lane >> 4) ^ ((fr >> 1) & 3)) & 3) * 8;

    f32x4 acc[4][4];
    #pragma unroll
    for (int i = 0; i < 4; ++i)
        #pragma unroll
        for (int j = 0; j < 4; ++j) acc[i][j] = (f32x4){0.f, 0.f, 0.f, 0.f};

    auto STAGE = [&](int buf, int kt) {
        #pragma unroll
        for (int j = 0; j < 2; ++j) {
            int off16 = j * 256 + t;
            int row = off16 >> 2;
            int kc = (((off16 & 3) ^ ((row >> 1) & 3)) & 3) * 8;
            lds_cp16(As + buf * 4096 + off16 * 8, A + (size_t)(m0 + row) * K + kt + kc);
            lds_cp16(Bs + buf * 4096 + off16 * 8, W + (size_t)(n0 + row) * K + kt + kc);
        }
    };

    const int NS = K >> 5;
    STAGE(0, 0);
    STAGE(1, 32);
    asm volatile("s_waitcnt vmcnt(4)" ::: "memory");
    __builtin_amdgcn_s_barrier();
    __builtin_amdgcn_sched_barrier(0);
    int b0 = 0, b1 = 1, b2 = 2;
    for (int i = 0; i < NS; ++i) {
        if (i + 2 < NS) STAGE(b2, (i + 2) << 5);
        const u16* Ac = As + b0 * 4096;
        const u16* Bc = Bs + b0 * 4096;
        bf16x8 af[4], bfr[4];
        #pragma unroll
        for (int ii = 0; ii < 4; ++ii) af[ii] = *(const bf16x8*)(Ac + (wm + ii * 16 + fr) * 32 + ksw);
        #pragma unroll
        for (int ii = 0; ii < 4; ++ii) bfr[ii] = *(const bf16x8*)(Bc + (wn + ii * 16 + fr) * 32 + ksw);
        #pragma unroll
        for (int ii = 0; ii < 4; ++ii)
            #pragma unroll
            for (int jj = 0; jj < 4; ++jj)
                acc[ii][jj] = __builtin_amdgcn_mfma_f32_16x16x32_bf16(af[ii], bfr[jj], acc[ii][jj], 0, 0, 0);
        if (i + 1 < NS) {
            if (i + 2 < NS) asm volatile("s_waitcnt vmcnt(4) lgkmcnt(0)" ::: "memory");
            else            asm volatile("s_waitcnt vmcnt(0) lgkmcnt(0)" ::: "memory");
            __builtin_amdgcn_s_barrier();
            __builtin_amdgcn_sched_barrier(0);
        }
        int bt = b0; b0 = b1; b1 = b2; b2 = bt;
    }
    __syncthreads();
    const int PAD = 136;
    #pragma unroll
    for (int i = 0; i < 4; ++i) {
        int rloc = wm + i * 16 + (lane >> 4) * 4;
        #pragma unroll
        for (int j = 0; j < 4; ++j) {
            int cloc = wn + j * 16 + fr;
            float bv = (EPI == 1) ? bias[n0 + cloc] : 0.f;
            #pragma unroll
            for (int r = 0; r < 4; ++r) {
                float v = acc[i][j][r];
                if (EPI == 1) {
                    float xg = v + bv;
                    v = 0.5f * xg * (1.f + erff(xg * 0.70710678118654752f));
                }
                SMEM[(rloc + r) * PAD + cloc] = f2bf(v);
            }
        }
    }
    __syncthreads();
    #pragma unroll
    for (int it = 0; it < 4; ++it) {
        int row = it * 32 + w * 8 + (lane >> 3);
        #pragma unroll
        for (int half = 0; half < 2; ++half) {
            int col = half * 64 + (lane & 7) * 8;
            uint4 v = *(const uint4*)(SMEM + row * PAD + col);
            *(uint4*)(C + (size_t)(m0 + row) * N + n0 + col) = v;
        }
    }
}

// ---------------- 128x64-tile GEMM, 3-buf pipeline + XCD swizzle + LDS epilogue (bf16 out) ----------------
template <int EPI>
__global__ __launch_bounds__(256) void k_gemm12864(
    const u16* __restrict__ A0, const u16* __restrict__ A1,
    const u16* __restrict__ W0, const u16* __restrict__ W1,
    u16* __restrict__ C0, u16* __restrict__ C1, int N, int K,
    const float* __restrict__ bias, const float* __restrict__ resid,
    float* __restrict__ outf) {
    const int z = blockIdx.z;
    const u16* A = z ? A1 : A0;
    const u16* W = z ? W1 : W0;
    u16* C = z ? C1 : C0;

    __shared__ __align__(16) u16 SMEM[18432];  // As 3x4096 | Bs 3x2048 ; epilogue [128][72]
    u16* As = SMEM;
    u16* Bs = SMEM + 12288;

    const int t = threadIdx.x;
    const int lane = t & 63;
    const int w = t >> 6;
    const int nwg = gridDim.x * gridDim.y;
    const int wg = blockIdx.y * gridDim.x + blockIdx.x;
    const int swz = (wg & 7) * (nwg >> 3) + (wg >> 3);
    const int m0 = (swz / gridDim.x) * 128;
    const int n0 = (swz % gridDim.x) * 64;
    const int wm = w * 32;
    const int fr = lane & 15;
    const int ksw = (((lane >> 4) ^ ((fr >> 1) & 3)) & 3) * 8;

    f32x4 acc[2][4];
    #pragma unroll
    for (int i = 0; i < 2; ++i)
        #pragma unroll
        for (int j = 0; j < 4; ++j) acc[i][j] = (f32x4){0.f, 0.f, 0.f, 0.f};

    auto STAGE = [&](int buf, int kt) {
        #pragma unroll
        for (int j = 0; j < 2; ++j) {
            int off16 = j * 256 + t;
            int row = off16 >> 2;
            int kc = (((off16 & 3) ^ ((row >> 1) & 3)) & 3) * 8;
            lds_cp16(As + buf * 4096 + off16 * 8, A + (size_t)(m0 + row) * K + kt + kc);
        }
        int brow = t >> 2;
        int bkc = (((t & 3) ^ ((brow >> 1) & 3)) & 3) * 8;
        lds_cp16(Bs + buf * 2048 + t * 8, W + (size_t)(n0 + brow) * K + kt + bkc);
    };

    const int NS = K >> 5;
    STAGE(0, 0);
    STAGE(1, 32);
    asm volatile("s_waitcnt vmcnt(3)" ::: "memory");
    __builtin_amdgcn_s_barrier();
    __builtin_amdgcn_sched_barrier(0);
    int b0 = 0, b1 = 1, b2 = 2;
    for (int i = 0; i < NS; ++i) {
        if (i + 2 < NS) STAGE(b2, (i + 2) << 5);
        const u16* Ac = As + b0 * 4096;
        const u16* Bc = Bs + b0 * 2048;
        bf16x8 af[2], bfr[4];
        #pragma unroll
        for (int ii = 0; ii < 2; ++ii) af[ii] = *(const bf16x8*)(Ac + (wm + ii * 16 + fr) * 32 + ksw);
        #pragma unroll
        for (int jj = 0; jj < 4; ++jj) bfr[jj] = *(const bf16x8*)(Bc + (jj * 16 + fr) * 32 + ksw);
        #pragma unroll
        for (int ii = 0; ii < 2; ++ii)
            #pragma unroll
            for (int jj = 0; jj < 4; ++jj)
                acc[ii][jj] = __builtin_amdgcn_mfma_f32_16x16x32_bf16(af[ii], bfr[jj], acc[ii][jj], 0, 0, 0);
        if (i + 1 < NS) {
            if (i + 2 < NS) asm volatile("s_waitcnt vmcnt(3) lgkmcnt(0)" ::: "memory");
            else            asm volatile("s_waitcnt vmcnt(0) lgkmcnt(0)" ::: "memory");
            __builtin_amdgcn_s_barrier();
            __builtin_amdgcn_sched_barrier(0);
        }
        int bt = b0; b0 = b1; b1 = b2; b2 = bt;
    }
    __syncthreads();
    const int PAD = 72;
    #pragma unroll
    for (int i = 0; i < 2; ++i) {
        int rloc = wm + i * 16 + (lane >> 4) * 4;
        #pragma unroll
        for (int j = 0; j < 4; ++j) {
            int cloc = j * 16 + fr;
            float bv = (EPI == 1) ? bias[n0 + cloc] : 0.f;
            #pragma unroll
            for (int r = 0; r < 4; ++r) {
                float v = acc[i][j][r];
                if (EPI == 1) {
                    float xg = v + bv;
                    v = 0.5f * xg * (1.f + erff(xg * 0.70710678118654752f));
                }
                SMEM[(rloc + r) * PAD + cloc] = f2bf(v);
            }
        }
    }
    __syncthreads();
    #pragma unroll
    for (int it = 0; it < 4; ++it) {
        int row = it * 32 + w * 8 + (lane >> 3);
        int col = (lane & 7) * 8;
        uint4 v = *(const uint4*)(SMEM + row * PAD + col);
        *(uint4*)(C + (size_t)(m0 + row) * N + n0 + col) = v;
    }
}

// ---------------- 64x64-tile GEMM, 3-buf pipeline + XCD swizzle; EPI2: f32 LDS epilogue ----------------
template <int EPI>
__global__ __launch_bounds__(256) void k_gemm64(
    const u16* __restrict__ A0, const u16* __restrict__ A1,
    const u16* __restrict__ W0, const u16* __restrict__ W1,
    u16* __restrict__ C0, u16* __restrict__ C1, int N, int K,
    const float* __restrict__ bias, const float* __restrict__ resid,
    float* __restrict__ outf) {
    const int z = blockIdx.z;
    const u16* A = z ? A1 : A0;
    const u16* W = z ? W1 : W0;
    u16* C = z ? C1 : C0;

    __shared__ __align__(16) u16 SMEM[12288];  // As 3x2048 | Bs 3x2048 ; epilogue f32 [64][68]
    u16* As = SMEM;
    u16* Bs = SMEM + 6144;

    const int t = threadIdx.x;
    const int lane = t & 63;
    const int w = t >> 6;
    const int nwg = gridDim.x * gridDim.y;
    const int wg = blockIdx.y * gridDim.x + blockIdx.x;
    const int swz = (wg & 7) * (nwg >> 3) + (wg >> 3);
    const int m0 = (swz / gridDim.x) * 64;
    const int n0 = (swz % gridDim.x) * 64;
    const int wm = (w >> 1) * 32;
    const int wn = (w & 1) * 32;
    const int fr = lane & 15;
    const int ksw = (((lane >> 4) ^ ((fr >> 1) & 3)) & 3) * 8;

    f32x4 acc[2][2];
    #pragma unroll
    for (int i = 0; i < 2; ++i)
        #pragma unroll
        for (int j = 0; j < 2; ++j) acc[i][j] = (f32x4){0.f, 0.f, 0.f, 0.f};

    const int srow = t >> 2;
    const int skc = (((t & 3) ^ ((srow >> 1) & 3)) & 3) * 8;
    auto STAGE = [&](int buf, int kt) {
        lds_cp16(As + buf * 2048 + t * 8, A + (size_t)(m0 + srow) * K + kt + skc);
        lds_cp16(Bs + buf * 2048 + t * 8, W + (size_t)(n0 + srow) * K + kt + skc);
    };

    const int NS = K >> 5;
    STAGE(0, 0);
    STAGE(1, 32);
    asm volatile("s_waitcnt vmcnt(2)" ::: "memory");
    __builtin_amdgcn_s_barrier();
    __builtin_amdgcn_sched_barrier(0);
    int b0 = 0, b1 = 1, b2 = 2;
    for (int i = 0; i < NS; ++i) {
        if (i + 2 < NS) STAGE(b2, (i + 2) << 5);
        const u16* Ac = As + b0 * 2048;
        const u16* Bc = Bs + b0 * 2048;
        bf16x8 af[2], bfr[2];
        #pragma unroll
        for (int ii = 0; ii < 2; ++ii) af[ii] = *(const bf16x8*)(Ac + (wm + ii * 16 + fr) * 32 + ksw);
        #pragma unroll
        for (int jj = 0; jj < 2; ++jj) bfr[jj] = *(const bf16x8*)(Bc + (wn + jj * 16 + fr) * 32 + ksw);
        #pragma unroll
        for (int ii = 0; ii < 2; ++ii)
            #pragma unroll
            for (int jj = 0; jj < 2; ++jj)
                acc[ii][jj] = __builtin_amdgcn_mfma_f32_16x16x32_bf16(af[ii], bfr[jj], acc[ii][jj], 0, 0, 0);
        if (i + 1 < NS) {
            if (i + 2 < NS) asm volatile("s_waitcnt vmcnt(2) lgkmcnt(0)" ::: "memory");
            else            asm volatile("s_waitcnt vmcnt(0) lgkmcnt(0)" ::: "memory");
            __builtin_amdgcn_s_barrier();
            __builtin_amdgcn_sched_barrier(0);
        }
        int bt = b0; b0 = b1; b1 = b2; b2 = bt;
    }
    if (EPI == 2) {
        __syncthreads();
        float* EPF = (float*)SMEM;
        const int PADF = 68;
        #pragma unroll
        for (int i = 0; i < 2; ++i) {
            int rloc = wm + i * 16 + (lane >> 4) * 4;
            #pragma unroll
            for (int j = 0; j < 2; ++j) {
                int cloc = wn + j * 16 + fr;
                #pragma unroll
                for (int r = 0; r < 4; ++r)
                    EPF[(rloc + r) * PADF + cloc] = acc[i][j][r];
            }
        }
        __syncthreads();
        #pragma unroll
        for (int it = 0; it < 4; ++it) {
            int row = it * 16 + w * 4 + (lane >> 4);
            int col = (lane & 15) * 4;
            float4 v = *(const float4*)(EPF + row * PADF + col);
            int gcol = n0 + col;
            float4 bz = *(const float4*)(bias + gcol);
            float4 rv = *(const float4*)(resid + (size_t)(m0 + row) * N + gcol);
            float4 o;
            o.x = v.x + bz.x + rv.x;
            o.y = v.y + bz.y + rv.y;
            o.z = v.z + bz.z + rv.z;
            o.w = v.w + bz.w + rv.w;
            *(float4*)(outf + (size_t)(m0 + row) * N + gcol) = o;
        }
    } else {
        #pragma unroll
        for (int i = 0; i < 2; ++i) {
            int rbase = m0 + wm + i * 16 + (lane >> 4) * 4;
            #pragma unroll
            for (int j = 0; j < 2; ++j) {
                int col = n0 + wn + j * 16 + fr;
                #pragma unroll
                for (int r = 0; r < 4; ++r) {
                    int m = rbase + r;
                    float v = acc[i][j][r];
                    if (EPI == 0) {
                        C[(size_t)m * N + col] = f2bf(v);
                    } else {
                        float xg = v + bias[col];
                        C[(size_t)m * N + col] = f2bf(0.5f * xg * (1.f + erff(xg * 0.70710678118654752f)));
                    }
                }
            }
        }
    }
}

// ---------------- causal conv4 + silu, 8 rows/block sliding window ----------------
__global__ __launch_bounds__(160) void k_conv(
    const u16* __restrict__ xb0, const u16* __restrict__ xb1,
    const float* __restrict__ cw0, const float* __restrict__ cb0,
    const float* __restrict__ dtb0, const float* __restrict__ al0,
    const float* __restrict__ cw1, const float* __restrict__ cb1,
    const float* __restrict__ dtb1, const float* __restrict__ al1,
    u16* __restrict__ xc0, u16* __restrict__ xc1,
    float* __restrict__ dtO0, float* __restrict__ dAO0,
    float* __restrict__ dtO1, float* __restrict__ dAO1) {
    int g = blockIdx.x;
    int dir = g >> 9;
    int row0 = (g & 511) * 8;
    const u16* xb = dir ? xb1 : xb0;
    const float* cw = dir ? cw1 : cw0;
    const float* cb = dir ? cb1 : cb0;
    const float* dtb = dir ? dtb1 : dtb0;
    const float* al = dir ? al1 : al0;
    u16* xc = dir ? xc1 : xc0;
    float* dtO = dir ? dtO1 : dtO0;
    float* dAO = dir ? dAO1 : dAO0;
    int tl0 = row0 & 2047;
    int rbatch = row0 - tl0;
    int t = threadIdx.x;
    if (t < 144) {
        int col = t * 8;
        float cwa[8][4];
        #pragma unroll
        for (int j = 0; j < 8; ++j) {
            float4 c4 = *(const float4*)(cw + (col + j) * 4);
            cwa[j][0] = c4.x; cwa[j][1] = c4.y; cwa[j][2] = c4.z; cwa[j][3] = c4.w;
        }
        float cbv[8];
        float4 cb0v = *(const float4*)(cb + col);
        float4 cb1v = *(const float4*)(cb + col + 4);
        cbv[0] = cb0v.x; cbv[1] = cb0v.y; cbv[2] = cb0v.z; cbv[3] = cb0v.w;
        cbv[4] = cb1v.x; cbv[5] = cb1v.y; cbv[6] = cb1v.z; cbv[7] = cb1v.w;
        uint4 win[4];
        win[0] = win[1] = win[2] = make_uint4(0, 0, 0, 0);
        #pragma unroll
        for (int i = 0; i < 3; ++i) {
            int tt = tl0 - 3 + i;
            if (tt >= 0) win[i] = *(const uint4*)(xb + (size_t)(rbatch + tt) * 1184 + col);
        }
        for (int s = 0; s < 8; ++s) {
            win[3] = *(const uint4*)(xb + (size_t)(rbatch + tl0 + s) * 1184 + col);
            const u16* w0 = (const u16*)&win[0];
            const u16* w1 = (const u16*)&win[1];
            const u16* w2 = (const u16*)&win[2];
            const u16* w3 = (const u16*)&win[3];
            u16 ov[8];
            #pragma unroll
            for (int j = 0; j < 8; ++j) {
                float a = cbv[j] + bf2f(w0[j]) * cwa[j][0] + bf2f(w1[j]) * cwa[j][1]
                        + bf2f(w2[j]) * cwa[j][2] + bf2f(w3[j]) * cwa[j][3];
                ov[j] = f2bf(a / (1.f + expf(-a)));
            }
            *(uint4*)(xc + (size_t)(row0 + s) * 1152 + col) = *(const uint4*)ov;
            win[0] = win[1]; win[1] = win[2]; win[2] = win[3];
        }
    } else if (t < 160) {
        int hh = t - 144;
        float nal = -expf(al[hh]);
        float dtbv = dtb[hh];
        for (int s = 0; s < 8; ++s) {
            int row = row0 + s;
            float v = bf2f(xb[(size_t)row * 1184 + 1152 + hh]) + dtbv;
            float sp = (v > 20.f) ? v : log1pf(expf(v));
            dtO[row * 16 + hh] = sp;
            dAO[row * 16 + hh] = nal * sp;
        }
    }
}

// ======== SSD chunked scan ========
__global__ __launch_bounds__(256) void k_ssd_state(
    const u16* __restrict__ xc0, const float* __restrict__ dt0, const float* __restrict__ ld0,
    const u16* __restrict__ xc1, const float* __restrict__ dt1, const float* __restrict__ ld1,
    float* __restrict__ S, float* __restrict__ Aprod) {
    int blk = blockIdx.x;
    int c = blk & 31, h = (blk >> 5) & 15, b = (blk >> 9) & 1, dir = blk >> 10;
    const u16* xc = dir ? xc1 : xc0;
    const float* dtp = dir ? dt1 : dt0;
    const float* ldp = dir ? ld1 : ld0;
    const int t = threadIdx.x, w = t >> 6, lane = t & 63;
    const int fr = lane & 15, fk = (lane >> 4) * 8;

    __shared__ __align__(16) u16 sBt[64 * 72];
    __shared__ __align__(16) u16 sXp[64 * 72];
    __shared__ float ssc[64];
    size_t row0 = (size_t)b * 2048 + c * 64;

    if (t < 64) {
        float v = ldp[(row0 + t) * 16 + h];
        float dtv = dtp[(row0 + t) * 16 + h];
        #pragma unroll
        for (int o = 1; o < 64; o <<= 1) {
            float u = __shfl_up(v, o);
            if (lane >= o) v += u;
        }
        float last = __shfl(v, 63);
        ssc[t] = dtv * expf(last - v);
        if (t == 63) Aprod[blk] = expf(v);
    }
    __syncthreads();
    // packed transposed staging: 2 rows/thread, b32 LDS writes (half the LDS ops, 8-way vs 16-way)
    {
        int rp = (t >> 3) * 2;          // 0..62 even
        int e8 = (t & 7) * 8;
        size_t rb0 = (row0 + rp) * 1152;
        size_t rb1 = (row0 + rp + 1) * 1152;
        uint4 bv0 = *(const uint4*)(xc + rb0 + 1024 + e8);
        uint4 bv1 = *(const uint4*)(xc + rb1 + 1024 + e8);
        uint4 xv0 = *(const uint4*)(xc + rb0 + h * 64 + e8);
        uint4 xv1 = *(const uint4*)(xc + rb1 + h * 64 + e8);
        const u16* pb0 = (const u16*)&bv0;
        const u16* pb1 = (const u16*)&bv1;
        const u16* px0 = (const u16*)&xv0;
        const u16* px1 = (const u16*)&xv1;
        float s0 = ssc[rp], s1 = ssc[rp + 1];
        #pragma unroll
        for (int j = 0; j < 8; ++j) {
            *(u32*)(sBt + (e8 + j) * 72 + rp) = (u32)pb0[j] | ((u32)pb1[j] << 16);
            u32 xw = (u32)f2bf(bf2f(px0[j]) * s0) | ((u32)f2bf(bf2f(px1[j]) * s1) << 16);
            *(u32*)(sXp + (e8 + j) * 72 + rp) = xw;
        }
    }
    __syncthreads();

    f32x4 acc[4];
    #pragma unroll
    for (int j = 0; j < 4; ++j) acc[j] = (f32x4){0.f, 0.f, 0.f, 0.f};
    #pragma unroll
    for (int k0 = 0; k0 < 64; k0 += 32) {
        bf16x8 a = *(const bf16x8*)(sBt + (w * 16 + fr) * 72 + k0 + fk);
        #pragma unroll
        for (int j = 0; j < 4; ++j) {
            bf16x8 bb = *(const bf16x8*)(sXp + (j * 16 + fr) * 72 + k0 + fk);
            acc[j] = __builtin_amdgcn_mfma_f32_16x16x32_bf16(a, bb, acc[j], 0, 0, 0);
        }
    }
    float* Sb = S + (size_t)blk * 4096;
    int nb = w * 16 + (lane >> 4) * 4;
    #pragma unroll
    for (int j = 0; j < 4; ++j) {
        int p = j * 16 + fr;
        *(f32x4*)(Sb + p * 64 + nb) = acc[j];
    }
}

// ---- Pass B: fully-parallel carry. grid 1024 = 64 blk-groups x 16; 1 element/thread ----
__global__ __launch_bounds__(256) void k_scan_carry(float* __restrict__ S,
                                                    const float* __restrict__ Aprod) {
    int g = blockIdx.x;
    int blk = g >> 4;
    int e = (g & 15) * 256 + threadIdx.x;
    size_t base = (size_t)blk * 32 * 4096 + e;
    float sv[32];
    #pragma unroll
    for (int c = 0; c < 32; ++c) sv[c] = S[base + (size_t)c * 4096];
    float ap[32];
    #pragma unroll
    for (int c = 0; c < 32; ++c) ap[c] = Aprod[blk * 32 + c];
    float h = 0.f;
    #pragma unroll
    for (int c = 0; c < 32; ++c) {
        S[base + (size_t)c * 4096] = h;
        h = ap[c] * h + sv[c];
    }
}

__global__ __launch_bounds__(256) void k_ssd_y(
    const u16* __restrict__ xc0, const float* __restrict__ dt0, const float* __restrict__ ld0,
    const float* __restrict__ Dv0, u16* __restrict__ y0,
    const u16* __restrict__ xc1, const float* __restrict__ dt1, const float* __restrict__ ld1,
    const float* __restrict__ Dv1, u16* __restrict__ y1,
    const float* __restrict__ S) {
    int blk = blockIdx.x;
    int c = blk & 31, h = (blk >> 5) & 15, b = (blk >> 9) & 1, dir = blk >> 10;
    const u16* xc = dir ? xc1 : xc0;
    const float* dtp = dir ? dt1 : dt0;
    const float* ldp = dir ? ld1 : ld0;
    u16* y = dir ? y1 : y0;
    const float Dh = (dir ? Dv1 : Dv0)[h];
    const int t = threadIdx.x, w = t >> 6, lane = t & 63;
    const int fr = lane & 15, fk = (lane >> 4) * 8;

    // 4 buffers (37.4 KB -> 4 blocks/CU). sHi time-multiplexed hi->lo (S tile held in regs);
    // sC reused as Gl after pass1; sB/sHi reused as result hi/lo for the epilogue.
    __shared__ __align__(16) u16 sB[64 * 72];
    __shared__ __align__(16) u16 sC[64 * 72];
    __shared__ __align__(16) u16 sXp[64 * 72];
    __shared__ __align__(16) u16 sHi[64 * 72];
    __shared__ float scl[64], sdt[64];
    size_t row0 = (size_t)b * 2048 + c * 64;

    if (t < 64) {
        float v = ldp[(row0 + t) * 16 + h];
        float dtv = dtp[(row0 + t) * 16 + h];
        #pragma unroll
        for (int o = 1; o < 64; o <<= 1) {
            float u = __shfl_up(v, o);
            if (lane >= o) v += u;
        }
        scl[t] = v;
        sdt[t] = dtv;
    }
    __syncthreads();
    // packed staging: 2 rows/thread; B/C row-major uint4; X transposed via b32 pairs
    {
        int rp = (t >> 3) * 2;
        int e8 = (t & 7) * 8;
        size_t rb0 = (row0 + rp) * 1152;
        size_t rb1 = (row0 + rp + 1) * 1152;
        *(uint4*)(sB + rp * 72 + e8)       = *(const uint4*)(xc + rb0 + 1024 + e8);
        *(uint4*)(sB + (rp + 1) * 72 + e8) = *(const uint4*)(xc + rb1 + 1024 + e8);
        *(uint4*)(sC + rp * 72 + e8)       = *(const uint4*)(xc + rb0 + 1088 + e8);
        *(uint4*)(sC + (rp + 1) * 72 + e8) = *(const uint4*)(xc + rb1 + 1088 + e8);
        uint4 xv0 = *(const uint4*)(xc + rb0 + h * 64 + e8);
        uint4 xv1 = *(const uint4*)(xc + rb1 + h * 64 + e8);
        const u16* px0 = (const u16*)&xv0;
        const u16* px1 = (const u16*)&xv1;
        float d0 = sdt[rp], d1 = sdt[rp + 1];
        #pragma unroll
        for (int j = 0; j < 8; ++j) {
            u32 xw = (u32)f2bf(bf2f(px0[j]) * d0) | ((u32)f2bf(bf2f(px1[j]) * d1) << 16);
            *(u32*)(sXp + (e8 + j) * 72 + rp) = xw;
        }
    }
    // S tile -> registers; stage hi part into sHi
    float4 hvr[4];
    #pragma unroll
    for (int q = 0; q < 4; ++q) {
        int i4 = t + q * 256;
        int p = i4 >> 4, n4 = (i4 & 15) * 4;
        hvr[q] = *(const float4*)(S + (size_t)blk * 4096 + p * 64 + n4);
        ushort4 hi4;
        hi4.x = f2bf(hvr[q].x);
        hi4.y = f2bf(hvr[q].y);
        hi4.z = f2bf(hvr[q].z);
        hi4.w = f2bf(hvr[q].w);
        *(ushort4*)(sHi + p * 72 + n4) = hi4;
    }
    __syncthreads();

    // pass 1a: g = C x B^T, acc2 = C x S_hi
    f32x4 g[4], acc2[4];
    #pragma unroll
    for (int j = 0; j < 4; ++j) { g[j] = (f32x4){0.f,0.f,0.f,0.f}; acc2[j] = (f32x4){0.f,0.f,0.f,0.f}; }
    #pragma unroll
    for (int k0 = 0; k0 < 64; k0 += 32) {
        bf16x8 a = *(const bf16x8*)(sC + (w * 16 + fr) * 72 + k0 + fk);
        #pragma unroll
        for (int j = 0; j < 4; ++j) {
            bf16x8 bb = *(const bf16x8*)(sB + (j * 16 + fr) * 72 + k0 + fk);
            g[j] = __builtin_amdgcn_mfma_f32_16x16x32_bf16(a, bb, g[j], 0, 0, 0);
            bf16x8 bh = *(const bf16x8*)(sHi + (j * 16 + fr) * 72 + k0 + fk);
            acc2[j] = __builtin_amdgcn_mfma_f32_16x16x32_bf16(a, bh, acc2[j], 0, 0, 0);
        }
    }
    __syncthreads();  // all reads of sHi(hi) done
    // restage sHi with lo part from registers
    #pragma unroll
    for (int q = 0; q < 4; ++q) {
        int i4 = t + q * 256;
        int p = i4 >> 4, n4 = (i4 & 15) * 4;
        ushort4 lo4;
        lo4.x = f2bf(hvr[q].x - bf2f(f2bf(hvr[q].x)));
        lo4.y = f2bf(hvr[q].y - bf2f(f2bf(hvr[q].y)));
        lo4.z = f2bf(hvr[q].z - bf2f(f2bf(hvr[q].z)));
        lo4.w = f2bf(hvr[q].w - bf2f(f2bf(hvr[q].w)));
        *(ushort4*)(sHi + p * 72 + n4) = lo4;
    }
    __syncthreads();
    // pass 1b: acc2 += C x S_lo
    #pragma unroll
    for (int k0 = 0; k0 < 64; k0 += 32) {
        bf16x8 a = *(const bf16x8*)(sC + (w * 16 + fr) * 72 + k0 + fk);
        #pragma unroll
        for (int j = 0; j < 4; ++j) {
            bf16x8 bl = *(const bf16x8*)(sHi + (j * 16 + fr) * 72 + k0 + fk);
            acc2[j] = __builtin_amdgcn_mfma_f32_16x16x32_bf16(a, bl, acc2[j], 0, 0, 0);
        }
    }
    __syncthreads();  // all reads of sC/sB/sHi done before Gl overwrite of sC
    #pragma unroll
    for (int j = 0; j < 4; ++j) {
        int r = j * 16 + fr;
        #pragma unroll
        for (int reg = 0; reg < 4; ++reg) {
            int s = w * 16 + (lane >> 4) * 4 + reg;
            float val = (r <= s) ? expf(scl[s] - scl[r]) * g[j][reg] : 0.f;
            sC[s * 72 + r] = f2bf(val);
        }
    }
    __syncthreads();

    f32x4 acc1[4];
    #pragma unroll
    for (int j = 0; j < 4; ++j) acc1[j] = (f32x4){0.f, 0.f, 0.f, 0.f};
    #pragma unroll
    for (int k0 = 0; k0 < 64; k0 += 32) {
        bf16x8 a = *(const bf16x8*)(sC + (w * 16 + fr) * 72 + k0 + fk);
        #pragma unroll
        for (int j = 0; j < 4; ++j) {
            bf16x8 bb = *(const bf16x8*)(sXp + (j * 16 + fr) * 72 + k0 + fk);
            acc1[j] = __builtin_amdgcn_mfma_f32_16x16x32_bf16(a, bb, acc1[j], 0, 0, 0);
        }
    }
    // stage partial result (hi/lo bf16 split for precision) into sB/sHi (dead after pass 1)
    #pragma unroll
    for (int reg = 0; reg < 4; ++reg) {
        int s = w * 16 + (lane >> 4) * 4 + reg;
        float es = expf(scl[s]);
        #pragma unroll
        for (int j = 0; j < 4; ++j) {
            int p = j * 16 + fr;
            float val = acc1[j][reg] + es * acc2[j][reg];
            u16 vh = f2bf(val);
            sB[s * 72 + p] = vh;
            sHi[s * 72 + p] = f2bf(val - bf2f(vh));
        }
    }
    __syncthreads();
    // coalesced: y = partial + x*Dh, 16B loads/stores
    {
        int row = t >> 2;
        int cseg = (t & 3) * 16;
        size_t yrb = (row0 + row) * 1024 + h * 64 + cseg;
        size_t xrb = (row0 + row) * 1152 + h * 64 + cseg;
        #pragma unroll
        for (int u = 0; u < 2; ++u) {
            uint4 svh = *(const uint4*)(sB + row * 72 + cseg + u * 8);
            uint4 svl = *(const uint4*)(sHi + row * 72 + cseg + u * 8);
            uint4 xv = *(const uint4*)(xc + xrb + u * 8);
            const u16* ph = (const u16*)&svh;
            const u16* pl = (const u16*)&svl;
            const u16* px = (const u16*)&xv;
            u16 ov[8];
            #pragma unroll
            for (int e = 0; e < 8; ++e)
                ov[e] = f2bf(bf2f(ph[e]) + bf2f(pl[e]) + bf2f(px[e]) * Dh);
            *(uint4*)(y + yrb + u * 8) = *(const uint4*)ov;
        }
    }
}

// ---------------- gated RMS norm: one wave per row, no barriers ----------------
__global__ __launch_bounds__(256) void k_gnorm(
    const u16* __restrict__ y0, const u16* __restrict__ z0,
    const float* __restrict__ gw0, u16* __restrict__ o0,
    const u16* __restrict__ y1, const u16* __restrict__ z1,
    const float* __restrict__ gw1, u16* __restrict__ o1) {
    int idx = blockIdx.x * 4 + (threadIdx.x >> 6);
    int dir = idx >> 12, row = idx & 4095;
    int lane = threadIdx.x & 63;
    const u16* y = dir ? y1 : y0;
    const u16* zp = dir ? z1 : z0;
    const float* gw = dir ? gw1 : gw0;
    u16* o = dir ? o1 : o0;
    size_t base = (size_t)row * 1024 + lane * 8;
    uint4 ya = *(const uint4*)(y + base);
    uint4 yb = *(const uint4*)(y + base + 512);
    uint4 za = *(const uint4*)(zp + base);
    uint4 zb = *(const uint4*)(zp + base + 512);
    const u16* yap = (const u16*)&ya;
    const u16* ybp = (const u16*)&yb;
    const u16* zap = (const u16*)&za;
    const u16* zbp = (const u16*)&zb;
    float v[16];
    float ss = 0.f;
    #pragma unroll
    for (int j = 0; j < 8; ++j) {
        float zf = bf2f(zap[j]);
        v[j] = bf2f(yap[j]) * (zf / (1.f + expf(-zf)));
        ss += v[j] * v[j];
    }
    #pragma unroll
    for (int j = 0; j < 8; ++j) {
        float zf = bf2f(zbp[j]);
        v[8 + j] = bf2f(ybp[j]) * (zf / (1.f + expf(-zf)));
        ss += v[8 + j] * v[8 + j];
    }
    ss = wave_sum(ss);
    float sc = rsqrtf(ss * (1.f / 1024.f) + 1e-5f);
    float4 g0 = *(const float4*)(gw + lane * 8);
    float4 g1 = *(const float4*)(gw + lane * 8 + 4);
    float4 g2 = *(const float4*)(gw + 512 + lane * 8);
    float4 g3 = *(const float4*)(gw + 512 + lane * 8 + 4);
    const float* gp0 = (const float*)&g0;
    const float* gp1 = (const float*)&g1;
    const float* gp2 = (const float*)&g2;
    const float* gp3 = (const float*)&g3;
    u16 oa[8], obv[8];
    #pragma unroll
    for (int j = 0; j < 4; ++j) {
        oa[j] = f2bf(v[j] * sc * gp0[j]);
        oa[4 + j] = f2bf(v[4 + j] * sc * gp1[j]);
        obv[j] = f2bf(v[8 + j] * sc * gp2[j]);
        obv[4 + j] = f2bf(v[12 + j] * sc * gp3[j]);
    }
    *(uint4*)(o + base) = *(const uint4*)oa;
    *(uint4*)(o + base + 512) = *(const uint4*)obv;
}

// ---- fused: x2 = x + (fwd+flip(bwd))*mask; rms(x2)*nfw -> bf16. One wave per row ----
__global__ __launch_bounds__(256) void k_add_rms(
    const float* __restrict__ x, const u16* __restrict__ of,
    const u16* __restrict__ ob, const float* __restrict__ mask,
    const float* __restrict__ wrms,
    float* __restrict__ x2, u16* __restrict__ o) {
    int row = blockIdx.x * 4 + (threadIdx.x >> 6);
    int lane = threadIdx.x & 63;
    int bb = row >> 11, tl = row & 2047;
    size_t fb = (size_t)((bb << 11) + (2047 - tl)) * 512;
    float m = mask[row];
    size_t base = (size_t)row * 512 + lane * 4;
    size_t fo = fb + lane * 4;
    float4 xa = *(const float4*)(x + base);
    float4 xb = *(const float4*)(x + base + 256);
    ushort4 fa = *(const ushort4*)(of + base);
    ushort4 fbv = *(const ushort4*)(of + base + 256);
    ushort4 ba = *(const ushort4*)(ob + fo);
    ushort4 bbv = *(const ushort4*)(ob + fo + 256);
    float va[4], vb[4];
    va[0] = xa.x + (bf2f(fa.x) + bf2f(ba.x)) * m;
    va[1] = xa.y + (bf2f(fa.y) + bf2f(ba.y)) * m;
    va[2] = xa.z + (bf2f(fa.z) + bf2f(ba.z)) * m;
    va[3] = xa.w + (bf2f(fa.w) + bf2f(ba.w)) * m;
    vb[0] = xb.x + (bf2f(fbv.x) + bf2f(bbv.x)) * m;
    vb[1] = xb.y + (bf2f(fbv.y) + bf2f(bbv.y)) * m;
    vb[2] = xb.z + (bf2f(fbv.z) + bf2f(bbv.z)) * m;
    vb[3] = xb.w + (bf2f(fbv.w) + bf2f(bbv.w)) * m;
    *(float4*)(x2 + base) = (float4){va[0], va[1], va[2], va[3]};
    *(float4*)(x2 + base + 256) = (float4){vb[0], vb[1], vb[2], vb[3]};
    float ss = va[0]*va[0] + va[1]*va[1] + va[2]*va[2] + va[3]*va[3]
             + vb[0]*vb[0] + vb[1]*vb[1] + vb[2]*vb[2] + vb[3]*vb[3];
    ss = wave_sum(ss);
    float sc = rsqrtf(ss * (1.f / 512.f) + 1.1920929e-07f);
    float4 wa = *(const float4*)(wrms + lane * 4);
    float4 wb = *(const float4*)(wrms + lane * 4 + 256);
    ushort4 oa, obv;
    oa.x = f2bf(va[0] * sc * wa.x);
    oa.y = f2bf(va[1] * sc * wa.y);
    oa.z = f2bf(va[2] * sc * wa.z);
    oa.w = f2bf(va[3] * sc * wa.w);
    obv.x = f2bf(vb[0] * sc * wb.x);
    obv.y = f2bf(vb[1] * sc * wb.y);
    obv.z = f2bf(vb[2] * sc * wb.z);
    obv.w = f2bf(vb[3] * sc * wb.w);
    *(ushort4*)(o + base) = oa;
    *(ushort4*)(o + base + 256) = obv;
}

extern "C" void kernel_launch(void* const* d_in, const int* in_sizes, int n_in,
                              void* d_out, int out_size, void* d_ws, size_t ws_size,
                              hipStream_t stream) {
    const float* x = (const float*)d_in[0];
    const float* pe = (const float*)d_in[1];
    const float* mask = (const float*)d_in[2];
    const float* nsw = (const float*)d_in[3];
    const float* nfw = (const float*)d_in[4];
    const float* w1 = (const float*)d_in[5];
    const float* b1 = (const float*)d_in[6];
    const float* w2 = (const float*)d_in[7];
    const float* b2 = (const float*)d_in[8];
    const float* f_inw = (const float*)d_in[9];
    const float* f_cw = (const float*)d_in[10];
    const float* f_cb = (const float*)d_in[11];
    const float* f_dtb = (const float*)d_in[12];
    const float* f_al = (const float*)d_in[13];
    const float* f_D = (const float*)d_in[14];
    const float* f_gw = (const float*)d_in[15];
    const float* f_ow = (const float*)d_in[16];
    const float* b_inw = (const float*)d_in[17];
    const float* b_cw = (const float*)d_in[18];
    const float* b_cb = (const float*)d_in[19];
    const float* b_dtb = (const float*)d_in[20];
    const float* b_al = (const float*)d_in[21];
    const float* b_D = (const float*)d_in[22];
    const float* b_gw = (const float*)d_in[23];
    const float* b_ow = (const float*)d_in[24];
    float* out = (float*)d_out;

    char* ws = (char*)d_ws;
    u16* Z0   = (u16*)(ws + 0);
    u16* Z1   = (u16*)(ws + 8388608);
    u16* XB0  = (u16*)(ws + 16777216);
    u16* XB1  = (u16*)(ws + 26476544);
    u16* INWF = (u16*)(ws + 36175872);
    u16* INWB = (u16*)(ws + 38535168);
    u16* SIB  = (u16*)(ws + 40894464);
    u16* XC0  = (u16*)(ws + 36175872);
    u16* XC1  = (u16*)(ws + 45613056);
    float* dtF = (float*)(ws + 55050240);
    float* dAF = (float*)(ws + 55312384);
    float* dtB = (float*)(ws + 55574528);
    float* dAB = (float*)(ws + 55836672);
    u16* Y0   = (u16*)(ws + 16777216);
    u16* Y1   = (u16*)(ws + 25165824);
    u16* YG0  = (u16*)(ws + 36175872);
    u16* YG1  = (u16*)(ws + 44564480);
    u16* OP0  = (u16*)(ws + 0);
    u16* OP1  = (u16*)(ws + 4194304);
    float* X2 = (float*)(ws + 8388608);
    u16* X2B  = (u16*)(ws + 0);
    u16* HACT = (u16*)(ws + 16777216);
    u16* OWF = (u16*)(ws + 56098816);
    u16* OWB = (u16*)(ws + 57147392);
    u16* W1B = (u16*)(ws + 58195968);
    u16* W2B = (u16*)(ws + 60293120);
    float* SBUF = (float*)(ws + 62390272);
    float* APR  = (float*)(ws + 95944704);

    k_prep<<<6400, 256, 0, stream>>>(f_inw, b_inw, f_ow, b_ow, w1, w2,
                                     INWF, INWB, OWF, OWB, W1B, W2B,
                                     x, pe, nsw, SIB);
    k_gemm_in<<<dim3(18, 32, 2), 256, 0, stream>>>(SIB, INWF, INWB, Z0, Z1, XB0, XB1);
    k_conv<<<1024, 160, 0, stream>>>(XB0, XB1, f_cw, f_cb, f_dtb, f_al,
                                     b_cw, b_cb, b_dtb, b_al,
                                     XC0, XC1, dtF, dAF, dtB, dAB);
    k_ssd_state<<<2048, 256, 0, stream>>>(XC0, dtF, dAF, XC1, dtB, dAB, SBUF, APR);
    k_scan_carry<<<1024, 256, 0, stream>>>(SBUF, APR);
    k_ssd_y<<<2048, 256, 0, stream>>>(XC0, dtF, dAF, f_D, Y0,
                                      XC1, dtB, dAB, b_D, Y1, SBUF);
    k_gnorm<<<2048, 256, 0, stream>>>(Y0, Z0, f_gw, YG0, Y1, Z1, b_gw, YG1);
    // out-proj: M=4096, N=512, K=1024, 2 dirs -> 128x64 tiles, 512 blocks (2/CU)
    k_gemm12864<0><<<dim3(8, 32, 2), 256, 0, stream>>>(YG0, YG1, OWF, OWB, OP0, OP1, 512, 1024,
                                                       nullptr, nullptr, nullptr);
    k_add_rms<<<1024, 256, 0, stream>>>(x, OP0, OP1, mask, nfw, X2, X2B);
    // FFN1: M=4096, N=2048, K=512 -> 128x128 tiles, 512 blocks (2/CU)
    k_gemm128<1><<<dim3(16, 32, 1), 256, 0, stream>>>(X2B, X2B, W1B, W1B, HACT, HACT, 2048, 512,
                                                      b1, nullptr, nullptr);
    // FFN2: M=4096, N=512, K=2048 -> 64x64 tiles, 512 blocks (2/CU, high occupancy)
    k_gemm64<2><<<dim3(8, 64, 1), 256, 0, stream>>>(HACT, HACT, W2B, W2B, nullptr, nullptr,
                                                    512, 2048, b2, X2, out);
}